// Round 3
// baseline (1137.794 us; speedup 1.0000x reference)
//
#include <hip/hip_runtime.h>
#include <hip/hip_fp16.h>
#include <cstddef>

// ---------------------------------------------------------------------------
// GATv2 backbone: 3 layers, N=100k nodes, E=1.6M edges (+self loops), H=4.
//   - CSR by dst built once (histogram + 3-kernel multi-block scan + scatter).
//   - GEMMs: split-bf16 MFMA, A pre-split, W pre-split+transposed; register
//     prefetch. 1-D grid, z(head)-fastest linearization + XCD-chunked
//     bijective swizzle so all 8 blocks sharing an A-tile co-reside on ONE
//     XCD's L2 (r2 evidence: hsel-in-block loop re-fetched A 4x = 202 MB).
//     fp16 C written via LDS restage -> 16B/lane coalesced stores (r2: scalar
//     __half stores amplified 205->367 MB).
//   - Layers 0/1 gather: fp16 rows [N,128], packed-fp16 logits, fp32 value acc.
//   - Layer 2: ONE fused gather over fp16 [N,512]. r1 evidence: two different
//     schedules both sit at ~3.75 TB/s / 877 MB FETCH -> memory-path bound.
//   - One k_prep dispatch does all 6 weight splits + layer-0 A split.
// ---------------------------------------------------------------------------

typedef __attribute__((ext_vector_type(8))) short bf16x8;
typedef __attribute__((ext_vector_type(4))) float f32x4;
typedef _Float16 f16x2 __attribute__((ext_vector_type(2)));
typedef float f32x2 __attribute__((ext_vector_type(2)));

#if defined(__has_builtin)
#if __has_builtin(__builtin_amdgcn_fdot2)
#define HAS_FDOT2 1
#endif
#endif

__device__ __forceinline__ float lrelu(float x) { return fmaxf(x, 0.2f * x); }

// 16B row-fragment load at 32-bit byte offset
__device__ __forceinline__ uint4 ldrow(const void* base, unsigned byteoff) {
  return *(const uint4*)((const char*)base + byteoff);
}

// RNE fp32 -> bf16 hi + bf16 residual
__device__ __forceinline__ void split2(float x, unsigned short& h, unsigned short& l) {
  unsigned b = __float_as_uint(x);
  unsigned r = b + 0x7fffu + ((b >> 16) & 1u);
  h = (unsigned short)(r >> 16);
  float hf = __uint_as_float((unsigned)h << 16);
  float res = x - hf;
  unsigned b2 = __float_as_uint(res);
  unsigned r2 = b2 + 0x7fffu + ((b2 >> 16) & 1u);
  l = (unsigned short)(r2 >> 16);
}

// ---------------- CSR build ----------------
__global__ void k_init(int* __restrict__ degree, int* __restrict__ cursor, int N) {
  int i = blockIdx.x * blockDim.x + threadIdx.x;
  if (i < N) { degree[i] = 1; cursor[i] = 0; }  // 1 accounts for the self-loop
}

__global__ void k_hist(const int* __restrict__ ei, int E, int* __restrict__ degree) {
  int e = blockIdx.x * blockDim.x + threadIdx.x;
  if (e < E) atomicAdd(&degree[ei[E + e]], 1);
}

// --- 3-kernel scan: per-block sums -> scan of sums -> per-block scan+base ---
__global__ __launch_bounds__(256) void k_scan1(const int* __restrict__ degree,
                                               int* __restrict__ partial, int N) {
  __shared__ int ws[4];
  const int i0 = blockIdx.x * 1024 + threadIdx.x * 4;
  int s = 0;
  if (i0 + 3 < N) {
    int4 v = *(const int4*)&degree[i0];
    s = v.x + v.y + v.z + v.w;
  } else {
    #pragma unroll
    for (int k = 0; k < 4; k++) if (i0 + k < N) s += degree[i0 + k];
  }
  #pragma unroll
  for (int d = 1; d < 64; d <<= 1) s += __shfl_xor(s, d);
  const int lane = threadIdx.x & 63, wid = threadIdx.x >> 6;
  if (lane == 0) ws[wid] = s;
  __syncthreads();
  if (threadIdx.x == 0) partial[blockIdx.x] = ws[0] + ws[1] + ws[2] + ws[3];
}

__global__ __launch_bounds__(256) void k_scan2(int* __restrict__ partial, int nb) {
  __shared__ int sh[256];
  const int tid = threadIdx.x;
  int v = (tid < nb) ? partial[tid] : 0;
  sh[tid] = v;
  __syncthreads();
  for (int d = 1; d < 256; d <<= 1) {
    int t = (tid >= d) ? sh[tid - d] : 0;
    __syncthreads();
    sh[tid] += t;
    __syncthreads();
  }
  if (tid < nb) partial[tid] = sh[tid] - v;   // exclusive base per block
}

__global__ __launch_bounds__(256) void k_scan3(const int* __restrict__ degree,
                                               const int* __restrict__ partial,
                                               int* __restrict__ offs, int N) {
  __shared__ int wsum[4];
  const int tid = threadIdx.x, lane = tid & 63, wid = tid >> 6;
  const int i0 = blockIdx.x * 1024 + tid * 4;
  int v0 = 0, v1 = 0, v2 = 0, v3 = 0;
  if (i0 + 3 < N) {
    int4 v = *(const int4*)&degree[i0];
    v0 = v.x; v1 = v.y; v2 = v.z; v3 = v.w;
  } else {
    if (i0     < N) v0 = degree[i0];
    if (i0 + 1 < N) v1 = degree[i0 + 1];
    if (i0 + 2 < N) v2 = degree[i0 + 2];
    if (i0 + 3 < N) v3 = degree[i0 + 3];
  }
  int s = v0 + v1 + v2 + v3, x = s;
  #pragma unroll
  for (int d = 1; d < 64; d <<= 1) {
    int y = __shfl_up(x, d);
    if (lane >= d) x += y;
  }
  if (lane == 63) wsum[wid] = x;
  __syncthreads();
  if (tid < 4) {
    int t = wsum[tid];
    #pragma unroll
    for (int d = 1; d < 4; d <<= 1) {
      int y = __shfl_up(t, d);
      if (tid >= d) t += y;
    }
    wsum[tid] = t;
  }
  __syncthreads();
  const int wbase = wid ? wsum[wid - 1] : 0;
  int e = partial[blockIdx.x] + wbase + (x - s);
  if (i0     < N) offs[i0]     = e;  e += v0;  if (i0     == N - 1) offs[N] = e;
  if (i0 + 1 < N) offs[i0 + 1] = e;  e += v1;  if (i0 + 1 == N - 1) offs[N] = e;
  if (i0 + 2 < N) offs[i0 + 2] = e;  e += v2;  if (i0 + 2 == N - 1) offs[N] = e;
  if (i0 + 3 < N) offs[i0 + 3] = e;  e += v3;  if (i0 + 3 == N - 1) offs[N] = e;
}

__global__ void k_scatter(const int* __restrict__ ei, int E, int N,
                          const int* __restrict__ offs, int* __restrict__ cursor,
                          int* __restrict__ csr_src) {
  int t = blockIdx.x * blockDim.x + threadIdx.x;
  int ET = E + N;
  if (t >= ET) return;
  int s, d;
  if (t < E) { s = ei[t]; d = ei[E + t]; }
  else       { s = t - E; d = s; }
  int pos = offs[d] + atomicAdd(&cursor[d], 1);
  csr_src[pos] = s;
}

// ---- ONE prep dispatch: split+transpose all 6 weights, split layer-0 A -----
// weight elems: Wl0/Wr0/Wl1/Wr1 16384 each, Wl2/Wr2 65536 each = 196608 total.
__global__ __launch_bounds__(256) void k_prep(
    const float* __restrict__ Wl0, const float* __restrict__ Wr0,
    const float* __restrict__ Wl1, const float* __restrict__ Wr1,
    const float* __restrict__ Wl2, const float* __restrict__ Wr2,
    unsigned short* __restrict__ W0hl, unsigned short* __restrict__ W0ll,
    unsigned short* __restrict__ W0hr, unsigned short* __restrict__ W0lr,
    unsigned short* __restrict__ W1hl, unsigned short* __restrict__ W1ll,
    unsigned short* __restrict__ W1hr, unsigned short* __restrict__ W1lr,
    unsigned short* __restrict__ W2hl, unsigned short* __restrict__ W2ll,
    unsigned short* __restrict__ W2hr, unsigned short* __restrict__ W2lr,
    const float* __restrict__ X,
    unsigned short* __restrict__ Ah, unsigned short* __restrict__ Al, int totalA) {
  const int t = blockIdx.x * blockDim.x + threadIdx.x;
  if (t < 196608) {
    const float* W; unsigned short *Whp, *Wlp; int idx, sh;
    if (t < 16384)       { W = Wl0; Whp = W0hl; Wlp = W0ll; idx = t;          sh = 7; }
    else if (t < 32768)  { W = Wr0; Whp = W0hr; Wlp = W0lr; idx = t - 16384;  sh = 7; }
    else if (t < 49152)  { W = Wl1; Whp = W1hl; Wlp = W1ll; idx = t - 32768;  sh = 7; }
    else if (t < 65536)  { W = Wr1; Whp = W1hr; Wlp = W1lr; idx = t - 49152;  sh = 7; }
    else if (t < 131072) { W = Wl2; Whp = W2hl; Wlp = W2ll; idx = t - 65536;  sh = 9; }
    else                 { W = Wr2; Whp = W2hr; Wlp = W2lr; idx = t - 131072; sh = 9; }
    const int n = idx & ((1 << sh) - 1), k = idx >> sh;
    unsigned short h, l;
    split2(W[idx], h, l);
    Whp[(size_t)n * 128 + k] = h;
    Wlp[(size_t)n * 128 + k] = l;
    return;
  }
  const int t4 = (t - 196608) * 4;
  if (t4 >= totalA) return;
  float4 v = *(const float4*)&X[t4];
  unsigned short h0, h1, h2, h3, l0, l1, l2, l3;
  split2(v.x, h0, l0); split2(v.y, h1, l1);
  split2(v.z, h2, l2); split2(v.w, h3, l3);
  uint2 hv, lv;
  hv.x = (unsigned)h0 | ((unsigned)h1 << 16);
  hv.y = (unsigned)h2 | ((unsigned)h3 << 16);
  lv.x = (unsigned)l0 | ((unsigned)l1 << 16);
  lv.y = (unsigned)l2 | ((unsigned)l3 << 16);
  *(uint2*)&Ah[t4] = hv;
  *(uint2*)&Al[t4] = lv;
}

// ---------------- split-bf16 MFMA GEMM, dual projection, reg prefetch -------
// 1-D grid of mb*2*nh blocks. Decode (after XCD swizzle): head chunk fastest,
// then l/r, then M tile -> the 2*nh blocks sharing one A-tile are consecutive
// lbids, land in one XCD's chunk, and share the A-tile via that XCD's L2.
// fp16 out: acc -> LDS [128][136] -> 16B/lane coalesced stores.
__global__ __launch_bounds__(256) void k_gemm2s(
    const unsigned short* __restrict__ Agh, const unsigned short* __restrict__ Agl,
    const unsigned short* __restrict__ Whl, const unsigned short* __restrict__ Wll,
    const unsigned short* __restrict__ Whr, const unsigned short* __restrict__ Wlr,
    const float* __restrict__ bias_l, const float* __restrict__ bias_r,
    void* __restrict__ Clp, void* __restrict__ Crp, int N,
    int ldC, int out_half, int nh) {
  __shared__ __align__(16) unsigned short smem[4 * 128 * 36];  // 36864 B
  unsigned short (* __restrict__ Ah_s)[36] = (unsigned short(*)[36])(smem);
  unsigned short (* __restrict__ Al_s)[36] = (unsigned short(*)[36])(smem + 128 * 36);
  unsigned short (* __restrict__ Wh_s)[36] = (unsigned short(*)[36])(smem + 2 * 128 * 36);
  unsigned short (* __restrict__ Wl_s)[36] = (unsigned short(*)[36])(smem + 3 * 128 * 36);

  // XCD-chunked bijective swizzle (hardware round-robins blockIdx.x % 8)
  const int total = gridDim.x;
  const int q8 = total >> 3, r8 = total & 7;
  const int xcd = blockIdx.x & 7, pos = blockIdx.x >> 3;
  const int lbid = (xcd < r8 ? xcd * (q8 + 1) : r8 * (q8 + 1) + (xcd - r8) * q8) + pos;
  const int hsel = lbid % nh;
  const int yy = (lbid / nh) & 1;
  const int m0 = (lbid / (2 * nh)) * 128;

  const unsigned short* __restrict__ Wth = (yy ? Whr : Whl) + hsel * 128 * 128;
  const unsigned short* __restrict__ Wtl = (yy ? Wlr : Wll) + hsel * 128 * 128;
  const float* __restrict__ bias = (yy ? bias_r : bias_l) + hsel * 128;
  void* __restrict__ Cp = yy ? Crp : Clp;
  const int coloff = hsel * 128;

  const int tid = threadIdx.x;
  const int wv = tid >> 6, lane = tid & 63;
  const int wm = (wv >> 1) * 64, wn = (wv & 1) * 64;
  const int l15 = lane & 15, kb = (lane >> 4) * 8;
  f32x4 acc[4][4] = {};

  const int r = tid >> 1;              // staging row 0..127
  const int cb = (tid & 1) * 16;       // staging col base 0/16
  const bool arow_ok = (m0 + r) < N;
  const unsigned short* ahp = Agh + (size_t)(m0 + r) * 128 + cb;
  const unsigned short* alp = Agl + (size_t)(m0 + r) * 128 + cb;
  const unsigned short* whp = Wth + r * 128 + cb;
  const unsigned short* wlp = Wtl + r * 128 + cb;
  const uint4 z4 = make_uint4(0, 0, 0, 0);

  uint4 pa0, pa1, pl0, pl1, pw0, pw1, pq0, pq1;
  #define LOADC(K0)                                                           \
    pa0 = arow_ok ? *(const uint4*)(ahp + (K0))     : z4;                     \
    pa1 = arow_ok ? *(const uint4*)(ahp + (K0) + 8) : z4;                     \
    pl0 = arow_ok ? *(const uint4*)(alp + (K0))     : z4;                     \
    pl1 = arow_ok ? *(const uint4*)(alp + (K0) + 8) : z4;                     \
    pw0 = *(const uint4*)(whp + (K0));                                        \
    pw1 = *(const uint4*)(whp + (K0) + 8);                                    \
    pq0 = *(const uint4*)(wlp + (K0));                                        \
    pq1 = *(const uint4*)(wlp + (K0) + 8);
  LOADC(0)
  for (int kc = 0; kc < 4; kc++) {
    *(uint4*)&Ah_s[r][cb]     = pa0;
    *(uint4*)&Ah_s[r][cb + 8] = pa1;
    *(uint4*)&Al_s[r][cb]     = pl0;
    *(uint4*)&Al_s[r][cb + 8] = pl1;
    *(uint4*)&Wh_s[r][cb]     = pw0;
    *(uint4*)&Wh_s[r][cb + 8] = pw1;
    *(uint4*)&Wl_s[r][cb]     = pq0;
    *(uint4*)&Wl_s[r][cb + 8] = pq1;
    __syncthreads();
    if (kc < 3) { LOADC((kc + 1) * 32) }   // in flight during MFMA below

    bf16x8 afh[4], afl[4];
    #pragma unroll
    for (int mi = 0; mi < 4; mi++) {
      const int row = wm + mi * 16 + l15;
      afh[mi] = *(const bf16x8*)&Ah_s[row][kb];
      afl[mi] = *(const bf16x8*)&Al_s[row][kb];
    }
    #pragma unroll
    for (int ni = 0; ni < 4; ni++) {
      const int rown = wn + ni * 16 + l15;
      bf16x8 bh = *(const bf16x8*)&Wh_s[rown][kb];
      bf16x8 bl = *(const bf16x8*)&Wl_s[rown][kb];
      #pragma unroll
      for (int mi = 0; mi < 4; mi++) {
        acc[mi][ni] = __builtin_amdgcn_mfma_f32_16x16x32_bf16(afh[mi], bh, acc[mi][ni], 0, 0, 0);
        acc[mi][ni] = __builtin_amdgcn_mfma_f32_16x16x32_bf16(afl[mi], bh, acc[mi][ni], 0, 0, 0);
        acc[mi][ni] = __builtin_amdgcn_mfma_f32_16x16x32_bf16(afh[mi], bl, acc[mi][ni], 0, 0, 0);
      }
    }
    __syncthreads();
  }
  #undef LOADC
  const int col = l15, rbase = (lane >> 4) * 4;
  if (out_half) {
    // restage chunk in LDS (staging buffers are dead after last barrier)
    __half* C_s = (__half*)smem;            // [128][136] = 34816 B <= 36864
    #pragma unroll
    for (int ni = 0; ni < 4; ni++) {
      const int gn = wn + ni * 16 + col;
      const float bv = bias[gn];
      #pragma unroll
      for (int mi = 0; mi < 4; mi++) {
        #pragma unroll
        for (int q = 0; q < 4; q++)
          C_s[(wm + mi * 16 + rbase + q) * 136 + gn] = __float2half(acc[mi][ni][q] + bv);
      }
    }
    __syncthreads();
    __half* Cb = (__half*)Cp + (size_t)m0 * ldC + coloff;
    #pragma unroll
    for (int i = 0; i < 8; i++) {
      const int flat = tid + i * 256;       // 0..2047 (128 rows x 16 uint4)
      const int row = flat >> 4, c16 = flat & 15;
      if (m0 + row < N)
        *(uint4*)(Cb + (size_t)row * ldC + c16 * 8) =
            *(const uint4*)(C_s + row * 136 + c16 * 8);
    }
  } else {
    #pragma unroll
    for (int ni = 0; ni < 4; ni++) {
      const int gn = wn + ni * 16 + col;
      const float bv = bias[gn];
      #pragma unroll
      for (int mi = 0; mi < 4; mi++) {
        #pragma unroll
        for (int q = 0; q < 4; q++) {
          const int gm = m0 + wm + mi * 16 + rbase + q;
          if (gm < N)
            ((float*)Cp)[(size_t)gm * ldC + coloff + gn] = acc[mi][ni][q] + bv;
        }
      }
    }
  }
}

// -------- butterfly ADD merge of per-group partials (plain-exp softmax) -----
#define MERGE_ADD(d)                                                          \
  {                                                                           \
    l += __shfl_xor(l, d);                                                    \
    aca.x += __shfl_xor(aca.x, d); aca.y += __shfl_xor(aca.y, d);             \
    aca.z += __shfl_xor(aca.z, d); aca.w += __shfl_xor(aca.w, d);             \
    acb.x += __shfl_xor(acb.x, d); acb.y += __shfl_xor(acb.y, d);             \
    acb.z += __shfl_xor(acb.z, d); acb.w += __shfl_xor(acb.w, d);             \
  }

// ---------------- fused GATv2 gather, layers 0/1 (fp32 fallback) ------------
__global__ __launch_bounds__(256) void k_gat_small(
    const float* __restrict__ xl, const float* __restrict__ xr,
    const float* __restrict__ att, const float* __restrict__ bias,
    const int* __restrict__ offs, const int* __restrict__ degree,
    const int* __restrict__ csr_src,
    unsigned short* __restrict__ Ah, unsigned short* __restrict__ Al, int N) {
  const int node = blockIdx.x * 4 + (threadIdx.x >> 6);
  if (node >= N) return;
  const int lane = threadIdx.x & 63;
  const int g = lane >> 4;
  const int c = lane & 15;
  const int d0 = c * 8;
  const size_t nb = (size_t)node * 128 + d0;
  const float4 xra = *(const float4*)&xr[nb];
  const float4 xrb = *(const float4*)&xr[nb + 4];
  const float4 ata = *(const float4*)&att[d0];
  const float4 atb = *(const float4*)&att[d0 + 4];
  const int off = offs[node];
  const int deg = degree[node];
  float l = 0.f;
  float4 aca = make_float4(0.f, 0.f, 0.f, 0.f);
  float4 acb = make_float4(0.f, 0.f, 0.f, 0.f);
  int s0 = (g < deg) ? csr_src[off + g] : 0;
  int s1 = (g + 4 < deg) ? csr_src[off + g + 4] : 0;
  for (int j = g; j < deg; j += 8) {
    int sn0 = (j + 8 < deg) ? csr_src[off + j + 8] : 0;
    int sn1 = (j + 12 < deg) ? csr_src[off + j + 12] : 0;
    const size_t sb0 = (size_t)s0 * 128 + d0;
    const size_t sb1 = (size_t)s1 * 128 + d0;
    float4 xa0 = *(const float4*)&xl[sb0];
    float4 xb0 = *(const float4*)&xl[sb0 + 4];
    float4 xa1 = *(const float4*)&xl[sb1];
    float4 xb1 = *(const float4*)&xl[sb1 + 4];
    float t0 = lrelu(xa0.x + xra.x) * ata.x + lrelu(xa0.y + xra.y) * ata.y +
               lrelu(xa0.z + xra.z) * ata.z + lrelu(xa0.w + xra.w) * ata.w +
               lrelu(xb0.x + xrb.x) * atb.x + lrelu(xb0.y + xrb.y) * atb.y +
               lrelu(xb0.z + xrb.z) * atb.z + lrelu(xb0.w + xrb.w) * atb.w;
    float t1 = lrelu(xa1.x + xra.x) * ata.x + lrelu(xa1.y + xra.y) * ata.y +
               lrelu(xa1.z + xra.z) * ata.z + lrelu(xa1.w + xra.w) * ata.w +
               lrelu(xb1.x + xrb.x) * atb.x + lrelu(xb1.y + xrb.y) * atb.y +
               lrelu(xb1.z + xrb.z) * atb.z + lrelu(xb1.w + xrb.w) * atb.w;
    t0 += __shfl_xor(t0, 1);
    t0 += __shfl_xor(t0, 2);       // 4-lane head cluster -> per-head logit
    t1 += __shfl_xor(t1, 1);
    t1 += __shfl_xor(t1, 2);
    float p0 = __expf(t0);
    float p1 = (j + 4 < deg) ? __expf(t1) : 0.f;
    aca.x += p0 * xa0.x + p1 * xa1.x; aca.y += p0 * xa0.y + p1 * xa1.y;
    aca.z += p0 * xa0.z + p1 * xa1.z; aca.w += p0 * xa0.w + p1 * xa1.w;
    acb.x += p0 * xb0.x + p1 * xb1.x; acb.y += p0 * xb0.y + p1 * xb1.y;
    acb.z += p0 * xb0.z + p1 * xb1.z; acb.w += p0 * xb0.w + p1 * xb1.w;
    l += p0 + p1;
    s0 = sn0; s1 = sn1;
  }
  MERGE_ADD(16)
  MERGE_ADD(32)
  if (lane < 16) {
    const float inv = 1.f / l;
    const float4 b0 = *(const float4*)&bias[d0];
    const float4 b1 = *(const float4*)&bias[d0 + 4];
    float o[8] = {aca.x * inv + b0.x, aca.y * inv + b0.y,
                  aca.z * inv + b0.z, aca.w * inv + b0.w,
                  acb.x * inv + b1.x, acb.y * inv + b1.y,
                  acb.z * inv + b1.z, acb.w * inv + b1.w};
    unsigned short hs[8], ls[8];
    #pragma unroll
    for (int i = 0; i < 8; i++) {
      o[i] = o[i] > 0.f ? o[i] : __expf(o[i]) - 1.f;   // ELU
      split2(o[i], hs[i], ls[i]);
    }
    uint4 hv, lv;
    hv.x = (unsigned)hs[0] | ((unsigned)hs[1] << 16);
    hv.y = (unsigned)hs[2] | ((unsigned)hs[3] << 16);
    hv.z = (unsigned)hs[4] | ((unsigned)hs[5] << 16);
    hv.w = (unsigned)hs[6] | ((unsigned)hs[7] << 16);
    lv.x = (unsigned)ls[0] | ((unsigned)ls[1] << 16);
    lv.y = (unsigned)ls[2] | ((unsigned)ls[3] << 16);
    lv.z = (unsigned)ls[4] | ((unsigned)ls[5] << 16);
    lv.w = (unsigned)ls[6] | ((unsigned)ls[7] << 16);
    *(uint4*)&Ah[nb] = hv;
    *(uint4*)&Al[nb] = lv;
  }
}

// ---------------- packed-fp16 edge steps ------------------------------------
// 512-wide (layer 2): 16-lane head group reduce (4 shfl)
__device__ __forceinline__ void edge_step(uint4 vv, bool valid,
                                          const f16x2* xrh, const f16x2* ath,
                                          f32x2* accv, float& l) {
  union { uint4 u; f16x2 h[4]; } xu; xu.u = vv;
  const f16x2 c02 = {(_Float16)0.2f, (_Float16)0.2f};
  float t = 0.f;
#if defined(HAS_FDOT2)
  #pragma unroll
  for (int i = 0; i < 4; i++) {
    f16x2 s = xu.h[i] + xrh[i];
    f16x2 lr = __builtin_elementwise_max(s, s * c02);
    t = __builtin_amdgcn_fdot2(lr, ath[i], t, false);
  }
#else
  #pragma unroll
  for (int i = 0; i < 4; i++) {
    f32x2 s = __builtin_convertvector(xu.h[i], f32x2) +
              __builtin_convertvector(xrh[i], f32x2);
    f32x2 a = __builtin_convertvector(ath[i], f32x2);
    t += fmaxf(s.x, 0.2f * s.x) * a.x + fmaxf(s.y, 0.2f * s.y) * a.y;
  }
#endif
  t += __shfl_xor(t, 1);
  t += __shfl_xor(t, 2);
  t += __shfl_xor(t, 4);
  t += __shfl_xor(t, 8);         // 16-lane head group -> head logit
  float p = valid ? __expf(t) : 0.f;
  l += p;
  f32x2 p2 = {p, p};
  #pragma unroll
  for (int i = 0; i < 4; i++)
    accv[i] += p2 * __builtin_convertvector(xu.h[i], f32x2);  // v_pk_fma_f32
}

// 128-wide (layers 0/1): 4-lane head cluster reduce (2 shfl), all edges valid
__device__ __forceinline__ void edge_step_small(uint4 vv,
                                                const f16x2* xrh, const f16x2* ath,
                                                f32x2* accv, float& l) {
  union { uint4 u; f16x2 h[4]; } xu; xu.u = vv;
  const f16x2 c02 = {(_Float16)0.2f, (_Float16)0.2f};
  float t = 0.f;
#if defined(HAS_FDOT2)
  #pragma unroll
  for (int i = 0; i < 4; i++) {
    f16x2 s = xu.h[i] + xrh[i];
    f16x2 lr = __builtin_elementwise_max(s, s * c02);
    t = __builtin_amdgcn_fdot2(lr, ath[i], t, false);
  }
#else
  #pragma unroll
  for (int i = 0; i < 4; i++) {
    f32x2 s = __builtin_convertvector(xu.h[i], f32x2) +
              __builtin_convertvector(xrh[i], f32x2);
    f32x2 a = __builtin_convertvector(ath[i], f32x2);
    t += fmaxf(s.x, 0.2f * s.x) * a.x + fmaxf(s.y, 0.2f * s.y) * a.y;
  }
#endif
  t += __shfl_xor(t, 1);
  t += __shfl_xor(t, 2);         // 4-lane head cluster -> per-head logit
  float p = __expf(t);
  l += p;
  f32x2 p2 = {p, p};
  #pragma unroll
  for (int i = 0; i < 4; i++)
    accv[i] += p2 * __builtin_convertvector(xu.h[i], f32x2);
}

// ---------------- layers 0/1 gather over fp16 [N,128] -----------------------
__global__ __launch_bounds__(256) void k_gat_small16(
    const __half* __restrict__ xl, const __half* __restrict__ xr,
    const float* __restrict__ att, const float* __restrict__ bias,
    const int* __restrict__ offs, const int* __restrict__ degree,
    const int* __restrict__ csr_src,
    unsigned short* __restrict__ Ah, unsigned short* __restrict__ Al, int N) {
  const int node = blockIdx.x * 4 + (threadIdx.x >> 6);
  if (node >= N) return;
  const int lane = threadIdx.x & 63;
  const int g = lane >> 4;        // edge slot
  const int c = lane & 15;        // channel group (8 ch)
  const int d0 = c * 8;
  f16x2 xrh[4], ath[4];
  {
    union { uint4 u; f16x2 h[4]; } ru;
    ru.u = *(const uint4*)&xr[(size_t)node * 128 + d0];
    float4 a0 = *(const float4*)&att[d0];
    float4 a1 = *(const float4*)&att[d0 + 4];
    #pragma unroll
    for (int i = 0; i < 4; i++) xrh[i] = ru.h[i];
    ath[0] = (f16x2){(_Float16)a0.x, (_Float16)a0.y};
    ath[1] = (f16x2){(_Float16)a0.z, (_Float16)a0.w};
    ath[2] = (f16x2){(_Float16)a1.x, (_Float16)a1.y};
    ath[3] = (f16x2){(_Float16)a1.z, (_Float16)a1.w};
  }
  const int off = offs[node];
  const int deg = degree[node];
  const unsigned lb = (unsigned)d0 * 2u;        // byte offset in 256 B row
  f32x2 accv[4] = {};
  float l = 0.f;
  int ia = (g < deg)     ? csr_src[off + g]     : 0;
  int ib = (g + 4 < deg) ? csr_src[off + g + 4] : 0;
  int ic = (g + 8 < deg) ? csr_src[off + g + 8] : 0;
  uint4 v0 = make_uint4(0, 0, 0, 0), v1 = v0;
  if (g < deg)     v0 = ldrow(xl, (unsigned)ia * 256u + lb);
  if (g + 4 < deg) v1 = ldrow(xl, (unsigned)ib * 256u + lb);
  for (int j = g; j < deg; j += 4) {
    uint4 vn = v0;
    if (j + 8 < deg) vn = ldrow(xl, (unsigned)ic * 256u + lb);
    int id = (j + 12 < deg) ? csr_src[off + j + 12] : 0;
    edge_step_small(v0, xrh, ath, accv, l);
    v0 = v1; v1 = vn; ic = id;
  }
  // merge the 4 slots (lanes differ in bits 4-5)
  #pragma unroll
  for (int d = 16; d < 64; d <<= 1) {
    l += __shfl_xor(l, d);
    #pragma unroll
    for (int i = 0; i < 4; i++) {
      accv[i].x += __shfl_xor(accv[i].x, d);
      accv[i].y += __shfl_xor(accv[i].y, d);
    }
  }
  if (lane < 16) {
    const float inv = 1.f / l;
    const float4 b0 = *(const float4*)&bias[d0];
    const float4 b1 = *(const float4*)&bias[d0 + 4];
    float o[8] = {accv[0].x * inv + b0.x, accv[0].y * inv + b0.y,
                  accv[1].x * inv + b0.z, accv[1].y * inv + b0.w,
                  accv[2].x * inv + b1.x, accv[2].y * inv + b1.y,
                  accv[3].x * inv + b1.z, accv[3].y * inv + b1.w};
    unsigned short hs[8], ls[8];
    #pragma unroll
    for (int i = 0; i < 8; i++) {
      o[i] = o[i] > 0.f ? o[i] : __expf(o[i]) - 1.f;   // ELU
      split2(o[i], hs[i], ls[i]);
    }
    uint4 hv, lv;
    hv.x = (unsigned)hs[0] | ((unsigned)hs[1] << 16);
    hv.y = (unsigned)hs[2] | ((unsigned)hs[3] << 16);
    hv.z = (unsigned)hs[4] | ((unsigned)hs[5] << 16);
    hv.w = (unsigned)hs[6] | ((unsigned)hs[7] << 16);
    lv.x = (unsigned)ls[0] | ((unsigned)ls[1] << 16);
    lv.y = (unsigned)ls[2] | ((unsigned)ls[3] << 16);
    lv.z = (unsigned)ls[4] | ((unsigned)ls[5] << 16);
    lv.w = (unsigned)ls[6] | ((unsigned)ls[7] << 16);
    const size_t nb = (size_t)node * 128 + d0;
    *(uint4*)&Ah[nb] = hv;
    *(uint4*)&Al[nb] = lv;
  }
}

// ---------------- layer 2 FUSED gather: rotating prefetch -------------------
__global__ __launch_bounds__(256) void k_gat_fused4(
    const __half* __restrict__ xl4, const __half* __restrict__ xr4,
    const float* __restrict__ att2, const float* __restrict__ bias,
    const int* __restrict__ offs, const int* __restrict__ degree,
    const int* __restrict__ csr_src, float* __restrict__ out, int N) {
  const int node = blockIdx.x * 4 + (threadIdx.x >> 6);
  if (node >= N) return;
  const int lane = threadIdx.x & 63;
  f16x2 xrh[4], ath[4];
  {
    union { uint4 u; f16x2 h[4]; } ru;
    ru.u = *(const uint4*)&xr4[(size_t)node * 512 + lane * 8];
    float4 a0 = *(const float4*)&att2[lane * 8];
    float4 a1 = *(const float4*)&att2[lane * 8 + 4];
    #pragma unroll
    for (int i = 0; i < 4; i++) xrh[i] = ru.h[i];
    ath[0] = (f16x2){(_Float16)a0.x, (_Float16)a0.y};
    ath[1] = (f16x2){(_Float16)a0.z, (_Float16)a0.w};
    ath[2] = (f16x2){(_Float16)a1.x, (_Float16)a1.y};
    ath[3] = (f16x2){(_Float16)a1.z, (_Float16)a1.w};
  }
  const int off = offs[node];
  const int deg = degree[node];
  const unsigned lb = (unsigned)lane * 16u;     // byte offset in 1 KB row
  f32x2 accv[4] = {};
  float l = 0.f;
  int s0 = csr_src[off];
  int s1 = (1 < deg) ? csr_src[off + 1] : 0;
  int s2 = (2 < deg) ? csr_src[off + 2] : 0;
  int s3 = (3 < deg) ? csr_src[off + 3] : 0;
  uint4 v0 = ldrow(xl4, (unsigned)s0 * 1024u + lb);
  uint4 v1 = (1 < deg) ? ldrow(xl4, (unsigned)s1 * 1024u + lb) : v0;
  uint4 v2 = (2 < deg) ? ldrow(xl4, (unsigned)s2 * 1024u + lb) : v0;
  uint4 v3 = (3 < deg) ? ldrow(xl4, (unsigned)s3 * 1024u + lb) : v0;
  s0 = (4 < deg) ? csr_src[off + 4] : 0;        // indices one iter ahead
  s1 = (5 < deg) ? csr_src[off + 5] : 0;
  s2 = (6 < deg) ? csr_src[off + 6] : 0;
  s3 = (7 < deg) ? csr_src[off + 7] : 0;
  for (int j = 0; j < deg; j += 4) {
    edge_step(v0, true, xrh, ath, accv, l);     // j < deg guaranteed
    if (j + 4 < deg) v0 = ldrow(xl4, (unsigned)s0 * 1024u + lb);
    s0 = (j + 8 < deg) ? csr_src[off + j + 8] : 0;
    edge_step(v1, j + 1 < deg, xrh, ath, accv, l);
    if (j + 5 < deg) v1 = ldrow(xl4, (unsigned)s1 * 1024u + lb);
    s1 = (j + 9 < deg) ? csr_src[off + j + 9] : 0;
    edge_step(v2, j + 2 < deg, xrh, ath, accv, l);
    if (j + 6 < deg) v2 = ldrow(xl4, (unsigned)s2 * 1024u + lb);
    s2 = (j + 10 < deg) ? csr_src[off + j + 10] : 0;
    edge_step(v3, j + 3 < deg, xrh, ath, accv, l);
    if (j + 7 < deg) v3 = ldrow(xl4, (unsigned)s3 * 1024u + lb);
    s3 = (j + 11 < deg) ? csr_src[off + j + 11] : 0;
  }
  // scale by own head's softmax-mean weight, then sum heads via butterfly
  const float w = 0.25f / l;
  const f32x2 w2 = {w, w};
  #pragma unroll
  for (int i = 0; i < 4; i++) accv[i] *= w2;
  #pragma unroll
  for (int d = 16; d < 64; d <<= 1) {
    #pragma unroll
    for (int i = 0; i < 4; i++) {
      accv[i].x += __shfl_xor(accv[i].x, d);
      accv[i].y += __shfl_xor(accv[i].y, d);
    }
  }
  if (lane < 16) {
    const int d0 = lane * 8;
    float4 b0 = *(const float4*)&bias[d0];
    float4 b1 = *(const float4*)&bias[d0 + 4];
    float* op = &out[(size_t)node * 128 + d0];
    *(float4*)op       = make_float4(accv[0].x + b0.x, accv[0].y + b0.y,
                                     accv[1].x + b0.z, accv[1].y + b0.w);
    *(float4*)(op + 4) = make_float4(accv[2].x + b1.x, accv[2].y + b1.y,
                                     accv[3].x + b1.z, accv[3].y + b1.w);
  }
}

// ---------------- fallback: layer 2 per-head fp32 gather --------------------
__global__ __launch_bounds__(256) void k_gat_head(
    const float* __restrict__ xl, const float* __restrict__ xr,
    const float* __restrict__ att_h, const float* __restrict__ bias,
    const int* __restrict__ offs, const int* __restrict__ degree,
    const int* __restrict__ csr_src, float* __restrict__ out, int N,
    int first, int last) {
  const int node = blockIdx.x * 4 + (threadIdx.x >> 6);
  if (node >= N) return;
  const int lane = threadIdx.x & 63;
  const int g = lane >> 4;
  const int c = lane & 15;
  const int d0 = c * 8;
  const size_t nb = (size_t)node * 128 + d0;
  const float4 xra = *(const float4*)&xr[nb];
  const float4 xrb = *(const float4*)&xr[nb + 4];
  const float4 ata = *(const float4*)&att_h[d0];
  const float4 atb = *(const float4*)&att_h[d0 + 4];
  const int off = offs[node];
  const int deg = degree[node];
  float l = 0.f;
  float4 aca = make_float4(0.f, 0.f, 0.f, 0.f);
  float4 acb = make_float4(0.f, 0.f, 0.f, 0.f);
  int s0 = (g < deg) ? csr_src[off + g] : 0;
  int s1 = (g + 4 < deg) ? csr_src[off + g + 4] : 0;
  for (int j = g; j < deg; j += 8) {
    int sn0 = (j + 8 < deg) ? csr_src[off + j + 8] : 0;
    int sn1 = (j + 12 < deg) ? csr_src[off + j + 12] : 0;
    const size_t sb0 = (size_t)s0 * 128 + d0;
    const size_t sb1 = (size_t)s1 * 128 + d0;
    float4 xa0 = *(const float4*)&xl[sb0];
    float4 xb0 = *(const float4*)&xl[sb0 + 4];
    float4 xa1 = *(const float4*)&xl[sb1];
    float4 xb1 = *(const float4*)&xl[sb1 + 4];
    float t0 = lrelu(xa0.x + xra.x) * ata.x + lrelu(xa0.y + xra.y) * ata.y +
               lrelu(xa0.z + xra.z) * ata.z + lrelu(xa0.w + xra.w) * ata.w +
               lrelu(xb0.x + xrb.x) * atb.x + lrelu(xb0.y + xrb.y) * atb.y +
               lrelu(xb0.z + xrb.z) * atb.z + lrelu(xb0.w + xrb.w) * atb.w;
    float t1 = lrelu(xa1.x + xra.x) * ata.x + lrelu(xa1.y + xra.y) * ata.y +
               lrelu(xa1.z + xra.z) * ata.z + lrelu(xa1.w + xra.w) * ata.w +
               lrelu(xb1.x + xrb.x) * atb.x + lrelu(xb1.y + xrb.y) * atb.y +
               lrelu(xb1.z + xrb.z) * atb.z + lrelu(xb1.w + xrb.w) * atb.w;
    t0 += __shfl_xor(t0, 1);
    t0 += __shfl_xor(t0, 2);
    t0 += __shfl_xor(t0, 4);
    t0 += __shfl_xor(t0, 8);
    t1 += __shfl_xor(t1, 1);
    t1 += __shfl_xor(t1, 2);
    t1 += __shfl_xor(t1, 4);
    t1 += __shfl_xor(t1, 8);
    float p0 = __expf(t0);
    float p1 = (j + 4 < deg) ? __expf(t1) : 0.f;
    aca.x += p0 * xa0.x + p1 * xa1.x; aca.y += p0 * xa0.y + p1 * xa1.y;
    aca.z += p0 * xa0.z + p1 * xa1.z; aca.w += p0 * xa0.w + p1 * xa1.w;
    acb.x += p0 * xb0.x + p1 * xb1.x; acb.y += p0 * xb0.y + p1 * xb1.y;
    acb.z += p0 * xb0.z + p1 * xb1.z; acb.w += p0 * xb0.w + p1 * xb1.w;
    l += p0 + p1;
    s0 = sn0; s1 = sn1;
  }
  MERGE_ADD(16)
  MERGE_ADD(32)
  if (lane < 16) {
    const float inv = 0.25f / l;
    float o[8] = {aca.x * inv, aca.y * inv, aca.z * inv, aca.w * inv,
                  acb.x * inv, acb.y * inv, acb.z * inv, acb.w * inv};
    float* op = &out[nb];
    if (!first) {
      float4 p0 = *(const float4*)op;
      float4 p1 = *(const float4*)(op + 4);
      o[0] += p0.x; o[1] += p0.y; o[2] += p0.z; o[3] += p0.w;
      o[4] += p1.x; o[5] += p1.y; o[6] += p1.z; o[7] += p1.w;
    }
    if (last) {
      float4 b0 = *(const float4*)&bias[d0];
      float4 b1 = *(const float4*)&bias[d0 + 4];
      o[0] += b0.x; o[1] += b0.y; o[2] += b0.z; o[3] += b0.w;
      o[4] += b1.x; o[5] += b1.y; o[6] += b1.z; o[7] += b1.w;
    }
    *(float4*)op       = make_float4(o[0], o[1], o[2], o[3]);
    *(float4*)(op + 4) = make_float4(o[4], o[5], o[6], o[7]);
  }
}

// ---------------------------------------------------------------------------
extern "C" void kernel_launch(void* const* d_in, const int* in_sizes, int n_in,
                              void* d_out, int out_size, void* d_ws, size_t ws_size,
                              hipStream_t stream) {
  const float* x     = (const float*)d_in[0];
  const int*   ei    = (const int*)  d_in[1];
  const float* Wl0   = (const float*)d_in[2];
  const float* bl0   = (const float*)d_in[3];
  const float* Wr0   = (const float*)d_in[4];
  const float* br0   = (const float*)d_in[5];
  const float* att0  = (const float*)d_in[6];
  const float* bias0 = (const float*)d_in[7];
  const float* Wl1   = (const float*)d_in[8];
  const float* bl1   = (const float*)d_in[9];
  const float* Wr1   = (const float*)d_in[10];
  const float* br1   = (const float*)d_in[11];
  const float* att1  = (const float*)d_in[12];
  const float* bias1 = (const float*)d_in[13];
  const float* Wl2   = (const float*)d_in[14];
  const float* bl2   = (const float*)d_in[15];
  const float* Wr2   = (const float*)d_in[16];
  const float* br2   = (const float*)d_in[17];
  const float* att2  = (const float*)d_in[18];
  const float* bias2 = (const float*)d_in[19];

  const int N = in_sizes[0] / 128;
  const int E = in_sizes[1] / 2;

  char* p = (char*)d_ws;
  auto alloc = [&](size_t bytes) {
    void* q = (void*)p;
    p += (bytes + 255) & ~(size_t)255;
    return q;
  };
  auto al = [](size_t b) { return (b + 255) & ~(size_t)255; };
  const size_t common = al((size_t)(N + 1) * 4) + 2 * al((size_t)N * 4) +
                        al((size_t)(E + N) * 4) + al((size_t)512) +
                        2 * al((size_t)N * 128 * 2) +
                        8 * al((size_t)128 * 128 * 2) +
                        4 * al((size_t)512 * 128 * 2);
  const size_t need_fused = common + 2 * al((size_t)N * 512 * 2);
  const bool fused = ws_size >= need_fused;   // deterministic across calls

  int* offs    = (int*)alloc((size_t)(N + 1) * 4);
  int* degree  = (int*)alloc((size_t)N * 4);
  int* cursor  = (int*)alloc((size_t)N * 4);
  int* csr_src = (int*)alloc((size_t)(E + N) * 4);
  int* partial = (int*)alloc((size_t)512);
  unsigned short* Agh = (unsigned short*)alloc((size_t)N * 128 * 2);
  unsigned short* Agl = (unsigned short*)alloc((size_t)N * 128 * 2);
  unsigned short* W0hl = (unsigned short*)alloc((size_t)128 * 128 * 2);
  unsigned short* W0ll = (unsigned short*)alloc((size_t)128 * 128 * 2);
  unsigned short* W0hr = (unsigned short*)alloc((size_t)128 * 128 * 2);
  unsigned short* W0lr = (unsigned short*)alloc((size_t)128 * 128 * 2);
  unsigned short* W1hl = (unsigned short*)alloc((size_t)128 * 128 * 2);
  unsigned short* W1ll = (unsigned short*)alloc((size_t)128 * 128 * 2);
  unsigned short* W1hr = (unsigned short*)alloc((size_t)128 * 128 * 2);
  unsigned short* W1lr = (unsigned short*)alloc((size_t)128 * 128 * 2);
  unsigned short* W2hl = (unsigned short*)alloc((size_t)512 * 128 * 2);
  unsigned short* W2ll = (unsigned short*)alloc((size_t)512 * 128 * 2);
  unsigned short* W2hr = (unsigned short*)alloc((size_t)512 * 128 * 2);
  unsigned short* W2lr = (unsigned short*)alloc((size_t)512 * 128 * 2);
  __half* xl4 = nullptr; __half* xr4 = nullptr;   // fused: fp16 [N,512]
  float* xl = nullptr; float* xr = nullptr;       // fallback fp32 [N,128]
  __half* xl16 = nullptr; __half* xr16 = nullptr; // fused: fp16 [N,128] views
  if (fused) {
    xl4 = (__half*)alloc((size_t)N * 512 * 2);
    xr4 = (__half*)alloc((size_t)N * 512 * 2);
    xl16 = xl4;              // layers 0/1 alias the big buffers ([N,128] fp16)
    xr16 = xr4;
  } else {
    xl = (float*)alloc((size_t)N * 128 * 4);
    xr = (float*)alloc((size_t)N * 128 * 4);
  }
  (void)n_in; (void)out_size;

  const int nb = (N + 1023) / 1024;

  // CSR build (ws is re-poisoned each call, so rebuild every launch)
  k_init<<<(N + 255) / 256, 256, 0, stream>>>(degree, cursor, N);
  k_hist<<<(E + 255) / 256, 256, 0, stream>>>(ei, E, degree);
  k_scan1<<<nb, 256, 0, stream>>>(degree, partial, N);
  k_scan2<<<1, 256, 0, stream>>>(partial, nb);
  k_scan3<<<nb, 256, 0, stream>>>(degree, partial, offs, N);
  k_scatter<<<(E + N + 255) / 256, 256, 0, stream>>>(ei, E, N, offs, cursor, csr_src);

  // one prep dispatch: all 6 weight splits + layer-0 A split
  const int prepT = 196608 + (N * 128 + 3) / 4;
  k_prep<<<(prepT + 255) / 256, 256, 0, stream>>>(
      Wl0, Wr0, Wl1, Wr1, Wl2, Wr2,
      W0hl, W0ll, W0hr, W0lr, W1hl, W1ll, W1hr, W1lr,
      W2hl, W2ll, W2hr, W2lr, x, Agh, Agl, N * 128);

  const int mb = (N + 127) / 128;        // M tiles
  const int gb = (N + 3) / 4;            // gather grid (4 nodes / block)

  if (fused) {
    // layer 0
    k_gemm2s<<<mb * 2, 256, 0, stream>>>(Agh, Agl, W0hl, W0ll, W0hr, W0lr,
                                         bl0, br0, xl16, xr16, N, 128, 1, 1);
    k_gat_small16<<<gb, 256, 0, stream>>>(xl16, xr16, att0, bias0, offs, degree,
                                          csr_src, Agh, Agl, N);
    // layer 1
    k_gemm2s<<<mb * 2, 256, 0, stream>>>(Agh, Agl, W1hl, W1ll, W1hr, W1lr,
                                         bl1, br1, xl16, xr16, N, 128, 1, 1);
    k_gat_small16<<<gb, 256, 0, stream>>>(xl16, xr16, att1, bias1, offs, degree,
                                          csr_src, Agh, Agl, N);
    // layer 2: head chunk per block (z-fastest), XCD-swizzled
    k_gemm2s<<<mb * 2 * 4, 256, 0, stream>>>(Agh, Agl, W2hl, W2ll, W2hr, W2lr,
                                             bl2, br2, xl4, xr4, N, 512, 1, 4);
    k_gat_fused4<<<gb, 256, 0, stream>>>(xl4, xr4, att2, bias2, offs, degree,
                                         csr_src, (float*)d_out, N);
  } else {
    // layer 0
    k_gemm2s<<<mb * 2, 256, 0, stream>>>(Agh, Agl, W0hl, W0ll, W0hr, W0lr,
                                         bl0, br0, xl, xr, N, 128, 0, 1);
    k_gat_small<<<gb, 256, 0, stream>>>(xl, xr, att0, bias0, offs, degree, csr_src,
                                        Agh, Agl, N);
    // layer 1
    k_gemm2s<<<mb * 2, 256, 0, stream>>>(Agh, Agl, W1hl, W1ll, W1hr, W1lr,
                                         bl1, br1, xl, xr, N, 128, 0, 1);
    k_gat_small<<<gb, 256, 0, stream>>>(xl, xr, att1, bias1, offs, degree, csr_src,
                                        Agh, Agl, N);
    // layer 2 per head
    for (int h = 0; h < 4; h++) {
      const int wo = h * 128 * 128;
      k_gemm2s<<<mb * 2, 256, 0, stream>>>(Agh, Agl, W2hl + wo, W2ll + wo,
                                           W2hr + wo, W2lr + wo,
                                           bl2 + h * 128, br2 + h * 128,
                                           xl, xr, N, 128, 0, 1);
      k_gat_head<<<gb, 256, 0, stream>>>(xl, xr, att2 + h * 128, bias2, offs, degree,
                                         csr_src, (float*)d_out, N,
                                         h == 0 ? 1 : 0, h == 3 ? 1 : 0);
    }
  }
}

// Round 4
// 1003.528 us; speedup vs baseline: 1.1338x; 1.1338x over previous
//
#include <hip/hip_runtime.h>
#include <hip/hip_fp16.h>
#include <cstddef>

// ---------------------------------------------------------------------------
// GATv2 backbone: 3 layers, N=100k nodes, E=1.6M edges (+self loops), H=4.
//   - CSR by dst built once (histogram + 3-kernel multi-block scan + scatter).
//   - GEMMs: split-bf16 MFMA, A pre-split, W pre-split+transposed; register
//     prefetch; r1-proven 3-D grid dispatch (r3 evidence: XCD swizzle +
//     LDS-restaged stores cut FETCH 202->27 MB and WRITE 367->225 MB yet ran
//     SLOWER - this GEMM is MFMA-pipeline-bound at ~265 TF effective, so
//     traffic optimizations don't pay; dispatch-structure r1 measured best).
//   - Layer-2 GEMM k_gemm2t: 2-TERM split ((Ah+Al)*Wh, drops Ah*Wl residual):
//     33% less MFMA work, no Wl staging (LDS 30 KB). Error ~1e-3, damped by
//     softmax. Layers 0/1 keep 3-term (errors compound across layers).
//   - Layers 0/1 gather: fp16 rows [N,128], packed-fp16 logits, fp32 value acc.
//   - Layer 2: ONE fused gather over fp16 [N,512]. r1 evidence: two different
//     schedules both sit at ~3.75 TB/s / 877 MB FETCH -> memory-path bound.
//   - One k_prep dispatch does all 6 weight splits + layer-0 A split.
// ---------------------------------------------------------------------------

typedef __attribute__((ext_vector_type(8))) short bf16x8;
typedef __attribute__((ext_vector_type(4))) float f32x4;
typedef _Float16 f16x2 __attribute__((ext_vector_type(2)));
typedef float f32x2 __attribute__((ext_vector_type(2)));

#if defined(__has_builtin)
#if __has_builtin(__builtin_amdgcn_fdot2)
#define HAS_FDOT2 1
#endif
#endif

__device__ __forceinline__ float lrelu(float x) { return fmaxf(x, 0.2f * x); }

// 16B row-fragment load at 32-bit byte offset
__device__ __forceinline__ uint4 ldrow(const void* base, unsigned byteoff) {
  return *(const uint4*)((const char*)base + byteoff);
}

// RNE fp32 -> bf16 hi + bf16 residual
__device__ __forceinline__ void split2(float x, unsigned short& h, unsigned short& l) {
  unsigned b = __float_as_uint(x);
  unsigned r = b + 0x7fffu + ((b >> 16) & 1u);
  h = (unsigned short)(r >> 16);
  float hf = __uint_as_float((unsigned)h << 16);
  float res = x - hf;
  unsigned b2 = __float_as_uint(res);
  unsigned r2 = b2 + 0x7fffu + ((b2 >> 16) & 1u);
  l = (unsigned short)(r2 >> 16);
}

// ---------------- CSR build ----------------
__global__ void k_init(int* __restrict__ degree, int* __restrict__ cursor, int N) {
  int i = blockIdx.x * blockDim.x + threadIdx.x;
  if (i < N) { degree[i] = 1; cursor[i] = 0; }  // 1 accounts for the self-loop
}

__global__ void k_hist(const int* __restrict__ ei, int E, int* __restrict__ degree) {
  int e = blockIdx.x * blockDim.x + threadIdx.x;
  if (e < E) atomicAdd(&degree[ei[E + e]], 1);
}

// --- 3-kernel scan: per-block sums -> scan of sums -> per-block scan+base ---
__global__ __launch_bounds__(256) void k_scan1(const int* __restrict__ degree,
                                               int* __restrict__ partial, int N) {
  __shared__ int ws[4];
  const int i0 = blockIdx.x * 1024 + threadIdx.x * 4;
  int s = 0;
  if (i0 + 3 < N) {
    int4 v = *(const int4*)&degree[i0];
    s = v.x + v.y + v.z + v.w;
  } else {
    #pragma unroll
    for (int k = 0; k < 4; k++) if (i0 + k < N) s += degree[i0 + k];
  }
  #pragma unroll
  for (int d = 1; d < 64; d <<= 1) s += __shfl_xor(s, d);
  const int lane = threadIdx.x & 63, wid = threadIdx.x >> 6;
  if (lane == 0) ws[wid] = s;
  __syncthreads();
  if (threadIdx.x == 0) partial[blockIdx.x] = ws[0] + ws[1] + ws[2] + ws[3];
}

__global__ __launch_bounds__(256) void k_scan2(int* __restrict__ partial, int nb) {
  __shared__ int sh[256];
  const int tid = threadIdx.x;
  int v = (tid < nb) ? partial[tid] : 0;
  sh[tid] = v;
  __syncthreads();
  for (int d = 1; d < 256; d <<= 1) {
    int t = (tid >= d) ? sh[tid - d] : 0;
    __syncthreads();
    sh[tid] += t;
    __syncthreads();
  }
  if (tid < nb) partial[tid] = sh[tid] - v;   // exclusive base per block
}

__global__ __launch_bounds__(256) void k_scan3(const int* __restrict__ degree,
                                               const int* __restrict__ partial,
                                               int* __restrict__ offs, int N) {
  __shared__ int wsum[4];
  const int tid = threadIdx.x, lane = tid & 63, wid = tid >> 6;
  const int i0 = blockIdx.x * 1024 + tid * 4;
  int v0 = 0, v1 = 0, v2 = 0, v3 = 0;
  if (i0 + 3 < N) {
    int4 v = *(const int4*)&degree[i0];
    v0 = v.x; v1 = v.y; v2 = v.z; v3 = v.w;
  } else {
    if (i0     < N) v0 = degree[i0];
    if (i0 + 1 < N) v1 = degree[i0 + 1];
    if (i0 + 2 < N) v2 = degree[i0 + 2];
    if (i0 + 3 < N) v3 = degree[i0 + 3];
  }
  int s = v0 + v1 + v2 + v3, x = s;
  #pragma unroll
  for (int d = 1; d < 64; d <<= 1) {
    int y = __shfl_up(x, d);
    if (lane >= d) x += y;
  }
  if (lane == 63) wsum[wid] = x;
  __syncthreads();
  if (tid < 4) {
    int t = wsum[tid];
    #pragma unroll
    for (int d = 1; d < 4; d <<= 1) {
      int y = __shfl_up(t, d);
      if (tid >= d) t += y;
    }
    wsum[tid] = t;
  }
  __syncthreads();
  const int wbase = wid ? wsum[wid - 1] : 0;
  int e = partial[blockIdx.x] + wbase + (x - s);
  if (i0     < N) offs[i0]     = e;  e += v0;  if (i0     == N - 1) offs[N] = e;
  if (i0 + 1 < N) offs[i0 + 1] = e;  e += v1;  if (i0 + 1 == N - 1) offs[N] = e;
  if (i0 + 2 < N) offs[i0 + 2] = e;  e += v2;  if (i0 + 2 == N - 1) offs[N] = e;
  if (i0 + 3 < N) offs[i0 + 3] = e;  e += v3;  if (i0 + 3 == N - 1) offs[N] = e;
}

__global__ void k_scatter(const int* __restrict__ ei, int E, int N,
                          const int* __restrict__ offs, int* __restrict__ cursor,
                          int* __restrict__ csr_src) {
  int t = blockIdx.x * blockDim.x + threadIdx.x;
  int ET = E + N;
  if (t >= ET) return;
  int s, d;
  if (t < E) { s = ei[t]; d = ei[E + t]; }
  else       { s = t - E; d = s; }
  int pos = offs[d] + atomicAdd(&cursor[d], 1);
  csr_src[pos] = s;
}

// ---- ONE prep dispatch: split+transpose all 6 weights, split layer-0 A -----
// weight elems: Wl0/Wr0/Wl1/Wr1 16384 each, Wl2/Wr2 65536 each = 196608 total.
__global__ __launch_bounds__(256) void k_prep(
    const float* __restrict__ Wl0, const float* __restrict__ Wr0,
    const float* __restrict__ Wl1, const float* __restrict__ Wr1,
    const float* __restrict__ Wl2, const float* __restrict__ Wr2,
    unsigned short* __restrict__ W0hl, unsigned short* __restrict__ W0ll,
    unsigned short* __restrict__ W0hr, unsigned short* __restrict__ W0lr,
    unsigned short* __restrict__ W1hl, unsigned short* __restrict__ W1ll,
    unsigned short* __restrict__ W1hr, unsigned short* __restrict__ W1lr,
    unsigned short* __restrict__ W2hl, unsigned short* __restrict__ W2ll,
    unsigned short* __restrict__ W2hr, unsigned short* __restrict__ W2lr,
    const float* __restrict__ X,
    unsigned short* __restrict__ Ah, unsigned short* __restrict__ Al, int totalA) {
  const int t = blockIdx.x * blockDim.x + threadIdx.x;
  if (t < 196608) {
    const float* W; unsigned short *Whp, *Wlp; int idx, sh;
    if (t < 16384)       { W = Wl0; Whp = W0hl; Wlp = W0ll; idx = t;          sh = 7; }
    else if (t < 32768)  { W = Wr0; Whp = W0hr; Wlp = W0lr; idx = t - 16384;  sh = 7; }
    else if (t < 49152)  { W = Wl1; Whp = W1hl; Wlp = W1ll; idx = t - 32768;  sh = 7; }
    else if (t < 65536)  { W = Wr1; Whp = W1hr; Wlp = W1lr; idx = t - 49152;  sh = 7; }
    else if (t < 131072) { W = Wl2; Whp = W2hl; Wlp = W2ll; idx = t - 65536;  sh = 9; }
    else                 { W = Wr2; Whp = W2hr; Wlp = W2lr; idx = t - 131072; sh = 9; }
    const int n = idx & ((1 << sh) - 1), k = idx >> sh;
    unsigned short h, l;
    split2(W[idx], h, l);
    Whp[(size_t)n * 128 + k] = h;
    Wlp[(size_t)n * 128 + k] = l;
    return;
  }
  const int t4 = (t - 196608) * 4;
  if (t4 >= totalA) return;
  float4 v = *(const float4*)&X[t4];
  unsigned short h0, h1, h2, h3, l0, l1, l2, l3;
  split2(v.x, h0, l0); split2(v.y, h1, l1);
  split2(v.z, h2, l2); split2(v.w, h3, l3);
  uint2 hv, lv;
  hv.x = (unsigned)h0 | ((unsigned)h1 << 16);
  hv.y = (unsigned)h2 | ((unsigned)h3 << 16);
  lv.x = (unsigned)l0 | ((unsigned)l1 << 16);
  lv.y = (unsigned)l2 | ((unsigned)l3 << 16);
  *(uint2*)&Ah[t4] = hv;
  *(uint2*)&Al[t4] = lv;
}

// ---------------- split-bf16 MFMA GEMM (3-term), dual projection ------------
// r1-proven dispatch: blockIdx.y = l/r, blockIdx.z = head slice. Register
// prefetch of next K-chunk during MFMA. Scalar stores.
__global__ __launch_bounds__(256) void k_gemm2s(
    const unsigned short* __restrict__ Agh, const unsigned short* __restrict__ Agl,
    const unsigned short* __restrict__ Whl, const unsigned short* __restrict__ Wll,
    const unsigned short* __restrict__ Whr, const unsigned short* __restrict__ Wlr,
    const float* __restrict__ bias_l, const float* __restrict__ bias_r,
    void* __restrict__ Clp, void* __restrict__ Crp, int N,
    int ldC, int coloff, int out_half) {
  __shared__ unsigned short Ah_s[128][40];   // row pad 40 (80 B = 5 superbanks)
  __shared__ unsigned short Al_s[128][40];
  __shared__ unsigned short Wh_s[128][40];
  __shared__ unsigned short Wl_s[128][40];
  const int hsel = blockIdx.z;
  const unsigned short* __restrict__ Wth = (blockIdx.y ? Whr : Whl) + hsel * 128 * 128;
  const unsigned short* __restrict__ Wtl = (blockIdx.y ? Wlr : Wll) + hsel * 128 * 128;
  const float* __restrict__ bias = (blockIdx.y ? bias_r : bias_l) + hsel * 128;
  void* __restrict__ Cp = blockIdx.y ? Crp : Clp;
  coloff += hsel * 128;

  const int tid = threadIdx.x;
  const int m0 = blockIdx.x * 128;
  const int wv = tid >> 6, lane = tid & 63;
  const int wm = (wv >> 1) * 64, wn = (wv & 1) * 64;
  const int l15 = lane & 15, kb = (lane >> 4) * 8;
  f32x4 acc[4][4] = {};

  const int r = tid >> 1;              // staging row 0..127
  const int cb = (tid & 1) * 16;       // staging col base 0/16
  const bool arow_ok = (m0 + r) < N;
  const unsigned short* ahp = Agh + (size_t)(m0 + r) * 128 + cb;
  const unsigned short* alp = Agl + (size_t)(m0 + r) * 128 + cb;
  const unsigned short* whp = Wth + r * 128 + cb;
  const unsigned short* wlp = Wtl + r * 128 + cb;
  const uint4 z4 = make_uint4(0, 0, 0, 0);

  uint4 pa0, pa1, pl0, pl1, pw0, pw1, pq0, pq1;
  #define LOADC(K0)                                                           \
    pa0 = arow_ok ? *(const uint4*)(ahp + (K0))     : z4;                     \
    pa1 = arow_ok ? *(const uint4*)(ahp + (K0) + 8) : z4;                     \
    pl0 = arow_ok ? *(const uint4*)(alp + (K0))     : z4;                     \
    pl1 = arow_ok ? *(const uint4*)(alp + (K0) + 8) : z4;                     \
    pw0 = *(const uint4*)(whp + (K0));                                        \
    pw1 = *(const uint4*)(whp + (K0) + 8);                                    \
    pq0 = *(const uint4*)(wlp + (K0));                                        \
    pq1 = *(const uint4*)(wlp + (K0) + 8);
  LOADC(0)
  for (int kc = 0; kc < 4; kc++) {
    *(uint4*)&Ah_s[r][cb]     = pa0;
    *(uint4*)&Ah_s[r][cb + 8] = pa1;
    *(uint4*)&Al_s[r][cb]     = pl0;
    *(uint4*)&Al_s[r][cb + 8] = pl1;
    *(uint4*)&Wh_s[r][cb]     = pw0;
    *(uint4*)&Wh_s[r][cb + 8] = pw1;
    *(uint4*)&Wl_s[r][cb]     = pq0;
    *(uint4*)&Wl_s[r][cb + 8] = pq1;
    __syncthreads();
    if (kc < 3) { LOADC((kc + 1) * 32) }   // in flight during MFMA below

    bf16x8 afh[4], afl[4];
    #pragma unroll
    for (int mi = 0; mi < 4; mi++) {
      const int row = wm + mi * 16 + l15;
      afh[mi] = *(const bf16x8*)&Ah_s[row][kb];
      afl[mi] = *(const bf16x8*)&Al_s[row][kb];
    }
    #pragma unroll
    for (int ni = 0; ni < 4; ni++) {
      const int rown = wn + ni * 16 + l15;
      bf16x8 bh = *(const bf16x8*)&Wh_s[rown][kb];
      bf16x8 bl = *(const bf16x8*)&Wl_s[rown][kb];
      #pragma unroll
      for (int mi = 0; mi < 4; mi++) {
        acc[mi][ni] = __builtin_amdgcn_mfma_f32_16x16x32_bf16(afh[mi], bh, acc[mi][ni], 0, 0, 0);
        acc[mi][ni] = __builtin_amdgcn_mfma_f32_16x16x32_bf16(afl[mi], bh, acc[mi][ni], 0, 0, 0);
        acc[mi][ni] = __builtin_amdgcn_mfma_f32_16x16x32_bf16(afh[mi], bl, acc[mi][ni], 0, 0, 0);
      }
    }
    __syncthreads();
  }
  #undef LOADC
  const int col = l15, rbase = (lane >> 4) * 4;
  #pragma unroll
  for (int ni = 0; ni < 4; ni++) {
    const int gn = wn + ni * 16 + col;
    const float bv = bias[gn];
    #pragma unroll
    for (int mi = 0; mi < 4; mi++) {
      #pragma unroll
      for (int q = 0; q < 4; q++) {
        const int gm = m0 + wm + mi * 16 + rbase + q;
        if (gm < N) {
          float v = acc[mi][ni][q] + bv;
          if (out_half) ((__half*)Cp)[(size_t)gm * ldC + coloff + gn] = __float2half(v);
          else          ((float*)Cp)[(size_t)gm * ldC + coloff + gn] = v;
        }
      }
    }
  }
}

// ---------------- layer-2 GEMM: 2-TERM split ((Ah+Al)*Wh), fp16 out ---------
// Drops the Ah*Wl residual (error ~1e-3, softmax-damped; final layer only).
// 33% fewer MFMA, no Wl staging (LDS 30 KB -> 5 blocks/CU possible).
__global__ __launch_bounds__(256) void k_gemm2t(
    const unsigned short* __restrict__ Agh, const unsigned short* __restrict__ Agl,
    const unsigned short* __restrict__ Whl, const unsigned short* __restrict__ Whr,
    const float* __restrict__ bias_l, const float* __restrict__ bias_r,
    __half* __restrict__ Clp, __half* __restrict__ Crp, int N) {
  __shared__ unsigned short Ah_s[128][40];
  __shared__ unsigned short Al_s[128][40];
  __shared__ unsigned short Wh_s[128][40];
  const int hsel = blockIdx.z;
  const unsigned short* __restrict__ Wth = (blockIdx.y ? Whr : Whl) + hsel * 128 * 128;
  const float* __restrict__ bias = (blockIdx.y ? bias_r : bias_l) + hsel * 128;
  __half* __restrict__ Cp = blockIdx.y ? Crp : Clp;
  const int coloff = hsel * 128;

  const int tid = threadIdx.x;
  const int m0 = blockIdx.x * 128;
  const int wv = tid >> 6, lane = tid & 63;
  const int wm = (wv >> 1) * 64, wn = (wv & 1) * 64;
  const int l15 = lane & 15, kb = (lane >> 4) * 8;
  f32x4 acc[4][4] = {};

  const int r = tid >> 1;              // staging row 0..127
  const int cb = (tid & 1) * 16;       // staging col base 0/16
  const bool arow_ok = (m0 + r) < N;
  const unsigned short* ahp = Agh + (size_t)(m0 + r) * 128 + cb;
  const unsigned short* alp = Agl + (size_t)(m0 + r) * 128 + cb;
  const unsigned short* whp = Wth + r * 128 + cb;
  const uint4 z4 = make_uint4(0, 0, 0, 0);

  uint4 pa0, pa1, pl0, pl1, pw0, pw1;
  #define LOADT(K0)                                                           \
    pa0 = arow_ok ? *(const uint4*)(ahp + (K0))     : z4;                     \
    pa1 = arow_ok ? *(const uint4*)(ahp + (K0) + 8) : z4;                     \
    pl0 = arow_ok ? *(const uint4*)(alp + (K0))     : z4;                     \
    pl1 = arow_ok ? *(const uint4*)(alp + (K0) + 8) : z4;                     \
    pw0 = *(const uint4*)(whp + (K0));                                        \
    pw1 = *(const uint4*)(whp + (K0) + 8);
  LOADT(0)
  for (int kc = 0; kc < 4; kc++) {
    *(uint4*)&Ah_s[r][cb]     = pa0;
    *(uint4*)&Ah_s[r][cb + 8] = pa1;
    *(uint4*)&Al_s[r][cb]     = pl0;
    *(uint4*)&Al_s[r][cb + 8] = pl1;
    *(uint4*)&Wh_s[r][cb]     = pw0;
    *(uint4*)&Wh_s[r][cb + 8] = pw1;
    __syncthreads();
    if (kc < 3) { LOADT((kc + 1) * 32) }   // in flight during MFMA below

    bf16x8 afh[4], afl[4];
    #pragma unroll
    for (int mi = 0; mi < 4; mi++) {
      const int row = wm + mi * 16 + l15;
      afh[mi] = *(const bf16x8*)&Ah_s[row][kb];
      afl[mi] = *(const bf16x8*)&Al_s[row][kb];
    }
    #pragma unroll
    for (int ni = 0; ni < 4; ni++) {
      const int rown = wn + ni * 16 + l15;
      bf16x8 bh = *(const bf16x8*)&Wh_s[rown][kb];
      #pragma unroll
      for (int mi = 0; mi < 4; mi++) {
        acc[mi][ni] = __builtin_amdgcn_mfma_f32_16x16x32_bf16(afh[mi], bh, acc[mi][ni], 0, 0, 0);
        acc[mi][ni] = __builtin_amdgcn_mfma_f32_16x16x32_bf16(afl[mi], bh, acc[mi][ni], 0, 0, 0);
      }
    }
    __syncthreads();
  }
  #undef LOADT
  const int col = l15, rbase = (lane >> 4) * 4;
  #pragma unroll
  for (int ni = 0; ni < 4; ni++) {
    const int gn = wn + ni * 16 + col;
    const float bv = bias[gn];
    #pragma unroll
    for (int mi = 0; mi < 4; mi++) {
      #pragma unroll
      for (int q = 0; q < 4; q++) {
        const int gm = m0 + wm + mi * 16 + rbase + q;
        if (gm < N)
          Cp[(size_t)gm * 512 + coloff + gn] = __float2half(acc[mi][ni][q] + bv);
      }
    }
  }
}

// -------- butterfly ADD merge of per-group partials (plain-exp softmax) -----
#define MERGE_ADD(d)                                                          \
  {                                                                           \
    l += __shfl_xor(l, d);                                                    \
    aca.x += __shfl_xor(aca.x, d); aca.y += __shfl_xor(aca.y, d);             \
    aca.z += __shfl_xor(aca.z, d); aca.w += __shfl_xor(aca.w, d);             \
    acb.x += __shfl_xor(acb.x, d); acb.y += __shfl_xor(acb.y, d);             \
    acb.z += __shfl_xor(acb.z, d); acb.w += __shfl_xor(acb.w, d);             \
  }

// ---------------- fused GATv2 gather, layers 0/1 (fp32 fallback) ------------
__global__ __launch_bounds__(256) void k_gat_small(
    const float* __restrict__ xl, const float* __restrict__ xr,
    const float* __restrict__ att, const float* __restrict__ bias,
    const int* __restrict__ offs, const int* __restrict__ degree,
    const int* __restrict__ csr_src,
    unsigned short* __restrict__ Ah, unsigned short* __restrict__ Al, int N) {
  const int node = blockIdx.x * 4 + (threadIdx.x >> 6);
  if (node >= N) return;
  const int lane = threadIdx.x & 63;
  const int g = lane >> 4;
  const int c = lane & 15;
  const int d0 = c * 8;
  const size_t nb = (size_t)node * 128 + d0;
  const float4 xra = *(const float4*)&xr[nb];
  const float4 xrb = *(const float4*)&xr[nb + 4];
  const float4 ata = *(const float4*)&att[d0];
  const float4 atb = *(const float4*)&att[d0 + 4];
  const int off = offs[node];
  const int deg = degree[node];
  float l = 0.f;
  float4 aca = make_float4(0.f, 0.f, 0.f, 0.f);
  float4 acb = make_float4(0.f, 0.f, 0.f, 0.f);
  int s0 = (g < deg) ? csr_src[off + g] : 0;
  int s1 = (g + 4 < deg) ? csr_src[off + g + 4] : 0;
  for (int j = g; j < deg; j += 8) {
    int sn0 = (j + 8 < deg) ? csr_src[off + j + 8] : 0;
    int sn1 = (j + 12 < deg) ? csr_src[off + j + 12] : 0;
    const size_t sb0 = (size_t)s0 * 128 + d0;
    const size_t sb1 = (size_t)s1 * 128 + d0;
    float4 xa0 = *(const float4*)&xl[sb0];
    float4 xb0 = *(const float4*)&xl[sb0 + 4];
    float4 xa1 = *(const float4*)&xl[sb1];
    float4 xb1 = *(const float4*)&xl[sb1 + 4];
    float t0 = lrelu(xa0.x + xra.x) * ata.x + lrelu(xa0.y + xra.y) * ata.y +
               lrelu(xa0.z + xra.z) * ata.z + lrelu(xa0.w + xra.w) * ata.w +
               lrelu(xb0.x + xrb.x) * atb.x + lrelu(xb0.y + xrb.y) * atb.y +
               lrelu(xb0.z + xrb.z) * atb.z + lrelu(xb0.w + xrb.w) * atb.w;
    float t1 = lrelu(xa1.x + xra.x) * ata.x + lrelu(xa1.y + xra.y) * ata.y +
               lrelu(xa1.z + xra.z) * ata.z + lrelu(xa1.w + xra.w) * ata.w +
               lrelu(xb1.x + xrb.x) * atb.x + lrelu(xb1.y + xrb.y) * atb.y +
               lrelu(xb1.z + xrb.z) * atb.z + lrelu(xb1.w + xrb.w) * atb.w;
    t0 += __shfl_xor(t0, 1);
    t0 += __shfl_xor(t0, 2);       // 4-lane head cluster -> per-head logit
    t1 += __shfl_xor(t1, 1);
    t1 += __shfl_xor(t1, 2);
    float p0 = __expf(t0);
    float p1 = (j + 4 < deg) ? __expf(t1) : 0.f;
    aca.x += p0 * xa0.x + p1 * xa1.x; aca.y += p0 * xa0.y + p1 * xa1.y;
    aca.z += p0 * xa0.z + p1 * xa1.z; aca.w += p0 * xa0.w + p1 * xa1.w;
    acb.x += p0 * xb0.x + p1 * xb1.x; acb.y += p0 * xb0.y + p1 * xb1.y;
    acb.z += p0 * xb0.z + p1 * xb1.z; acb.w += p0 * xb0.w + p1 * xb1.w;
    l += p0 + p1;
    s0 = sn0; s1 = sn1;
  }
  MERGE_ADD(16)
  MERGE_ADD(32)
  if (lane < 16) {
    const float inv = 1.f / l;
    const float4 b0 = *(const float4*)&bias[d0];
    const float4 b1 = *(const float4*)&bias[d0 + 4];
    float o[8] = {aca.x * inv + b0.x, aca.y * inv + b0.y,
                  aca.z * inv + b0.z, aca.w * inv + b0.w,
                  acb.x * inv + b1.x, acb.y * inv + b1.y,
                  acb.z * inv + b1.z, acb.w * inv + b1.w};
    unsigned short hs[8], ls[8];
    #pragma unroll
    for (int i = 0; i < 8; i++) {
      o[i] = o[i] > 0.f ? o[i] : __expf(o[i]) - 1.f;   // ELU
      split2(o[i], hs[i], ls[i]);
    }
    uint4 hv, lv;
    hv.x = (unsigned)hs[0] | ((unsigned)hs[1] << 16);
    hv.y = (unsigned)hs[2] | ((unsigned)hs[3] << 16);
    hv.z = (unsigned)hs[4] | ((unsigned)hs[5] << 16);
    hv.w = (unsigned)hs[6] | ((unsigned)hs[7] << 16);
    lv.x = (unsigned)ls[0] | ((unsigned)ls[1] << 16);
    lv.y = (unsigned)ls[2] | ((unsigned)ls[3] << 16);
    lv.z = (unsigned)ls[4] | ((unsigned)ls[5] << 16);
    lv.w = (unsigned)ls[6] | ((unsigned)ls[7] << 16);
    *(uint4*)&Ah[nb] = hv;
    *(uint4*)&Al[nb] = lv;
  }
}

// ---------------- packed-fp16 edge steps ------------------------------------
// 512-wide (layer 2): 16-lane head group reduce (4 shfl)
__device__ __forceinline__ void edge_step(uint4 vv, bool valid,
                                          const f16x2* xrh, const f16x2* ath,
                                          f32x2* accv, float& l) {
  union { uint4 u; f16x2 h[4]; } xu; xu.u = vv;
  const f16x2 c02 = {(_Float16)0.2f, (_Float16)0.2f};
  float t = 0.f;
#if defined(HAS_FDOT2)
  #pragma unroll
  for (int i = 0; i < 4; i++) {
    f16x2 s = xu.h[i] + xrh[i];
    f16x2 lr = __builtin_elementwise_max(s, s * c02);
    t = __builtin_amdgcn_fdot2(lr, ath[i], t, false);
  }
#else
  #pragma unroll
  for (int i = 0; i < 4; i++) {
    f32x2 s = __builtin_convertvector(xu.h[i], f32x2) +
              __builtin_convertvector(xrh[i], f32x2);
    f32x2 a = __builtin_convertvector(ath[i], f32x2);
    t += fmaxf(s.x, 0.2f * s.x) * a.x + fmaxf(s.y, 0.2f * s.y) * a.y;
  }
#endif
  t += __shfl_xor(t, 1);
  t += __shfl_xor(t, 2);
  t += __shfl_xor(t, 4);
  t += __shfl_xor(t, 8);         // 16-lane head group -> head logit
  float p = valid ? __expf(t) : 0.f;
  l += p;
  f32x2 p2 = {p, p};
  #pragma unroll
  for (int i = 0; i < 4; i++)
    accv[i] += p2 * __builtin_convertvector(xu.h[i], f32x2);  // v_pk_fma_f32
}

// 128-wide (layers 0/1): 4-lane head cluster reduce (2 shfl), all edges valid
__device__ __forceinline__ void edge_step_small(uint4 vv,
                                                const f16x2* xrh, const f16x2* ath,
                                                f32x2* accv, float& l) {
  union { uint4 u; f16x2 h[4]; } xu; xu.u = vv;
  const f16x2 c02 = {(_Float16)0.2f, (_Float16)0.2f};
  float t = 0.f;
#if defined(HAS_FDOT2)
  #pragma unroll
  for (int i = 0; i < 4; i++) {
    f16x2 s = xu.h[i] + xrh[i];
    f16x2 lr = __builtin_elementwise_max(s, s * c02);
    t = __builtin_amdgcn_fdot2(lr, ath[i], t, false);
  }
#else
  #pragma unroll
  for (int i = 0; i < 4; i++) {
    f32x2 s = __builtin_convertvector(xu.h[i], f32x2) +
              __builtin_convertvector(xrh[i], f32x2);
    f32x2 a = __builtin_convertvector(ath[i], f32x2);
    t += fmaxf(s.x, 0.2f * s.x) * a.x + fmaxf(s.y, 0.2f * s.y) * a.y;
  }
#endif
  t += __shfl_xor(t, 1);
  t += __shfl_xor(t, 2);         // 4-lane head cluster -> per-head logit
  float p = __expf(t);
  l += p;
  f32x2 p2 = {p, p};
  #pragma unroll
  for (int i = 0; i < 4; i++)
    accv[i] += p2 * __builtin_convertvector(xu.h[i], f32x2);
}

// ---------------- layers 0/1 gather over fp16 [N,128] -----------------------
__global__ __launch_bounds__(256) void k_gat_small16(
    const __half* __restrict__ xl, const __half* __restrict__ xr,
    const float* __restrict__ att, const float* __restrict__ bias,
    const int* __restrict__ offs, const int* __restrict__ degree,
    const int* __restrict__ csr_src,
    unsigned short* __restrict__ Ah, unsigned short* __restrict__ Al, int N) {
  const int node = blockIdx.x * 4 + (threadIdx.x >> 6);
  if (node >= N) return;
  const int lane = threadIdx.x & 63;
  const int g = lane >> 4;        // edge slot
  const int c = lane & 15;        // channel group (8 ch)
  const int d0 = c * 8;
  f16x2 xrh[4], ath[4];
  {
    union { uint4 u; f16x2 h[4]; } ru;
    ru.u = *(const uint4*)&xr[(size_t)node * 128 + d0];
    float4 a0 = *(const float4*)&att[d0];
    float4 a1 = *(const float4*)&att[d0 + 4];
    #pragma unroll
    for (int i = 0; i < 4; i++) xrh[i] = ru.h[i];
    ath[0] = (f16x2){(_Float16)a0.x, (_Float16)a0.y};
    ath[1] = (f16x2){(_Float16)a0.z, (_Float16)a0.w};
    ath[2] = (f16x2){(_Float16)a1.x, (_Float16)a1.y};
    ath[3] = (f16x2){(_Float16)a1.z, (_Float16)a1.w};
  }
  const int off = offs[node];
  const int deg = degree[node];
  const unsigned lb = (unsigned)d0 * 2u;        // byte offset in 256 B row
  f32x2 accv[4] = {};
  float l = 0.f;
  int ia = (g < deg)     ? csr_src[off + g]     : 0;
  int ib = (g + 4 < deg) ? csr_src[off + g + 4] : 0;
  int ic = (g + 8 < deg) ? csr_src[off + g + 8] : 0;
  uint4 v0 = make_uint4(0, 0, 0, 0), v1 = v0;
  if (g < deg)     v0 = ldrow(xl, (unsigned)ia * 256u + lb);
  if (g + 4 < deg) v1 = ldrow(xl, (unsigned)ib * 256u + lb);
  for (int j = g; j < deg; j += 4) {
    uint4 vn = v0;
    if (j + 8 < deg) vn = ldrow(xl, (unsigned)ic * 256u + lb);
    int id = (j + 12 < deg) ? csr_src[off + j + 12] : 0;
    edge_step_small(v0, xrh, ath, accv, l);
    v0 = v1; v1 = vn; ic = id;
  }
  // merge the 4 slots (lanes differ in bits 4-5)
  #pragma unroll
  for (int d = 16; d < 64; d <<= 1) {
    l += __shfl_xor(l, d);
    #pragma unroll
    for (int i = 0; i < 4; i++) {
      accv[i].x += __shfl_xor(accv[i].x, d);
      accv[i].y += __shfl_xor(accv[i].y, d);
    }
  }
  if (lane < 16) {
    const float inv = 1.f / l;
    const float4 b0 = *(const float4*)&bias[d0];
    const float4 b1 = *(const float4*)&bias[d0 + 4];
    float o[8] = {accv[0].x * inv + b0.x, accv[0].y * inv + b0.y,
                  accv[1].x * inv + b0.z, accv[1].y * inv + b0.w,
                  accv[2].x * inv + b1.x, accv[2].y * inv + b1.y,
                  accv[3].x * inv + b1.z, accv[3].y * inv + b1.w};
    unsigned short hs[8], ls[8];
    #pragma unroll
    for (int i = 0; i < 8; i++) {
      o[i] = o[i] > 0.f ? o[i] : __expf(o[i]) - 1.f;   // ELU
      split2(o[i], hs[i], ls[i]);
    }
    uint4 hv, lv;
    hv.x = (unsigned)hs[0] | ((unsigned)hs[1] << 16);
    hv.y = (unsigned)hs[2] | ((unsigned)hs[3] << 16);
    hv.z = (unsigned)hs[4] | ((unsigned)hs[5] << 16);
    hv.w = (unsigned)hs[6] | ((unsigned)hs[7] << 16);
    lv.x = (unsigned)ls[0] | ((unsigned)ls[1] << 16);
    lv.y = (unsigned)ls[2] | ((unsigned)ls[3] << 16);
    lv.z = (unsigned)ls[4] | ((unsigned)ls[5] << 16);
    lv.w = (unsigned)ls[6] | ((unsigned)ls[7] << 16);
    const size_t nb = (size_t)node * 128 + d0;
    *(uint4*)&Ah[nb] = hv;
    *(uint4*)&Al[nb] = lv;
  }
}

// ---------------- layer 2 FUSED gather: rotating prefetch -------------------
__global__ __launch_bounds__(256) void k_gat_fused4(
    const __half* __restrict__ xl4, const __half* __restrict__ xr4,
    const float* __restrict__ att2, const float* __restrict__ bias,
    const int* __restrict__ offs, const int* __restrict__ degree,
    const int* __restrict__ csr_src, float* __restrict__ out, int N) {
  const int node = blockIdx.x * 4 + (threadIdx.x >> 6);
  if (node >= N) return;
  const int lane = threadIdx.x & 63;
  f16x2 xrh[4], ath[4];
  {
    union { uint4 u; f16x2 h[4]; } ru;
    ru.u = *(const uint4*)&xr4[(size_t)node * 512 + lane * 8];
    float4 a0 = *(const float4*)&att2[lane * 8];
    float4 a1 = *(const float4*)&att2[lane * 8 + 4];
    #pragma unroll
    for (int i = 0; i < 4; i++) xrh[i] = ru.h[i];
    ath[0] = (f16x2){(_Float16)a0.x, (_Float16)a0.y};
    ath[1] = (f16x2){(_Float16)a0.z, (_Float16)a0.w};
    ath[2] = (f16x2){(_Float16)a1.x, (_Float16)a1.y};
    ath[3] = (f16x2){(_Float16)a1.z, (_Float16)a1.w};
  }
  const int off = offs[node];
  const int deg = degree[node];
  const unsigned lb = (unsigned)lane * 16u;     // byte offset in 1 KB row
  f32x2 accv[4] = {};
  float l = 0.f;
  int s0 = csr_src[off];
  int s1 = (1 < deg) ? csr_src[off + 1] : 0;
  int s2 = (2 < deg) ? csr_src[off + 2] : 0;
  int s3 = (3 < deg) ? csr_src[off + 3] : 0;
  uint4 v0 = ldrow(xl4, (unsigned)s0 * 1024u + lb);
  uint4 v1 = (1 < deg) ? ldrow(xl4, (unsigned)s1 * 1024u + lb) : v0;
  uint4 v2 = (2 < deg) ? ldrow(xl4, (unsigned)s2 * 1024u + lb) : v0;
  uint4 v3 = (3 < deg) ? ldrow(xl4, (unsigned)s3 * 1024u + lb) : v0;
  s0 = (4 < deg) ? csr_src[off + 4] : 0;        // indices one iter ahead
  s1 = (5 < deg) ? csr_src[off + 5] : 0;
  s2 = (6 < deg) ? csr_src[off + 6] : 0;
  s3 = (7 < deg) ? csr_src[off + 7] : 0;
  for (int j = 0; j < deg; j += 4) {
    edge_step(v0, true, xrh, ath, accv, l);     // j < deg guaranteed
    if (j + 4 < deg) v0 = ldrow(xl4, (unsigned)s0 * 1024u + lb);
    s0 = (j + 8 < deg) ? csr_src[off + j + 8] : 0;
    edge_step(v1, j + 1 < deg, xrh, ath, accv, l);
    if (j + 5 < deg) v1 = ldrow(xl4, (unsigned)s1 * 1024u + lb);
    s1 = (j + 9 < deg) ? csr_src[off + j + 9] : 0;
    edge_step(v2, j + 2 < deg, xrh, ath, accv, l);
    if (j + 6 < deg) v2 = ldrow(xl4, (unsigned)s2 * 1024u + lb);
    s2 = (j + 10 < deg) ? csr_src[off + j + 10] : 0;
    edge_step(v3, j + 3 < deg, xrh, ath, accv, l);
    if (j + 7 < deg) v3 = ldrow(xl4, (unsigned)s3 * 1024u + lb);
    s3 = (j + 11 < deg) ? csr_src[off + j + 11] : 0;
  }
  // scale by own head's softmax-mean weight, then sum heads via butterfly
  const float w = 0.25f / l;
  const f32x2 w2 = {w, w};
  #pragma unroll
  for (int i = 0; i < 4; i++) accv[i] *= w2;
  #pragma unroll
  for (int d = 16; d < 64; d <<= 1) {
    #pragma unroll
    for (int i = 0; i < 4; i++) {
      accv[i].x += __shfl_xor(accv[i].x, d);
      accv[i].y += __shfl_xor(accv[i].y, d);
    }
  }
  if (lane < 16) {
    const int d0 = lane * 8;
    float4 b0 = *(const float4*)&bias[d0];
    float4 b1 = *(const float4*)&bias[d0 + 4];
    float* op = &out[(size_t)node * 128 + d0];
    *(float4*)op       = make_float4(accv[0].x + b0.x, accv[0].y + b0.y,
                                     accv[1].x + b0.z, accv[1].y + b0.w);
    *(float4*)(op + 4) = make_float4(accv[2].x + b1.x, accv[2].y + b1.y,
                                     accv[3].x + b1.z, accv[3].y + b1.w);
  }
}

// ---------------- fallback: layer 2 per-head fp32 gather --------------------
__global__ __launch_bounds__(256) void k_gat_head(
    const float* __restrict__ xl, const float* __restrict__ xr,
    const float* __restrict__ att_h, const float* __restrict__ bias,
    const int* __restrict__ offs, const int* __restrict__ degree,
    const int* __restrict__ csr_src, float* __restrict__ out, int N,
    int first, int last) {
  const int node = blockIdx.x * 4 + (threadIdx.x >> 6);
  if (node >= N) return;
  const int lane = threadIdx.x & 63;
  const int g = lane >> 4;
  const int c = lane & 15;
  const int d0 = c * 8;
  const size_t nb = (size_t)node * 128 + d0;
  const float4 xra = *(const float4*)&xr[nb];
  const float4 xrb = *(const float4*)&xr[nb + 4];
  const float4 ata = *(const float4*)&att_h[d0];
  const float4 atb = *(const float4*)&att_h[d0 + 4];
  const int off = offs[node];
  const int deg = degree[node];
  float l = 0.f;
  float4 aca = make_float4(0.f, 0.f, 0.f, 0.f);
  float4 acb = make_float4(0.f, 0.f, 0.f, 0.f);
  int s0 = (g < deg) ? csr_src[off + g] : 0;
  int s1 = (g + 4 < deg) ? csr_src[off + g + 4] : 0;
  for (int j = g; j < deg; j += 8) {
    int sn0 = (j + 8 < deg) ? csr_src[off + j + 8] : 0;
    int sn1 = (j + 12 < deg) ? csr_src[off + j + 12] : 0;
    const size_t sb0 = (size_t)s0 * 128 + d0;
    const size_t sb1 = (size_t)s1 * 128 + d0;
    float4 xa0 = *(const float4*)&xl[sb0];
    float4 xb0 = *(const float4*)&xl[sb0 + 4];
    float4 xa1 = *(const float4*)&xl[sb1];
    float4 xb1 = *(const float4*)&xl[sb1 + 4];
    float t0 = lrelu(xa0.x + xra.x) * ata.x + lrelu(xa0.y + xra.y) * ata.y +
               lrelu(xa0.z + xra.z) * ata.z + lrelu(xa0.w + xra.w) * ata.w +
               lrelu(xb0.x + xrb.x) * atb.x + lrelu(xb0.y + xrb.y) * atb.y +
               lrelu(xb0.z + xrb.z) * atb.z + lrelu(xb0.w + xrb.w) * atb.w;
    float t1 = lrelu(xa1.x + xra.x) * ata.x + lrelu(xa1.y + xra.y) * ata.y +
               lrelu(xa1.z + xra.z) * ata.z + lrelu(xa1.w + xra.w) * ata.w +
               lrelu(xb1.x + xrb.x) * atb.x + lrelu(xb1.y + xrb.y) * atb.y +
               lrelu(xb1.z + xrb.z) * atb.z + lrelu(xb1.w + xrb.w) * atb.w;
    t0 += __shfl_xor(t0, 1);
    t0 += __shfl_xor(t0, 2);
    t0 += __shfl_xor(t0, 4);
    t0 += __shfl_xor(t0, 8);
    t1 += __shfl_xor(t1, 1);
    t1 += __shfl_xor(t1, 2);
    t1 += __shfl_xor(t1, 4);
    t1 += __shfl_xor(t1, 8);
    float p0 = __expf(t0);
    float p1 = (j + 4 < deg) ? __expf(t1) : 0.f;
    aca.x += p0 * xa0.x + p1 * xa1.x; aca.y += p0 * xa0.y + p1 * xa1.y;
    aca.z += p0 * xa0.z + p1 * xa1.z; aca.w += p0 * xa0.w + p1 * xa1.w;
    acb.x += p0 * xb0.x + p1 * xb1.x; acb.y += p0 * xb0.y + p1 * xb1.y;
    acb.z += p0 * xb0.z + p1 * xb1.z; acb.w += p0 * xb0.w + p1 * xb1.w;
    l += p0 + p1;
    s0 = sn0; s1 = sn1;
  }
  MERGE_ADD(16)
  MERGE_ADD(32)
  if (lane < 16) {
    const float inv = 0.25f / l;
    float o[8] = {aca.x * inv, aca.y * inv, aca.z * inv, aca.w * inv,
                  acb.x * inv, acb.y * inv, acb.z * inv, acb.w * inv};
    float* op = &out[nb];
    if (!first) {
      float4 p0 = *(const float4*)op;
      float4 p1 = *(const float4*)(op + 4);
      o[0] += p0.x; o[1] += p0.y; o[2] += p0.z; o[3] += p0.w;
      o[4] += p1.x; o[5] += p1.y; o[6] += p1.z; o[7] += p1.w;
    }
    if (last) {
      float4 b0 = *(const float4*)&bias[d0];
      float4 b1 = *(const float4*)&bias[d0 + 4];
      o[0] += b0.x; o[1] += b0.y; o[2] += b0.z; o[3] += b0.w;
      o[4] += b1.x; o[5] += b1.y; o[6] += b1.z; o[7] += b1.w;
    }
    *(float4*)op       = make_float4(o[0], o[1], o[2], o[3]);
    *(float4*)(op + 4) = make_float4(o[4], o[5], o[6], o[7]);
  }
}

// ---------------------------------------------------------------------------
extern "C" void kernel_launch(void* const* d_in, const int* in_sizes, int n_in,
                              void* d_out, int out_size, void* d_ws, size_t ws_size,
                              hipStream_t stream) {
  const float* x     = (const float*)d_in[0];
  const int*   ei    = (const int*)  d_in[1];
  const float* Wl0   = (const float*)d_in[2];
  const float* bl0   = (const float*)d_in[3];
  const float* Wr0   = (const float*)d_in[4];
  const float* br0   = (const float*)d_in[5];
  const float* att0  = (const float*)d_in[6];
  const float* bias0 = (const float*)d_in[7];
  const float* Wl1   = (const float*)d_in[8];
  const float* bl1   = (const float*)d_in[9];
  const float* Wr1   = (const float*)d_in[10];
  const float* br1   = (const float*)d_in[11];
  const float* att1  = (const float*)d_in[12];
  const float* bias1 = (const float*)d_in[13];
  const float* Wl2   = (const float*)d_in[14];
  const float* bl2   = (const float*)d_in[15];
  const float* Wr2   = (const float*)d_in[16];
  const float* br2   = (const float*)d_in[17];
  const float* att2  = (const float*)d_in[18];
  const float* bias2 = (const float*)d_in[19];

  const int N = in_sizes[0] / 128;
  const int E = in_sizes[1] / 2;

  char* p = (char*)d_ws;
  auto alloc = [&](size_t bytes) {
    void* q = (void*)p;
    p += (bytes + 255) & ~(size_t)255;
    return q;
  };
  auto al = [](size_t b) { return (b + 255) & ~(size_t)255; };
  const size_t common = al((size_t)(N + 1) * 4) + 2 * al((size_t)N * 4) +
                        al((size_t)(E + N) * 4) + al((size_t)512) +
                        2 * al((size_t)N * 128 * 2) +
                        8 * al((size_t)128 * 128 * 2) +
                        4 * al((size_t)512 * 128 * 2);
  const size_t need_fused = common + 2 * al((size_t)N * 512 * 2);
  const bool fused = ws_size >= need_fused;   // deterministic across calls

  int* offs    = (int*)alloc((size_t)(N + 1) * 4);
  int* degree  = (int*)alloc((size_t)N * 4);
  int* cursor  = (int*)alloc((size_t)N * 4);
  int* csr_src = (int*)alloc((size_t)(E + N) * 4);
  int* partial = (int*)alloc((size_t)512);
  unsigned short* Agh = (unsigned short*)alloc((size_t)N * 128 * 2);
  unsigned short* Agl = (unsigned short*)alloc((size_t)N * 128 * 2);
  unsigned short* W0hl = (unsigned short*)alloc((size_t)128 * 128 * 2);
  unsigned short* W0ll = (unsigned short*)alloc((size_t)128 * 128 * 2);
  unsigned short* W0hr = (unsigned short*)alloc((size_t)128 * 128 * 2);
  unsigned short* W0lr = (unsigned short*)alloc((size_t)128 * 128 * 2);
  unsigned short* W1hl = (unsigned short*)alloc((size_t)128 * 128 * 2);
  unsigned short* W1ll = (unsigned short*)alloc((size_t)128 * 128 * 2);
  unsigned short* W1hr = (unsigned short*)alloc((size_t)128 * 128 * 2);
  unsigned short* W1lr = (unsigned short*)alloc((size_t)128 * 128 * 2);
  unsigned short* W2hl = (unsigned short*)alloc((size_t)512 * 128 * 2);
  unsigned short* W2ll = (unsigned short*)alloc((size_t)512 * 128 * 2);
  unsigned short* W2hr = (unsigned short*)alloc((size_t)512 * 128 * 2);
  unsigned short* W2lr = (unsigned short*)alloc((size_t)512 * 128 * 2);
  __half* xl4 = nullptr; __half* xr4 = nullptr;   // fused: fp16 [N,512]
  float* xl = nullptr; float* xr = nullptr;       // fallback fp32 [N,128]
  __half* xl16 = nullptr; __half* xr16 = nullptr; // fused: fp16 [N,128] views
  if (fused) {
    xl4 = (__half*)alloc((size_t)N * 512 * 2);
    xr4 = (__half*)alloc((size_t)N * 512 * 2);
    xl16 = xl4;              // layers 0/1 alias the big buffers ([N,128] fp16)
    xr16 = xr4;
  } else {
    xl = (float*)alloc((size_t)N * 128 * 4);
    xr = (float*)alloc((size_t)N * 128 * 4);
  }
  (void)n_in; (void)out_size;

  const int nb = (N + 1023) / 1024;

  // CSR build (ws is re-poisoned each call, so rebuild every launch)
  k_init<<<(N + 255) / 256, 256, 0, stream>>>(degree, cursor, N);
  k_hist<<<(E + 255) / 256, 256, 0, stream>>>(ei, E, degree);
  k_scan1<<<nb, 256, 0, stream>>>(degree, partial, N);
  k_scan2<<<1, 256, 0, stream>>>(partial, nb);
  k_scan3<<<nb, 256, 0, stream>>>(degree, partial, offs, N);
  k_scatter<<<(E + N + 255) / 256, 256, 0, stream>>>(ei, E, N, offs, cursor, csr_src);

  // one prep dispatch: all 6 weight splits + layer-0 A split
  const int prepT = 196608 + (N * 128 + 3) / 4;
  k_prep<<<(prepT + 255) / 256, 256, 0, stream>>>(
      Wl0, Wr0, Wl1, Wr1, Wl2, Wr2,
      W0hl, W0ll, W0hr, W0lr, W1hl, W1ll, W1hr, W1lr,
      W2hl, W2ll, W2hr, W2lr, x, Agh, Agl, N * 128);

  const int mb = (N + 127) / 128;        // M tiles
  const dim3 gg(mb, 2);                  // layer-0/1 GEMM grid
  const dim3 gg4(mb, 2, 4);              // layer-2 GEMM grid (z = head)
  const int gb = (N + 3) / 4;            // gather grid (4 nodes / block)

  if (fused) {
    // layer 0
    k_gemm2s<<<gg, 256, 0, stream>>>(Agh, Agl, W0hl, W0ll, W0hr, W0lr,
                                     bl0, br0, xl16, xr16, N, 128, 0, 1);
    k_gat_small16<<<gb, 256, 0, stream>>>(xl16, xr16, att0, bias0, offs, degree,
                                          csr_src, Agh, Agl, N);
    // layer 1
    k_gemm2s<<<gg, 256, 0, stream>>>(Agh, Agl, W1hl, W1ll, W1hr, W1lr,
                                     bl1, br1, xl16, xr16, N, 128, 0, 1);
    k_gat_small16<<<gb, 256, 0, stream>>>(xl16, xr16, att1, bias1, offs, degree,
                                          csr_src, Agh, Agl, N);
    // layer 2: 2-term GEMM (hi-W only), one dispatch, z = head slice
    k_gemm2t<<<gg4, 256, 0, stream>>>(Agh, Agl, W2hl, W2hr,
                                      bl2, br2, xl4, xr4, N);
    k_gat_fused4<<<gb, 256, 0, stream>>>(xl4, xr4, att2, bias2, offs, degree,
                                         csr_src, (float*)d_out, N);
  } else {
    // layer 0
    k_gemm2s<<<gg, 256, 0, stream>>>(Agh, Agl, W0hl, W0ll, W0hr, W0lr,
                                     bl0, br0, xl, xr, N, 128, 0, 0);
    k_gat_small<<<gb, 256, 0, stream>>>(xl, xr, att0, bias0, offs, degree, csr_src,
                                        Agh, Agl, N);
    // layer 1
    k_gemm2s<<<gg, 256, 0, stream>>>(Agh, Agl, W1hl, W1ll, W1hr, W1lr,
                                     bl1, br1, xl, xr, N, 128, 0, 0);
    k_gat_small<<<gb, 256, 0, stream>>>(xl, xr, att1, bias1, offs, degree, csr_src,
                                        Agh, Agl, N);
    // layer 2 per head (full 3-term precision)
    for (int h = 0; h < 4; h++) {
      const int wo = h * 128 * 128;
      k_gemm2s<<<gg, 256, 0, stream>>>(Agh, Agl, W2hl + wo, W2ll + wo,
                                       W2hr + wo, W2lr + wo,
                                       bl2 + h * 128, br2 + h * 128,
                                       xl, xr, N, 128, 0, 0);
      k_gat_head<<<gb, 256, 0, stream>>>(xl, xr, att2 + h * 128, bias2, offs, degree,
                                         csr_src, (float*)d_out, N,
                                         h == 0 ? 1 : 0, h == 3 ? 1 : 0);
    }
  }
}

// Round 5
// 951.809 us; speedup vs baseline: 1.1954x; 1.0543x over previous
//
#include <hip/hip_runtime.h>
#include <hip/hip_fp16.h>
#include <cstddef>

// ---------------------------------------------------------------------------
// GATv2 backbone: 3 layers, N=100k nodes, E=1.6M edges (+self loops), H=4.
//   - CSR by dst built once (histogram + 3-kernel multi-block scan + scatter).
//   - Layers 0/1 GEMM: split-bf16 3-term MFMA (precision preserved; errors
//     compound across layers). r1-proven dispatch (y=l/r), pad-40 LDS.
//   - Layer-2 GEMM k_gemm2h: SINGLE-term fp16 MFMA (A fp16, W fp16).
//     Error ~1.6e-4 < fp16 output quantization (~5e-4) the pipeline already
//     carries. Half the MFMA of r4's 2-term, half staging, LDS 20.5 KB.
//   - Layers 0/1 gather: fp16 rows [N,128], packed-fp16 logits, fp32 value
//     acc. Layer-1 instance writes fp16 A directly (no bf16 split).
//   - Layer 2: ONE fused gather over fp16 [N,512]. r1/r4 evidence: ~3.7 TB/s
//     878 MB L2-miss traffic across schedules -> memory-path bound, left alone.
//   - One k_prep dispatch: all weight preps + layer-0 A split.
// ---------------------------------------------------------------------------

typedef __attribute__((ext_vector_type(8))) short bf16x8;
typedef _Float16 f16x8 __attribute__((ext_vector_type(8)));
typedef __attribute__((ext_vector_type(4))) float f32x4;
typedef _Float16 f16x2 __attribute__((ext_vector_type(2)));
typedef float f32x2 __attribute__((ext_vector_type(2)));

#if defined(__has_builtin)
#if __has_builtin(__builtin_amdgcn_fdot2)
#define HAS_FDOT2 1
#endif
#endif

__device__ __forceinline__ float lrelu(float x) { return fmaxf(x, 0.2f * x); }

// 16B row-fragment load at 32-bit byte offset
__device__ __forceinline__ uint4 ldrow(const void* base, unsigned byteoff) {
  return *(const uint4*)((const char*)base + byteoff);
}

// RNE fp32 -> bf16 hi + bf16 residual
__device__ __forceinline__ void split2(float x, unsigned short& h, unsigned short& l) {
  unsigned b = __float_as_uint(x);
  unsigned r = b + 0x7fffu + ((b >> 16) & 1u);
  h = (unsigned short)(r >> 16);
  float hf = __uint_as_float((unsigned)h << 16);
  float res = x - hf;
  unsigned b2 = __float_as_uint(res);
  unsigned r2 = b2 + 0x7fffu + ((b2 >> 16) & 1u);
  l = (unsigned short)(r2 >> 16);
}

// ---------------- CSR build ----------------
__global__ void k_init(int* __restrict__ degree, int* __restrict__ cursor, int N) {
  int i = blockIdx.x * blockDim.x + threadIdx.x;
  if (i < N) { degree[i] = 1; cursor[i] = 0; }  // 1 accounts for the self-loop
}

__global__ void k_hist(const int* __restrict__ ei, int E, int* __restrict__ degree) {
  int e = blockIdx.x * blockDim.x + threadIdx.x;
  if (e < E) atomicAdd(&degree[ei[E + e]], 1);
}

// --- 3-kernel scan: per-block sums -> scan of sums -> per-block scan+base ---
__global__ __launch_bounds__(256) void k_scan1(const int* __restrict__ degree,
                                               int* __restrict__ partial, int N) {
  __shared__ int ws[4];
  const int i0 = blockIdx.x * 1024 + threadIdx.x * 4;
  int s = 0;
  if (i0 + 3 < N) {
    int4 v = *(const int4*)&degree[i0];
    s = v.x + v.y + v.z + v.w;
  } else {
    #pragma unroll
    for (int k = 0; k < 4; k++) if (i0 + k < N) s += degree[i0 + k];
  }
  #pragma unroll
  for (int d = 1; d < 64; d <<= 1) s += __shfl_xor(s, d);
  const int lane = threadIdx.x & 63, wid = threadIdx.x >> 6;
  if (lane == 0) ws[wid] = s;
  __syncthreads();
  if (threadIdx.x == 0) partial[blockIdx.x] = ws[0] + ws[1] + ws[2] + ws[3];
}

__global__ __launch_bounds__(256) void k_scan2(int* __restrict__ partial, int nb) {
  __shared__ int sh[256];
  const int tid = threadIdx.x;
  int v = (tid < nb) ? partial[tid] : 0;
  sh[tid] = v;
  __syncthreads();
  for (int d = 1; d < 256; d <<= 1) {
    int t = (tid >= d) ? sh[tid - d] : 0;
    __syncthreads();
    sh[tid] += t;
    __syncthreads();
  }
  if (tid < nb) partial[tid] = sh[tid] - v;   // exclusive base per block
}

__global__ __launch_bounds__(256) void k_scan3(const int* __restrict__ degree,
                                               const int* __restrict__ partial,
                                               int* __restrict__ offs, int N) {
  __shared__ int wsum[4];
  const int tid = threadIdx.x, lane = tid & 63, wid = tid >> 6;
  const int i0 = blockIdx.x * 1024 + tid * 4;
  int v0 = 0, v1 = 0, v2 = 0, v3 = 0;
  if (i0 + 3 < N) {
    int4 v = *(const int4*)&degree[i0];
    v0 = v.x; v1 = v.y; v2 = v.z; v3 = v.w;
  } else {
    if (i0     < N) v0 = degree[i0];
    if (i0 + 1 < N) v1 = degree[i0 + 1];
    if (i0 + 2 < N) v2 = degree[i0 + 2];
    if (i0 + 3 < N) v3 = degree[i0 + 3];
  }
  int s = v0 + v1 + v2 + v3, x = s;
  #pragma unroll
  for (int d = 1; d < 64; d <<= 1) {
    int y = __shfl_up(x, d);
    if (lane >= d) x += y;
  }
  if (lane == 63) wsum[wid] = x;
  __syncthreads();
  if (tid < 4) {
    int t = wsum[tid];
    #pragma unroll
    for (int d = 1; d < 4; d <<= 1) {
      int y = __shfl_up(t, d);
      if (tid >= d) t += y;
    }
    wsum[tid] = t;
  }
  __syncthreads();
  const int wbase = wid ? wsum[wid - 1] : 0;
  int e = partial[blockIdx.x] + wbase + (x - s);
  if (i0     < N) offs[i0]     = e;  e += v0;  if (i0     == N - 1) offs[N] = e;
  if (i0 + 1 < N) offs[i0 + 1] = e;  e += v1;  if (i0 + 1 == N - 1) offs[N] = e;
  if (i0 + 2 < N) offs[i0 + 2] = e;  e += v2;  if (i0 + 2 == N - 1) offs[N] = e;
  if (i0 + 3 < N) offs[i0 + 3] = e;  e += v3;  if (i0 + 3 == N - 1) offs[N] = e;
}

__global__ void k_scatter(const int* __restrict__ ei, int E, int N,
                          const int* __restrict__ offs, int* __restrict__ cursor,
                          int* __restrict__ csr_src) {
  int t = blockIdx.x * blockDim.x + threadIdx.x;
  int ET = E + N;
  if (t >= ET) return;
  int s, d;
  if (t < E) { s = ei[t]; d = ei[E + t]; }
  else       { s = t - E; d = s; }
  int pos = offs[d] + atomicAdd(&cursor[d], 1);
  csr_src[pos] = s;
}

// ---- ONE prep dispatch: W0/W1 split, W2 split (fallback) + fp16 (fused),
// ---- layer-0 A split. Weight split elems 196608; W2 fp16 elems 131072.
__global__ __launch_bounds__(256) void k_prep(
    const float* __restrict__ Wl0, const float* __restrict__ Wr0,
    const float* __restrict__ Wl1, const float* __restrict__ Wr1,
    const float* __restrict__ Wl2, const float* __restrict__ Wr2,
    unsigned short* __restrict__ W0hl, unsigned short* __restrict__ W0ll,
    unsigned short* __restrict__ W0hr, unsigned short* __restrict__ W0lr,
    unsigned short* __restrict__ W1hl, unsigned short* __restrict__ W1ll,
    unsigned short* __restrict__ W1hr, unsigned short* __restrict__ W1lr,
    unsigned short* __restrict__ W2hl, unsigned short* __restrict__ W2ll,
    unsigned short* __restrict__ W2hr, unsigned short* __restrict__ W2lr,
    __half* __restrict__ W2fl, __half* __restrict__ W2fr,
    const float* __restrict__ X,
    unsigned short* __restrict__ Ah, unsigned short* __restrict__ Al, int totalA) {
  const int t = blockIdx.x * blockDim.x + threadIdx.x;
  if (t < 196608) {
    const float* W; unsigned short *Whp, *Wlp; int idx, sh;
    if (t < 16384)       { W = Wl0; Whp = W0hl; Wlp = W0ll; idx = t;          sh = 7; }
    else if (t < 32768)  { W = Wr0; Whp = W0hr; Wlp = W0lr; idx = t - 16384;  sh = 7; }
    else if (t < 49152)  { W = Wl1; Whp = W1hl; Wlp = W1ll; idx = t - 32768;  sh = 7; }
    else if (t < 65536)  { W = Wr1; Whp = W1hr; Wlp = W1lr; idx = t - 49152;  sh = 7; }
    else if (t < 131072) { W = Wl2; Whp = W2hl; Wlp = W2ll; idx = t - 65536;  sh = 9; }
    else                 { W = Wr2; Whp = W2hr; Wlp = W2lr; idx = t - 131072; sh = 9; }
    const int n = idx & ((1 << sh) - 1), k = idx >> sh;
    unsigned short h, l;
    split2(W[idx], h, l);
    Whp[(size_t)n * 128 + k] = h;
    Wlp[(size_t)n * 128 + k] = l;
    return;
  }
  if (t < 327680) {               // W2 fp16 transpose (fused layer-2 GEMM)
    const int u = t - 196608;
    const float* W = (u < 65536) ? Wl2 : Wr2;
    __half* O = (u < 65536) ? W2fl : W2fr;
    const int idx = (u < 65536) ? u : u - 65536;
    const int n = idx & 511, k = idx >> 9;
    O[(size_t)n * 128 + k] = __float2half(W[idx]);
    return;
  }
  const int t4 = (t - 327680) * 4;
  if (t4 >= totalA) return;
  float4 v = *(const float4*)&X[t4];
  unsigned short h0, h1, h2, h3, l0, l1, l2, l3;
  split2(v.x, h0, l0); split2(v.y, h1, l1);
  split2(v.z, h2, l2); split2(v.w, h3, l3);
  uint2 hv, lv;
  hv.x = (unsigned)h0 | ((unsigned)h1 << 16);
  hv.y = (unsigned)h2 | ((unsigned)h3 << 16);
  lv.x = (unsigned)l0 | ((unsigned)l1 << 16);
  lv.y = (unsigned)l2 | ((unsigned)l3 << 16);
  *(uint2*)&Ah[t4] = hv;
  *(uint2*)&Al[t4] = lv;
}

// ---------------- split-bf16 MFMA GEMM (3-term), dual projection ------------
// r1-proven dispatch: blockIdx.y = l/r, blockIdx.z = head slice. Register
// prefetch of next K-chunk during MFMA. Scalar stores.
__global__ __launch_bounds__(256) void k_gemm2s(
    const unsigned short* __restrict__ Agh, const unsigned short* __restrict__ Agl,
    const unsigned short* __restrict__ Whl, const unsigned short* __restrict__ Wll,
    const unsigned short* __restrict__ Whr, const unsigned short* __restrict__ Wlr,
    const float* __restrict__ bias_l, const float* __restrict__ bias_r,
    void* __restrict__ Clp, void* __restrict__ Crp, int N,
    int ldC, int coloff, int out_half) {
  __shared__ unsigned short Ah_s[128][40];   // row pad 40 (80 B = 5 superbanks)
  __shared__ unsigned short Al_s[128][40];
  __shared__ unsigned short Wh_s[128][40];
  __shared__ unsigned short Wl_s[128][40];
  const int hsel = blockIdx.z;
  const unsigned short* __restrict__ Wth = (blockIdx.y ? Whr : Whl) + hsel * 128 * 128;
  const unsigned short* __restrict__ Wtl = (blockIdx.y ? Wlr : Wll) + hsel * 128 * 128;
  const float* __restrict__ bias = (blockIdx.y ? bias_r : bias_l) + hsel * 128;
  void* __restrict__ Cp = blockIdx.y ? Crp : Clp;
  coloff += hsel * 128;

  const int tid = threadIdx.x;
  const int m0 = blockIdx.x * 128;
  const int wv = tid >> 6, lane = tid & 63;
  const int wm = (wv >> 1) * 64, wn = (wv & 1) * 64;
  const int l15 = lane & 15, kb = (lane >> 4) * 8;
  f32x4 acc[4][4] = {};

  const int r = tid >> 1;              // staging row 0..127
  const int cb = (tid & 1) * 16;       // staging col base 0/16
  const bool arow_ok = (m0 + r) < N;
  const unsigned short* ahp = Agh + (size_t)(m0 + r) * 128 + cb;
  const unsigned short* alp = Agl + (size_t)(m0 + r) * 128 + cb;
  const unsigned short* whp = Wth + r * 128 + cb;
  const unsigned short* wlp = Wtl + r * 128 + cb;
  const uint4 z4 = make_uint4(0, 0, 0, 0);

  uint4 pa0, pa1, pl0, pl1, pw0, pw1, pq0, pq1;
  #define LOADC(K0)                                                           \
    pa0 = arow_ok ? *(const uint4*)(ahp + (K0))     : z4;                     \
    pa1 = arow_ok ? *(const uint4*)(ahp + (K0) + 8) : z4;                     \
    pl0 = arow_ok ? *(const uint4*)(alp + (K0))     : z4;                     \
    pl1 = arow_ok ? *(const uint4*)(alp + (K0) + 8) : z4;                     \
    pw0 = *(const uint4*)(whp + (K0));                                        \
    pw1 = *(const uint4*)(whp + (K0) + 8);                                    \
    pq0 = *(const uint4*)(wlp + (K0));                                        \
    pq1 = *(const uint4*)(wlp + (K0) + 8);
  LOADC(0)
  for (int kc = 0; kc < 4; kc++) {
    *(uint4*)&Ah_s[r][cb]     = pa0;
    *(uint4*)&Ah_s[r][cb + 8] = pa1;
    *(uint4*)&Al_s[r][cb]     = pl0;
    *(uint4*)&Al_s[r][cb + 8] = pl1;
    *(uint4*)&Wh_s[r][cb]     = pw0;
    *(uint4*)&Wh_s[r][cb + 8] = pw1;
    *(uint4*)&Wl_s[r][cb]     = pq0;
    *(uint4*)&Wl_s[r][cb + 8] = pq1;
    __syncthreads();
    if (kc < 3) { LOADC((kc + 1) * 32) }   // in flight during MFMA below

    bf16x8 afh[4], afl[4];
    #pragma unroll
    for (int mi = 0; mi < 4; mi++) {
      const int row = wm + mi * 16 + l15;
      afh[mi] = *(const bf16x8*)&Ah_s[row][kb];
      afl[mi] = *(const bf16x8*)&Al_s[row][kb];
    }
    #pragma unroll
    for (int ni = 0; ni < 4; ni++) {
      const int rown = wn + ni * 16 + l15;
      bf16x8 bh = *(const bf16x8*)&Wh_s[rown][kb];
      bf16x8 bl = *(const bf16x8*)&Wl_s[rown][kb];
      #pragma unroll
      for (int mi = 0; mi < 4; mi++) {
        acc[mi][ni] = __builtin_amdgcn_mfma_f32_16x16x32_bf16(afh[mi], bh, acc[mi][ni], 0, 0, 0);
        acc[mi][ni] = __builtin_amdgcn_mfma_f32_16x16x32_bf16(afl[mi], bh, acc[mi][ni], 0, 0, 0);
        acc[mi][ni] = __builtin_amdgcn_mfma_f32_16x16x32_bf16(afh[mi], bl, acc[mi][ni], 0, 0, 0);
      }
    }
    __syncthreads();
  }
  #undef LOADC
  const int col = l15, rbase = (lane >> 4) * 4;
  #pragma unroll
  for (int ni = 0; ni < 4; ni++) {
    const int gn = wn + ni * 16 + col;
    const float bv = bias[gn];
    #pragma unroll
    for (int mi = 0; mi < 4; mi++) {
      #pragma unroll
      for (int q = 0; q < 4; q++) {
        const int gm = m0 + wm + mi * 16 + rbase + q;
        if (gm < N) {
          float v = acc[mi][ni][q] + bv;
          if (out_half) ((__half*)Cp)[(size_t)gm * ldC + coloff + gn] = __float2half(v);
          else          ((float*)Cp)[(size_t)gm * ldC + coloff + gn] = v;
        }
      }
    }
  }
}

// ---------------- layer-2 GEMM: SINGLE-term fp16 MFMA, fp16 out -------------
// A fp16 [N,128] (layer-1 gather output), W fp16 transposed. Exact fp16
// products with fp32 accumulation: input-quantization error ~1.6e-4 < fp16
// output step. Half the MFMA of the 2-term bf16 split; LDS 20.5 KB.
__global__ __launch_bounds__(256) void k_gemm2h(
    const __half* __restrict__ A16,
    const __half* __restrict__ Wfl, const __half* __restrict__ Wfr,
    const float* __restrict__ bias_l, const float* __restrict__ bias_r,
    __half* __restrict__ Clp, __half* __restrict__ Crp, int N) {
  __shared__ __half A_s[128][40];
  __shared__ __half W_s[128][40];
  const int hsel = blockIdx.z;
  const __half* __restrict__ Wt = (blockIdx.y ? Wfr : Wfl) + hsel * 128 * 128;
  const float* __restrict__ bias = (blockIdx.y ? bias_r : bias_l) + hsel * 128;
  __half* __restrict__ Cp = blockIdx.y ? Crp : Clp;
  const int coloff = hsel * 128;

  const int tid = threadIdx.x;
  const int m0 = blockIdx.x * 128;
  const int wv = tid >> 6, lane = tid & 63;
  const int wm = (wv >> 1) * 64, wn = (wv & 1) * 64;
  const int l15 = lane & 15, kb = (lane >> 4) * 8;
  f32x4 acc[4][4] = {};

  const int r = tid >> 1;              // staging row 0..127
  const int cb = (tid & 1) * 16;       // staging col base 0/16
  const bool arow_ok = (m0 + r) < N;
  const __half* ap = A16 + (size_t)(m0 + r) * 128 + cb;
  const __half* wp = Wt + r * 128 + cb;
  const uint4 z4 = make_uint4(0, 0, 0, 0);

  uint4 pa0, pa1, pw0, pw1;
  #define LOADH(K0)                                                           \
    pa0 = arow_ok ? *(const uint4*)(ap + (K0))     : z4;                      \
    pa1 = arow_ok ? *(const uint4*)(ap + (K0) + 8) : z4;                      \
    pw0 = *(const uint4*)(wp + (K0));                                         \
    pw1 = *(const uint4*)(wp + (K0) + 8);
  LOADH(0)
  for (int kc = 0; kc < 4; kc++) {
    *(uint4*)&A_s[r][cb]     = pa0;
    *(uint4*)&A_s[r][cb + 8] = pa1;
    *(uint4*)&W_s[r][cb]     = pw0;
    *(uint4*)&W_s[r][cb + 8] = pw1;
    __syncthreads();
    if (kc < 3) { LOADH((kc + 1) * 32) }   // in flight during MFMA below

    f16x8 af[4];
    #pragma unroll
    for (int mi = 0; mi < 4; mi++)
      af[mi] = *(const f16x8*)&A_s[wm + mi * 16 + l15][kb];
    #pragma unroll
    for (int ni = 0; ni < 4; ni++) {
      f16x8 bh = *(const f16x8*)&W_s[wn + ni * 16 + l15][kb];
      #pragma unroll
      for (int mi = 0; mi < 4; mi++)
        acc[mi][ni] = __builtin_amdgcn_mfma_f32_16x16x32_f16(af[mi], bh, acc[mi][ni], 0, 0, 0);
    }
    __syncthreads();
  }
  #undef LOADH
  const int col = l15, rbase = (lane >> 4) * 4;
  #pragma unroll
  for (int ni = 0; ni < 4; ni++) {
    const int gn = wn + ni * 16 + col;
    const float bv = bias[gn];
    #pragma unroll
    for (int mi = 0; mi < 4; mi++) {
      #pragma unroll
      for (int q = 0; q < 4; q++) {
        const int gm = m0 + wm + mi * 16 + rbase + q;
        if (gm < N)
          Cp[(size_t)gm * 512 + coloff + gn] = __float2half(acc[mi][ni][q] + bv);
      }
    }
  }
}

// -------- butterfly ADD merge of per-group partials (plain-exp softmax) -----
#define MERGE_ADD(d)                                                          \
  {                                                                           \
    l += __shfl_xor(l, d);                                                    \
    aca.x += __shfl_xor(aca.x, d); aca.y += __shfl_xor(aca.y, d);             \
    aca.z += __shfl_xor(aca.z, d); aca.w += __shfl_xor(aca.w, d);             \
    acb.x += __shfl_xor(acb.x, d); acb.y += __shfl_xor(acb.y, d);             \
    acb.z += __shfl_xor(acb.z, d); acb.w += __shfl_xor(acb.w, d);             \
  }

// ---------------- fused GATv2 gather, layers 0/1 (fp32 fallback) ------------
__global__ __launch_bounds__(256) void k_gat_small(
    const float* __restrict__ xl, const float* __restrict__ xr,
    const float* __restrict__ att, const float* __restrict__ bias,
    const int* __restrict__ offs, const int* __restrict__ degree,
    const int* __restrict__ csr_src,
    unsigned short* __restrict__ Ah, unsigned short* __restrict__ Al, int N) {
  const int node = blockIdx.x * 4 + (threadIdx.x >> 6);
  if (node >= N) return;
  const int lane = threadIdx.x & 63;
  const int g = lane >> 4;
  const int c = lane & 15;
  const int d0 = c * 8;
  const size_t nb = (size_t)node * 128 + d0;
  const float4 xra = *(const float4*)&xr[nb];
  const float4 xrb = *(const float4*)&xr[nb + 4];
  const float4 ata = *(const float4*)&att[d0];
  const float4 atb = *(const float4*)&att[d0 + 4];
  const int off = offs[node];
  const int deg = degree[node];
  float l = 0.f;
  float4 aca = make_float4(0.f, 0.f, 0.f, 0.f);
  float4 acb = make_float4(0.f, 0.f, 0.f, 0.f);
  int s0 = (g < deg) ? csr_src[off + g] : 0;
  int s1 = (g + 4 < deg) ? csr_src[off + g + 4] : 0;
  for (int j = g; j < deg; j += 8) {
    int sn0 = (j + 8 < deg) ? csr_src[off + j + 8] : 0;
    int sn1 = (j + 12 < deg) ? csr_src[off + j + 12] : 0;
    const size_t sb0 = (size_t)s0 * 128 + d0;
    const size_t sb1 = (size_t)s1 * 128 + d0;
    float4 xa0 = *(const float4*)&xl[sb0];
    float4 xb0 = *(const float4*)&xl[sb0 + 4];
    float4 xa1 = *(const float4*)&xl[sb1];
    float4 xb1 = *(const float4*)&xl[sb1 + 4];
    float t0 = lrelu(xa0.x + xra.x) * ata.x + lrelu(xa0.y + xra.y) * ata.y +
               lrelu(xa0.z + xra.z) * ata.z + lrelu(xa0.w + xra.w) * ata.w +
               lrelu(xb0.x + xrb.x) * atb.x + lrelu(xb0.y + xrb.y) * atb.y +
               lrelu(xb0.z + xrb.z) * atb.z + lrelu(xb0.w + xrb.w) * atb.w;
    float t1 = lrelu(xa1.x + xra.x) * ata.x + lrelu(xa1.y + xra.y) * ata.y +
               lrelu(xa1.z + xra.z) * ata.z + lrelu(xa1.w + xra.w) * ata.w +
               lrelu(xb1.x + xrb.x) * atb.x + lrelu(xb1.y + xrb.y) * atb.y +
               lrelu(xb1.z + xrb.z) * atb.z + lrelu(xb1.w + xrb.w) * atb.w;
    t0 += __shfl_xor(t0, 1);
    t0 += __shfl_xor(t0, 2);       // 4-lane head cluster -> per-head logit
    t1 += __shfl_xor(t1, 1);
    t1 += __shfl_xor(t1, 2);
    float p0 = __expf(t0);
    float p1 = (j + 4 < deg) ? __expf(t1) : 0.f;
    aca.x += p0 * xa0.x + p1 * xa1.x; aca.y += p0 * xa0.y + p1 * xa1.y;
    aca.z += p0 * xa0.z + p1 * xa1.z; aca.w += p0 * xa0.w + p1 * xa1.w;
    acb.x += p0 * xb0.x + p1 * xb1.x; acb.y += p0 * xb0.y + p1 * xb1.y;
    acb.z += p0 * xb0.z + p1 * xb1.z; acb.w += p0 * xb0.w + p1 * xb1.w;
    l += p0 + p1;
    s0 = sn0; s1 = sn1;
  }
  MERGE_ADD(16)
  MERGE_ADD(32)
  if (lane < 16) {
    const float inv = 1.f / l;
    const float4 b0 = *(const float4*)&bias[d0];
    const float4 b1 = *(const float4*)&bias[d0 + 4];
    float o[8] = {aca.x * inv + b0.x, aca.y * inv + b0.y,
                  aca.z * inv + b0.z, aca.w * inv + b0.w,
                  acb.x * inv + b1.x, acb.y * inv + b1.y,
                  acb.z * inv + b1.z, acb.w * inv + b1.w};
    unsigned short hs[8], ls[8];
    #pragma unroll
    for (int i = 0; i < 8; i++) {
      o[i] = o[i] > 0.f ? o[i] : __expf(o[i]) - 1.f;   // ELU
      split2(o[i], hs[i], ls[i]);
    }
    uint4 hv, lv;
    hv.x = (unsigned)hs[0] | ((unsigned)hs[1] << 16);
    hv.y = (unsigned)hs[2] | ((unsigned)hs[3] << 16);
    hv.z = (unsigned)hs[4] | ((unsigned)hs[5] << 16);
    hv.w = (unsigned)hs[6] | ((unsigned)hs[7] << 16);
    lv.x = (unsigned)ls[0] | ((unsigned)ls[1] << 16);
    lv.y = (unsigned)ls[2] | ((unsigned)ls[3] << 16);
    lv.z = (unsigned)ls[4] | ((unsigned)ls[5] << 16);
    lv.w = (unsigned)ls[6] | ((unsigned)ls[7] << 16);
    *(uint4*)&Ah[nb] = hv;
    *(uint4*)&Al[nb] = lv;
  }
}

// ---------------- packed-fp16 edge steps ------------------------------------
// 512-wide (layer 2): 16-lane head group reduce (4 shfl)
__device__ __forceinline__ void edge_step(uint4 vv, bool valid,
                                          const f16x2* xrh, const f16x2* ath,
                                          f32x2* accv, float& l) {
  union { uint4 u; f16x2 h[4]; } xu; xu.u = vv;
  const f16x2 c02 = {(_Float16)0.2f, (_Float16)0.2f};
  float t = 0.f;
#if defined(HAS_FDOT2)
  #pragma unroll
  for (int i = 0; i < 4; i++) {
    f16x2 s = xu.h[i] + xrh[i];
    f16x2 lr = __builtin_elementwise_max(s, s * c02);
    t = __builtin_amdgcn_fdot2(lr, ath[i], t, false);
  }
#else
  #pragma unroll
  for (int i = 0; i < 4; i++) {
    f32x2 s = __builtin_convertvector(xu.h[i], f32x2) +
              __builtin_convertvector(xrh[i], f32x2);
    f32x2 a = __builtin_convertvector(ath[i], f32x2);
    t += fmaxf(s.x, 0.2f * s.x) * a.x + fmaxf(s.y, 0.2f * s.y) * a.y;
  }
#endif
  t += __shfl_xor(t, 1);
  t += __shfl_xor(t, 2);
  t += __shfl_xor(t, 4);
  t += __shfl_xor(t, 8);         // 16-lane head group -> head logit
  float p = valid ? __expf(t) : 0.f;
  l += p;
  f32x2 p2 = {p, p};
  #pragma unroll
  for (int i = 0; i < 4; i++)
    accv[i] += p2 * __builtin_convertvector(xu.h[i], f32x2);  // v_pk_fma_f32
}

// 128-wide (layers 0/1): 4-lane head cluster reduce (2 shfl), all edges valid
__device__ __forceinline__ void edge_step_small(uint4 vv,
                                                const f16x2* xrh, const f16x2* ath,
                                                f32x2* accv, float& l) {
  union { uint4 u; f16x2 h[4]; } xu; xu.u = vv;
  const f16x2 c02 = {(_Float16)0.2f, (_Float16)0.2f};
  float t = 0.f;
#if defined(HAS_FDOT2)
  #pragma unroll
  for (int i = 0; i < 4; i++) {
    f16x2 s = xu.h[i] + xrh[i];
    f16x2 lr = __builtin_elementwise_max(s, s * c02);
    t = __builtin_amdgcn_fdot2(lr, ath[i], t, false);
  }
#else
  #pragma unroll
  for (int i = 0; i < 4; i++) {
    f32x2 s = __builtin_convertvector(xu.h[i], f32x2) +
              __builtin_convertvector(xrh[i], f32x2);
    f32x2 a = __builtin_convertvector(ath[i], f32x2);
    t += fmaxf(s.x, 0.2f * s.x) * a.x + fmaxf(s.y, 0.2f * s.y) * a.y;
  }
#endif
  t += __shfl_xor(t, 1);
  t += __shfl_xor(t, 2);         // 4-lane head cluster -> per-head logit
  float p = __expf(t);
  l += p;
  f32x2 p2 = {p, p};
  #pragma unroll
  for (int i = 0; i < 4; i++)
    accv[i] += p2 * __builtin_convertvector(xu.h[i], f32x2);
}

// ---------------- layers 0/1 gather over fp16 [N,128] -----------------------
// mode 0: write split-bf16 Ah/Al (feeds 3-term GEMM).  mode 1: write fp16 A16
// (feeds layer-2 fp16 single-term GEMM) - no split2, one store.
__global__ __launch_bounds__(256) void k_gat_small16(
    const __half* __restrict__ xl, const __half* __restrict__ xr,
    const float* __restrict__ att, const float* __restrict__ bias,
    const int* __restrict__ offs, const int* __restrict__ degree,
    const int* __restrict__ csr_src,
    unsigned short* __restrict__ Ah, unsigned short* __restrict__ Al,
    __half* __restrict__ A16, int mode, int N) {
  const int node = blockIdx.x * 4 + (threadIdx.x >> 6);
  if (node >= N) return;
  const int lane = threadIdx.x & 63;
  const int g = lane >> 4;        // edge slot
  const int c = lane & 15;        // channel group (8 ch)
  const int d0 = c * 8;
  f16x2 xrh[4], ath[4];
  {
    union { uint4 u; f16x2 h[4]; } ru;
    ru.u = *(const uint4*)&xr[(size_t)node * 128 + d0];
    float4 a0 = *(const float4*)&att[d0];
    float4 a1 = *(const float4*)&att[d0 + 4];
    #pragma unroll
    for (int i = 0; i < 4; i++) xrh[i] = ru.h[i];
    ath[0] = (f16x2){(_Float16)a0.x, (_Float16)a0.y};
    ath[1] = (f16x2){(_Float16)a0.z, (_Float16)a0.w};
    ath[2] = (f16x2){(_Float16)a1.x, (_Float16)a1.y};
    ath[3] = (f16x2){(_Float16)a1.z, (_Float16)a1.w};
  }
  const int off = offs[node];
  const int deg = degree[node];
  const unsigned lb = (unsigned)d0 * 2u;        // byte offset in 256 B row
  f32x2 accv[4] = {};
  float l = 0.f;
  int ia = (g < deg)     ? csr_src[off + g]     : 0;
  int ib = (g + 4 < deg) ? csr_src[off + g + 4] : 0;
  int ic = (g + 8 < deg) ? csr_src[off + g + 8] : 0;
  uint4 v0 = make_uint4(0, 0, 0, 0), v1 = v0;
  if (g < deg)     v0 = ldrow(xl, (unsigned)ia * 256u + lb);
  if (g + 4 < deg) v1 = ldrow(xl, (unsigned)ib * 256u + lb);
  for (int j = g; j < deg; j += 4) {
    uint4 vn = v0;
    if (j + 8 < deg) vn = ldrow(xl, (unsigned)ic * 256u + lb);
    int id = (j + 12 < deg) ? csr_src[off + j + 12] : 0;
    edge_step_small(v0, xrh, ath, accv, l);
    v0 = v1; v1 = vn; ic = id;
  }
  // merge the 4 slots (lanes differ in bits 4-5)
  #pragma unroll
  for (int d = 16; d < 64; d <<= 1) {
    l += __shfl_xor(l, d);
    #pragma unroll
    for (int i = 0; i < 4; i++) {
      accv[i].x += __shfl_xor(accv[i].x, d);
      accv[i].y += __shfl_xor(accv[i].y, d);
    }
  }
  if (lane < 16) {
    const float inv = 1.f / l;
    const float4 b0 = *(const float4*)&bias[d0];
    const float4 b1 = *(const float4*)&bias[d0 + 4];
    float o[8] = {accv[0].x * inv + b0.x, accv[0].y * inv + b0.y,
                  accv[1].x * inv + b0.z, accv[1].y * inv + b0.w,
                  accv[2].x * inv + b1.x, accv[2].y * inv + b1.y,
                  accv[3].x * inv + b1.z, accv[3].y * inv + b1.w};
    #pragma unroll
    for (int i = 0; i < 8; i++)
      o[i] = o[i] > 0.f ? o[i] : __expf(o[i]) - 1.f;   // ELU
    const size_t nb = (size_t)node * 128 + d0;
    if (mode == 1) {
      union { uint4 u; __half h[8]; } ou;
      #pragma unroll
      for (int i = 0; i < 8; i++) ou.h[i] = __float2half(o[i]);
      *(uint4*)&A16[nb] = ou.u;
    } else {
      unsigned short hs[8], ls[8];
      #pragma unroll
      for (int i = 0; i < 8; i++) split2(o[i], hs[i], ls[i]);
      uint4 hv, lv;
      hv.x = (unsigned)hs[0] | ((unsigned)hs[1] << 16);
      hv.y = (unsigned)hs[2] | ((unsigned)hs[3] << 16);
      hv.z = (unsigned)hs[4] | ((unsigned)hs[5] << 16);
      hv.w = (unsigned)hs[6] | ((unsigned)hs[7] << 16);
      lv.x = (unsigned)ls[0] | ((unsigned)ls[1] << 16);
      lv.y = (unsigned)ls[2] | ((unsigned)ls[3] << 16);
      lv.z = (unsigned)ls[4] | ((unsigned)ls[5] << 16);
      lv.w = (unsigned)ls[6] | ((unsigned)ls[7] << 16);
      *(uint4*)&Ah[nb] = hv;
      *(uint4*)&Al[nb] = lv;
    }
  }
}

// ---------------- layer 2 FUSED gather: rotating prefetch -------------------
__global__ __launch_bounds__(256) void k_gat_fused4(
    const __half* __restrict__ xl4, const __half* __restrict__ xr4,
    const float* __restrict__ att2, const float* __restrict__ bias,
    const int* __restrict__ offs, const int* __restrict__ degree,
    const int* __restrict__ csr_src, float* __restrict__ out, int N) {
  const int node = blockIdx.x * 4 + (threadIdx.x >> 6);
  if (node >= N) return;
  const int lane = threadIdx.x & 63;
  f16x2 xrh[4], ath[4];
  {
    union { uint4 u; f16x2 h[4]; } ru;
    ru.u = *(const uint4*)&xr4[(size_t)node * 512 + lane * 8];
    float4 a0 = *(const float4*)&att2[lane * 8];
    float4 a1 = *(const float4*)&att2[lane * 8 + 4];
    #pragma unroll
    for (int i = 0; i < 4; i++) xrh[i] = ru.h[i];
    ath[0] = (f16x2){(_Float16)a0.x, (_Float16)a0.y};
    ath[1] = (f16x2){(_Float16)a0.z, (_Float16)a0.w};
    ath[2] = (f16x2){(_Float16)a1.x, (_Float16)a1.y};
    ath[3] = (f16x2){(_Float16)a1.z, (_Float16)a1.w};
  }
  const int off = offs[node];
  const int deg = degree[node];
  const unsigned lb = (unsigned)lane * 16u;     // byte offset in 1 KB row
  f32x2 accv[4] = {};
  float l = 0.f;
  int s0 = csr_src[off];
  int s1 = (1 < deg) ? csr_src[off + 1] : 0;
  int s2 = (2 < deg) ? csr_src[off + 2] : 0;
  int s3 = (3 < deg) ? csr_src[off + 3] : 0;
  uint4 v0 = ldrow(xl4, (unsigned)s0 * 1024u + lb);
  uint4 v1 = (1 < deg) ? ldrow(xl4, (unsigned)s1 * 1024u + lb) : v0;
  uint4 v2 = (2 < deg) ? ldrow(xl4, (unsigned)s2 * 1024u + lb) : v0;
  uint4 v3 = (3 < deg) ? ldrow(xl4, (unsigned)s3 * 1024u + lb) : v0;
  s0 = (4 < deg) ? csr_src[off + 4] : 0;        // indices one iter ahead
  s1 = (5 < deg) ? csr_src[off + 5] : 0;
  s2 = (6 < deg) ? csr_src[off + 6] : 0;
  s3 = (7 < deg) ? csr_src[off + 7] : 0;
  for (int j = 0; j < deg; j += 4) {
    edge_step(v0, true, xrh, ath, accv, l);     // j < deg guaranteed
    if (j + 4 < deg) v0 = ldrow(xl4, (unsigned)s0 * 1024u + lb);
    s0 = (j + 8 < deg) ? csr_src[off + j + 8] : 0;
    edge_step(v1, j + 1 < deg, xrh, ath, accv, l);
    if (j + 5 < deg) v1 = ldrow(xl4, (unsigned)s1 * 1024u + lb);
    s1 = (j + 9 < deg) ? csr_src[off + j + 9] : 0;
    edge_step(v2, j + 2 < deg, xrh, ath, accv, l);
    if (j + 6 < deg) v2 = ldrow(xl4, (unsigned)s2 * 1024u + lb);
    s2 = (j + 10 < deg) ? csr_src[off + j + 10] : 0;
    edge_step(v3, j + 3 < deg, xrh, ath, accv, l);
    if (j + 7 < deg) v3 = ldrow(xl4, (unsigned)s3 * 1024u + lb);
    s3 = (j + 11 < deg) ? csr_src[off + j + 11] : 0;
  }
  // scale by own head's softmax-mean weight, then sum heads via butterfly
  const float w = 0.25f / l;
  const f32x2 w2 = {w, w};
  #pragma unroll
  for (int i = 0; i < 4; i++) accv[i] *= w2;
  #pragma unroll
  for (int d = 16; d < 64; d <<= 1) {
    #pragma unroll
    for (int i = 0; i < 4; i++) {
      accv[i].x += __shfl_xor(accv[i].x, d);
      accv[i].y += __shfl_xor(accv[i].y, d);
    }
  }
  if (lane < 16) {
    const int d0 = lane * 8;
    float4 b0 = *(const float4*)&bias[d0];
    float4 b1 = *(const float4*)&bias[d0 + 4];
    float* op = &out[(size_t)node * 128 + d0];
    *(float4*)op       = make_float4(accv[0].x + b0.x, accv[0].y + b0.y,
                                     accv[1].x + b0.z, accv[1].y + b0.w);
    *(float4*)(op + 4) = make_float4(accv[2].x + b1.x, accv[2].y + b1.y,
                                     accv[3].x + b1.z, accv[3].y + b1.w);
  }
}

// ---------------- fallback: layer 2 per-head fp32 gather --------------------
__global__ __launch_bounds__(256) void k_gat_head(
    const float* __restrict__ xl, const float* __restrict__ xr,
    const float* __restrict__ att_h, const float* __restrict__ bias,
    const int* __restrict__ offs, const int* __restrict__ degree,
    const int* __restrict__ csr_src, float* __restrict__ out, int N,
    int first, int last) {
  const int node = blockIdx.x * 4 + (threadIdx.x >> 6);
  if (node >= N) return;
  const int lane = threadIdx.x & 63;
  const int g = lane >> 4;
  const int c = lane & 15;
  const int d0 = c * 8;
  const size_t nb = (size_t)node * 128 + d0;
  const float4 xra = *(const float4*)&xr[nb];
  const float4 xrb = *(const float4*)&xr[nb + 4];
  const float4 ata = *(const float4*)&att_h[d0];
  const float4 atb = *(const float4*)&att_h[d0 + 4];
  const int off = offs[node];
  const int deg = degree[node];
  float l = 0.f;
  float4 aca = make_float4(0.f, 0.f, 0.f, 0.f);
  float4 acb = make_float4(0.f, 0.f, 0.f, 0.f);
  int s0 = (g < deg) ? csr_src[off + g] : 0;
  int s1 = (g + 4 < deg) ? csr_src[off + g + 4] : 0;
  for (int j = g; j < deg; j += 8) {
    int sn0 = (j + 8 < deg) ? csr_src[off + j + 8] : 0;
    int sn1 = (j + 12 < deg) ? csr_src[off + j + 12] : 0;
    const size_t sb0 = (size_t)s0 * 128 + d0;
    const size_t sb1 = (size_t)s1 * 128 + d0;
    float4 xa0 = *(const float4*)&xl[sb0];
    float4 xb0 = *(const float4*)&xl[sb0 + 4];
    float4 xa1 = *(const float4*)&xl[sb1];
    float4 xb1 = *(const float4*)&xl[sb1 + 4];
    float t0 = lrelu(xa0.x + xra.x) * ata.x + lrelu(xa0.y + xra.y) * ata.y +
               lrelu(xa0.z + xra.z) * ata.z + lrelu(xa0.w + xra.w) * ata.w +
               lrelu(xb0.x + xrb.x) * atb.x + lrelu(xb0.y + xrb.y) * atb.y +
               lrelu(xb0.z + xrb.z) * atb.z + lrelu(xb0.w + xrb.w) * atb.w;
    float t1 = lrelu(xa1.x + xra.x) * ata.x + lrelu(xa1.y + xra.y) * ata.y +
               lrelu(xa1.z + xra.z) * ata.z + lrelu(xa1.w + xra.w) * ata.w +
               lrelu(xb1.x + xrb.x) * atb.x + lrelu(xb1.y + xrb.y) * atb.y +
               lrelu(xb1.z + xrb.z) * atb.z + lrelu(xb1.w + xrb.w) * atb.w;
    t0 += __shfl_xor(t0, 1);
    t0 += __shfl_xor(t0, 2);
    t0 += __shfl_xor(t0, 4);
    t0 += __shfl_xor(t0, 8);
    t1 += __shfl_xor(t1, 1);
    t1 += __shfl_xor(t1, 2);
    t1 += __shfl_xor(t1, 4);
    t1 += __shfl_xor(t1, 8);
    float p0 = __expf(t0);
    float p1 = (j + 4 < deg) ? __expf(t1) : 0.f;
    aca.x += p0 * xa0.x + p1 * xa1.x; aca.y += p0 * xa0.y + p1 * xa1.y;
    aca.z += p0 * xa0.z + p1 * xa1.z; aca.w += p0 * xa0.w + p1 * xa1.w;
    acb.x += p0 * xb0.x + p1 * xb1.x; acb.y += p0 * xb0.y + p1 * xb1.y;
    acb.z += p0 * xb0.z + p1 * xb1.z; acb.w += p0 * xb0.w + p1 * xb1.w;
    l += p0 + p1;
    s0 = sn0; s1 = sn1;
  }
  MERGE_ADD(16)
  MERGE_ADD(32)
  if (lane < 16) {
    const float inv = 0.25f / l;
    float o[8] = {aca.x * inv, aca.y * inv, aca.z * inv, aca.w * inv,
                  acb.x * inv, acb.y * inv, acb.z * inv, acb.w * inv};
    float* op = &out[nb];
    if (!first) {
      float4 p0 = *(const float4*)op;
      float4 p1 = *(const float4*)(op + 4);
      o[0] += p0.x; o[1] += p0.y; o[2] += p0.z; o[3] += p0.w;
      o[4] += p1.x; o[5] += p1.y; o[6] += p1.z; o[7] += p1.w;
    }
    if (last) {
      float4 b0 = *(const float4*)&bias[d0];
      float4 b1 = *(const float4*)&bias[d0 + 4];
      o[0] += b0.x; o[1] += b0.y; o[2] += b0.z; o[3] += b0.w;
      o[4] += b1.x; o[5] += b1.y; o[6] += b1.z; o[7] += b1.w;
    }
    *(float4*)op       = make_float4(o[0], o[1], o[2], o[3]);
    *(float4*)(op + 4) = make_float4(o[4], o[5], o[6], o[7]);
  }
}

// ---------------------------------------------------------------------------
extern "C" void kernel_launch(void* const* d_in, const int* in_sizes, int n_in,
                              void* d_out, int out_size, void* d_ws, size_t ws_size,
                              hipStream_t stream) {
  const float* x     = (const float*)d_in[0];
  const int*   ei    = (const int*)  d_in[1];
  const float* Wl0   = (const float*)d_in[2];
  const float* bl0   = (const float*)d_in[3];
  const float* Wr0   = (const float*)d_in[4];
  const float* br0   = (const float*)d_in[5];
  const float* att0  = (const float*)d_in[6];
  const float* bias0 = (const float*)d_in[7];
  const float* Wl1   = (const float*)d_in[8];
  const float* bl1   = (const float*)d_in[9];
  const float* Wr1   = (const float*)d_in[10];
  const float* br1   = (const float*)d_in[11];
  const float* att1  = (const float*)d_in[12];
  const float* bias1 = (const float*)d_in[13];
  const float* Wl2   = (const float*)d_in[14];
  const float* bl2   = (const float*)d_in[15];
  const float* Wr2   = (const float*)d_in[16];
  const float* br2   = (const float*)d_in[17];
  const float* att2  = (const float*)d_in[18];
  const float* bias2 = (const float*)d_in[19];

  const int N = in_sizes[0] / 128;
  const int E = in_sizes[1] / 2;

  char* p = (char*)d_ws;
  auto alloc = [&](size_t bytes) {
    void* q = (void*)p;
    p += (bytes + 255) & ~(size_t)255;
    return q;
  };
  auto al = [](size_t b) { return (b + 255) & ~(size_t)255; };
  const size_t common = al((size_t)(N + 1) * 4) + 2 * al((size_t)N * 4) +
                        al((size_t)(E + N) * 4) + al((size_t)512) +
                        2 * al((size_t)N * 128 * 2) +
                        8 * al((size_t)128 * 128 * 2) +
                        4 * al((size_t)512 * 128 * 2) +
                        2 * al((size_t)512 * 128 * 2);
  const size_t need_fused = common + 2 * al((size_t)N * 512 * 2);
  const bool fused = ws_size >= need_fused;   // deterministic across calls

  int* offs    = (int*)alloc((size_t)(N + 1) * 4);
  int* degree  = (int*)alloc((size_t)N * 4);
  int* cursor  = (int*)alloc((size_t)N * 4);
  int* csr_src = (int*)alloc((size_t)(E + N) * 4);
  int* partial = (int*)alloc((size_t)512);
  unsigned short* Agh = (unsigned short*)alloc((size_t)N * 128 * 2);
  unsigned short* Agl = (unsigned short*)alloc((size_t)N * 128 * 2);
  unsigned short* W0hl = (unsigned short*)alloc((size_t)128 * 128 * 2);
  unsigned short* W0ll = (unsigned short*)alloc((size_t)128 * 128 * 2);
  unsigned short* W0hr = (unsigned short*)alloc((size_t)128 * 128 * 2);
  unsigned short* W0lr = (unsigned short*)alloc((size_t)128 * 128 * 2);
  unsigned short* W1hl = (unsigned short*)alloc((size_t)128 * 128 * 2);
  unsigned short* W1ll = (unsigned short*)alloc((size_t)128 * 128 * 2);
  unsigned short* W1hr = (unsigned short*)alloc((size_t)128 * 128 * 2);
  unsigned short* W1lr = (unsigned short*)alloc((size_t)128 * 128 * 2);
  unsigned short* W2hl = (unsigned short*)alloc((size_t)512 * 128 * 2);
  unsigned short* W2ll = (unsigned short*)alloc((size_t)512 * 128 * 2);
  unsigned short* W2hr = (unsigned short*)alloc((size_t)512 * 128 * 2);
  unsigned short* W2lr = (unsigned short*)alloc((size_t)512 * 128 * 2);
  __half* W2fl = (__half*)alloc((size_t)512 * 128 * 2);   // fp16 W2 (fused)
  __half* W2fr = (__half*)alloc((size_t)512 * 128 * 2);
  __half* xl4 = nullptr; __half* xr4 = nullptr;   // fused: fp16 [N,512]
  float* xl = nullptr; float* xr = nullptr;       // fallback fp32 [N,128]
  __half* xl16 = nullptr; __half* xr16 = nullptr; // fused: fp16 [N,128] views
  if (fused) {
    xl4 = (__half*)alloc((size_t)N * 512 * 2);
    xr4 = (__half*)alloc((size_t)N * 512 * 2);
    xl16 = xl4;              // layers 0/1 alias the big buffers ([N,128] fp16)
    xr16 = xr4;
  } else {
    xl = (float*)alloc((size_t)N * 128 * 4);
    xr = (float*)alloc((size_t)N * 128 * 4);
  }
  __half* A16 = (__half*)Agh;    // layer-2 fp16 A aliases Agh (free then)
  (void)n_in; (void)out_size;

  const int nb = (N + 1023) / 1024;

  // CSR build (ws is re-poisoned each call, so rebuild every launch)
  k_init<<<(N + 255) / 256, 256, 0, stream>>>(degree, cursor, N);
  k_hist<<<(E + 255) / 256, 256, 0, stream>>>(ei, E, degree);
  k_scan1<<<nb, 256, 0, stream>>>(degree, partial, N);
  k_scan2<<<1, 256, 0, stream>>>(partial, nb);
  k_scan3<<<nb, 256, 0, stream>>>(degree, partial, offs, N);
  k_scatter<<<(E + N + 255) / 256, 256, 0, stream>>>(ei, E, N, offs, cursor, csr_src);

  // one prep dispatch: all weight preps + layer-0 A split
  const int prepT = 327680 + (N * 128 + 3) / 4;
  k_prep<<<(prepT + 255) / 256, 256, 0, stream>>>(
      Wl0, Wr0, Wl1, Wr1, Wl2, Wr2,
      W0hl, W0ll, W0hr, W0lr, W1hl, W1ll, W1hr, W1lr,
      W2hl, W2ll, W2hr, W2lr, W2fl, W2fr, x, Agh, Agl, N * 128);

  const int mb = (N + 127) / 128;        // M tiles
  const dim3 gg(mb, 2);                  // layer-0/1 GEMM grid
  const dim3 gg4(mb, 2, 4);              // layer-2 GEMM grid (z = head)
  const int gb = (N + 3) / 4;            // gather grid (4 nodes / block)

  if (fused) {
    // layer 0
    k_gemm2s<<<gg, 256, 0, stream>>>(Agh, Agl, W0hl, W0ll, W0hr, W0lr,
                                     bl0, br0, xl16, xr16, N, 128, 0, 1);
    k_gat_small16<<<gb, 256, 0, stream>>>(xl16, xr16, att0, bias0, offs, degree,
                                          csr_src, Agh, Agl, nullptr, 0, N);
    // layer 1
    k_gemm2s<<<gg, 256, 0, stream>>>(Agh, Agl, W1hl, W1ll, W1hr, W1lr,
                                     bl1, br1, xl16, xr16, N, 128, 0, 1);
    k_gat_small16<<<gb, 256, 0, stream>>>(xl16, xr16, att1, bias1, offs, degree,
                                          csr_src, nullptr, nullptr, A16, 1, N);
    // layer 2: single-term fp16 GEMM, z = head slice
    k_gemm2h<<<gg4, 256, 0, stream>>>(A16, W2fl, W2fr, bl2, br2, xl4, xr4, N);
    k_gat_fused4<<<gb, 256, 0, stream>>>(xl4, xr4, att2, bias2, offs, degree,
                                         csr_src, (float*)d_out, N);
  } else {
    // layer 0
    k_gemm2s<<<gg, 256, 0, stream>>>(Agh, Agl, W0hl, W0ll, W0hr, W0lr,
                                     bl0, br0, xl, xr, N, 128, 0, 0);
    k_gat_small<<<gb, 256, 0, stream>>>(xl, xr, att0, bias0, offs, degree, csr_src,
                                        Agh, Agl, N);
    // layer 1
    k_gemm2s<<<gg, 256, 0, stream>>>(Agh, Agl, W1hl, W1ll, W1hr, W1lr,
                                     bl1, br1, xl, xr, N, 128, 0, 0);
    k_gat_small<<<gb, 256, 0, stream>>>(xl, xr, att1, bias1, offs, degree, csr_src,
                                        Agh, Agl, N);
    // layer 2 per head (full 3-term precision)
    for (int h = 0; h < 4; h++) {
      const int wo = h * 128 * 128;
      k_gemm2s<<<gg, 256, 0, stream>>>(Agh, Agl, W2hl + wo, W2ll + wo,
                                       W2hr + wo, W2lr + wo,
                                       bl2 + h * 128, br2 + h * 128,
                                       xl, xr, N, 128, 0, 0);
      k_gat_head<<<gb, 256, 0, stream>>>(xl, xr, att2 + h * 128, bias2, offs, degree,
                                         csr_src, (float*)d_out, N,
                                         h == 0 ? 1 : 0, h == 3 ? 1 : 0);
    }
  }
}

// Round 6
// 924.190 us; speedup vs baseline: 1.2311x; 1.0299x over previous
//
#include <hip/hip_runtime.h>
#include <hip/hip_fp16.h>
#include <cstddef>

// ---------------------------------------------------------------------------
// GATv2 backbone: 3 layers, N=100k nodes, E=1.6M edges (+self loops), H=4.
//   - CSR by dst built once (histogram + 3-kernel multi-block scan + scatter).
//   - ALL GEMMs (fused path): single-term fp16 MFMA k_gemm2h (A fp16, W fp16,
//     fp32 accum). r5 evidence: fp16 single-term == 3-term split-bf16 within
//     the fp16 output quantization the pipeline already carries (absmax
//     unchanged through 5 precision reductions). 1/3 MFMA, 1/2 staging.
//   - Gathers: fp16 rows, packed-fp16 logits, fp32 value acc, fp16 A out.
//   - Layer 2: ONE fused gather over fp16 [N,512]. r1/r4/r5 evidence: ~3.7
//     TB/s / 878 MB L2-miss traffic invariant across schedules -> memory-path
//     bound, left alone.
//   - One k_prep dispatch: weight preps + x->fp16 (fused) or splits (fallback).
//   - Fallback path (tiny ws): original fp32 3-term pipeline, unchanged.
// ---------------------------------------------------------------------------

typedef __attribute__((ext_vector_type(8))) short bf16x8;
typedef _Float16 f16x8 __attribute__((ext_vector_type(8)));
typedef __attribute__((ext_vector_type(4))) float f32x4;
typedef _Float16 f16x2 __attribute__((ext_vector_type(2)));
typedef float f32x2 __attribute__((ext_vector_type(2)));

#if defined(__has_builtin)
#if __has_builtin(__builtin_amdgcn_fdot2)
#define HAS_FDOT2 1
#endif
#endif

__device__ __forceinline__ float lrelu(float x) { return fmaxf(x, 0.2f * x); }

// 16B row-fragment load at 32-bit byte offset
__device__ __forceinline__ uint4 ldrow(const void* base, unsigned byteoff) {
  return *(const uint4*)((const char*)base + byteoff);
}

// RNE fp32 -> bf16 hi + bf16 residual
__device__ __forceinline__ void split2(float x, unsigned short& h, unsigned short& l) {
  unsigned b = __float_as_uint(x);
  unsigned r = b + 0x7fffu + ((b >> 16) & 1u);
  h = (unsigned short)(r >> 16);
  float hf = __uint_as_float((unsigned)h << 16);
  float res = x - hf;
  unsigned b2 = __float_as_uint(res);
  unsigned r2 = b2 + 0x7fffu + ((b2 >> 16) & 1u);
  l = (unsigned short)(r2 >> 16);
}

// ---------------- CSR build ----------------
__global__ void k_init(int* __restrict__ degree, int* __restrict__ cursor, int N) {
  int i = blockIdx.x * blockDim.x + threadIdx.x;
  if (i < N) { degree[i] = 1; cursor[i] = 0; }  // 1 accounts for the self-loop
}

__global__ void k_hist(const int* __restrict__ ei, int E, int* __restrict__ degree) {
  int e = blockIdx.x * blockDim.x + threadIdx.x;
  if (e < E) atomicAdd(&degree[ei[E + e]], 1);
}

// --- 3-kernel scan: per-block sums -> scan of sums -> per-block scan+base ---
__global__ __launch_bounds__(256) void k_scan1(const int* __restrict__ degree,
                                               int* __restrict__ partial, int N) {
  __shared__ int ws[4];
  const int i0 = blockIdx.x * 1024 + threadIdx.x * 4;
  int s = 0;
  if (i0 + 3 < N) {
    int4 v = *(const int4*)&degree[i0];
    s = v.x + v.y + v.z + v.w;
  } else {
    #pragma unroll
    for (int k = 0; k < 4; k++) if (i0 + k < N) s += degree[i0 + k];
  }
  #pragma unroll
  for (int d = 1; d < 64; d <<= 1) s += __shfl_xor(s, d);
  const int lane = threadIdx.x & 63, wid = threadIdx.x >> 6;
  if (lane == 0) ws[wid] = s;
  __syncthreads();
  if (threadIdx.x == 0) partial[blockIdx.x] = ws[0] + ws[1] + ws[2] + ws[3];
}

__global__ __launch_bounds__(256) void k_scan2(int* __restrict__ partial, int nb) {
  __shared__ int sh[256];
  const int tid = threadIdx.x;
  int v = (tid < nb) ? partial[tid] : 0;
  sh[tid] = v;
  __syncthreads();
  for (int d = 1; d < 256; d <<= 1) {
    int t = (tid >= d) ? sh[tid - d] : 0;
    __syncthreads();
    sh[tid] += t;
    __syncthreads();
  }
  if (tid < nb) partial[tid] = sh[tid] - v;   // exclusive base per block
}

__global__ __launch_bounds__(256) void k_scan3(const int* __restrict__ degree,
                                               const int* __restrict__ partial,
                                               int* __restrict__ offs, int N) {
  __shared__ int wsum[4];
  const int tid = threadIdx.x, lane = tid & 63, wid = tid >> 6;
  const int i0 = blockIdx.x * 1024 + tid * 4;
  int v0 = 0, v1 = 0, v2 = 0, v3 = 0;
  if (i0 + 3 < N) {
    int4 v = *(const int4*)&degree[i0];
    v0 = v.x; v1 = v.y; v2 = v.z; v3 = v.w;
  } else {
    if (i0     < N) v0 = degree[i0];
    if (i0 + 1 < N) v1 = degree[i0 + 1];
    if (i0 + 2 < N) v2 = degree[i0 + 2];
    if (i0 + 3 < N) v3 = degree[i0 + 3];
  }
  int s = v0 + v1 + v2 + v3, x = s;
  #pragma unroll
  for (int d = 1; d < 64; d <<= 1) {
    int y = __shfl_up(x, d);
    if (lane >= d) x += y;
  }
  if (lane == 63) wsum[wid] = x;
  __syncthreads();
  if (tid < 4) {
    int t = wsum[tid];
    #pragma unroll
    for (int d = 1; d < 4; d <<= 1) {
      int y = __shfl_up(t, d);
      if (tid >= d) t += y;
    }
    wsum[tid] = t;
  }
  __syncthreads();
  const int wbase = wid ? wsum[wid - 1] : 0;
  int e = partial[blockIdx.x] + wbase + (x - s);
  if (i0     < N) offs[i0]     = e;  e += v0;  if (i0     == N - 1) offs[N] = e;
  if (i0 + 1 < N) offs[i0 + 1] = e;  e += v1;  if (i0 + 1 == N - 1) offs[N] = e;
  if (i0 + 2 < N) offs[i0 + 2] = e;  e += v2;  if (i0 + 2 == N - 1) offs[N] = e;
  if (i0 + 3 < N) offs[i0 + 3] = e;  e += v3;  if (i0 + 3 == N - 1) offs[N] = e;
}

__global__ void k_scatter(const int* __restrict__ ei, int E, int N,
                          const int* __restrict__ offs, int* __restrict__ cursor,
                          int* __restrict__ csr_src) {
  int t = blockIdx.x * blockDim.x + threadIdx.x;
  int ET = E + N;
  if (t >= ET) return;
  int s, d;
  if (t < E) { s = ei[t]; d = ei[E + t]; }
  else       { s = t - E; d = s; }
  int pos = offs[d] + atomicAdd(&cursor[d], 1);
  csr_src[pos] = s;
}

// ---- ONE prep dispatch ------------------------------------------------------
// [0,196608): bf16 splits of all 6 W (fallback only, cheap).
// [196608,327680): W2 fp16 transpose. [327680,393216): W0/W1 fp16 transpose.
// [393216,...): x -> fp16 A16x (fused) or split-bf16 Agh/Agl (fallback).
__global__ __launch_bounds__(256) void k_prep(
    const float* __restrict__ Wl0, const float* __restrict__ Wr0,
    const float* __restrict__ Wl1, const float* __restrict__ Wr1,
    const float* __restrict__ Wl2, const float* __restrict__ Wr2,
    unsigned short* __restrict__ W0hl, unsigned short* __restrict__ W0ll,
    unsigned short* __restrict__ W0hr, unsigned short* __restrict__ W0lr,
    unsigned short* __restrict__ W1hl, unsigned short* __restrict__ W1ll,
    unsigned short* __restrict__ W1hr, unsigned short* __restrict__ W1lr,
    unsigned short* __restrict__ W2hl, unsigned short* __restrict__ W2ll,
    unsigned short* __restrict__ W2hr, unsigned short* __restrict__ W2lr,
    __half* __restrict__ W0fl, __half* __restrict__ W0fr,
    __half* __restrict__ W1fl, __half* __restrict__ W1fr,
    __half* __restrict__ W2fl, __half* __restrict__ W2fr,
    const float* __restrict__ X, __half* __restrict__ A16x,
    unsigned short* __restrict__ Ah, unsigned short* __restrict__ Al,
    int totalA, int fusedF) {
  const int t = blockIdx.x * blockDim.x + threadIdx.x;
  if (t < 196608) {
    const float* W; unsigned short *Whp, *Wlp; int idx, sh;
    if (t < 16384)       { W = Wl0; Whp = W0hl; Wlp = W0ll; idx = t;          sh = 7; }
    else if (t < 32768)  { W = Wr0; Whp = W0hr; Wlp = W0lr; idx = t - 16384;  sh = 7; }
    else if (t < 49152)  { W = Wl1; Whp = W1hl; Wlp = W1ll; idx = t - 32768;  sh = 7; }
    else if (t < 65536)  { W = Wr1; Whp = W1hr; Wlp = W1lr; idx = t - 49152;  sh = 7; }
    else if (t < 131072) { W = Wl2; Whp = W2hl; Wlp = W2ll; idx = t - 65536;  sh = 9; }
    else                 { W = Wr2; Whp = W2hr; Wlp = W2lr; idx = t - 131072; sh = 9; }
    const int n = idx & ((1 << sh) - 1), k = idx >> sh;
    unsigned short h, l;
    split2(W[idx], h, l);
    Whp[(size_t)n * 128 + k] = h;
    Wlp[(size_t)n * 128 + k] = l;
    return;
  }
  if (t < 327680) {               // W2 fp16 transpose (512-col)
    const int u = t - 196608;
    const float* W = (u < 65536) ? Wl2 : Wr2;
    __half* O = (u < 65536) ? W2fl : W2fr;
    const int idx = (u < 65536) ? u : u - 65536;
    const int n = idx & 511, k = idx >> 9;
    O[(size_t)n * 128 + k] = __float2half(W[idx]);
    return;
  }
  if (t < 393216) {               // W0/W1 fp16 transpose (128-col)
    const int u = t - 327680;
    const float* W; __half* O; int idx;
    if (u < 16384)      { W = Wl0; O = W0fl; idx = u; }
    else if (u < 32768) { W = Wr0; O = W0fr; idx = u - 16384; }
    else if (u < 49152) { W = Wl1; O = W1fl; idx = u - 32768; }
    else                { W = Wr1; O = W1fr; idx = u - 49152; }
    const int n = idx & 127, k = idx >> 7;
    O[(size_t)n * 128 + k] = __float2half(W[idx]);
    return;
  }
  const int t4 = (t - 393216) * 4;
  if (t4 >= totalA) return;
  float4 v = *(const float4*)&X[t4];
  if (fusedF) {
    union { uint2 u; __half h[4]; } ou;
    ou.h[0] = __float2half(v.x); ou.h[1] = __float2half(v.y);
    ou.h[2] = __float2half(v.z); ou.h[3] = __float2half(v.w);
    *(uint2*)&A16x[t4] = ou.u;
  } else {
    unsigned short h0, h1, h2, h3, l0, l1, l2, l3;
    split2(v.x, h0, l0); split2(v.y, h1, l1);
    split2(v.z, h2, l2); split2(v.w, h3, l3);
    uint2 hv, lv;
    hv.x = (unsigned)h0 | ((unsigned)h1 << 16);
    hv.y = (unsigned)h2 | ((unsigned)h3 << 16);
    lv.x = (unsigned)l0 | ((unsigned)l1 << 16);
    lv.y = (unsigned)l2 | ((unsigned)l3 << 16);
    *(uint2*)&Ah[t4] = hv;
    *(uint2*)&Al[t4] = lv;
  }
}

// ---------------- split-bf16 MFMA GEMM (3-term, FALLBACK only) --------------
__global__ __launch_bounds__(256) void k_gemm2s(
    const unsigned short* __restrict__ Agh, const unsigned short* __restrict__ Agl,
    const unsigned short* __restrict__ Whl, const unsigned short* __restrict__ Wll,
    const unsigned short* __restrict__ Whr, const unsigned short* __restrict__ Wlr,
    const float* __restrict__ bias_l, const float* __restrict__ bias_r,
    void* __restrict__ Clp, void* __restrict__ Crp, int N,
    int ldC, int coloff, int out_half) {
  __shared__ unsigned short Ah_s[128][40];   // row pad 40 (80 B = 5 superbanks)
  __shared__ unsigned short Al_s[128][40];
  __shared__ unsigned short Wh_s[128][40];
  __shared__ unsigned short Wl_s[128][40];
  const int hsel = blockIdx.z;
  const unsigned short* __restrict__ Wth = (blockIdx.y ? Whr : Whl) + hsel * 128 * 128;
  const unsigned short* __restrict__ Wtl = (blockIdx.y ? Wlr : Wll) + hsel * 128 * 128;
  const float* __restrict__ bias = (blockIdx.y ? bias_r : bias_l) + hsel * 128;
  void* __restrict__ Cp = blockIdx.y ? Crp : Clp;
  coloff += hsel * 128;

  const int tid = threadIdx.x;
  const int m0 = blockIdx.x * 128;
  const int wv = tid >> 6, lane = tid & 63;
  const int wm = (wv >> 1) * 64, wn = (wv & 1) * 64;
  const int l15 = lane & 15, kb = (lane >> 4) * 8;
  f32x4 acc[4][4] = {};

  const int r = tid >> 1;              // staging row 0..127
  const int cb = (tid & 1) * 16;       // staging col base 0/16
  const bool arow_ok = (m0 + r) < N;
  const unsigned short* ahp = Agh + (size_t)(m0 + r) * 128 + cb;
  const unsigned short* alp = Agl + (size_t)(m0 + r) * 128 + cb;
  const unsigned short* whp = Wth + r * 128 + cb;
  const unsigned short* wlp = Wtl + r * 128 + cb;
  const uint4 z4 = make_uint4(0, 0, 0, 0);

  uint4 pa0, pa1, pl0, pl1, pw0, pw1, pq0, pq1;
  #define LOADC(K0)                                                           \
    pa0 = arow_ok ? *(const uint4*)(ahp + (K0))     : z4;                     \
    pa1 = arow_ok ? *(const uint4*)(ahp + (K0) + 8) : z4;                     \
    pl0 = arow_ok ? *(const uint4*)(alp + (K0))     : z4;                     \
    pl1 = arow_ok ? *(const uint4*)(alp + (K0) + 8) : z4;                     \
    pw0 = *(const uint4*)(whp + (K0));                                        \
    pw1 = *(const uint4*)(whp + (K0) + 8);                                    \
    pq0 = *(const uint4*)(wlp + (K0));                                        \
    pq1 = *(const uint4*)(wlp + (K0) + 8);
  LOADC(0)
  for (int kc = 0; kc < 4; kc++) {
    *(uint4*)&Ah_s[r][cb]     = pa0;
    *(uint4*)&Ah_s[r][cb + 8] = pa1;
    *(uint4*)&Al_s[r][cb]     = pl0;
    *(uint4*)&Al_s[r][cb + 8] = pl1;
    *(uint4*)&Wh_s[r][cb]     = pw0;
    *(uint4*)&Wh_s[r][cb + 8] = pw1;
    *(uint4*)&Wl_s[r][cb]     = pq0;
    *(uint4*)&Wl_s[r][cb + 8] = pq1;
    __syncthreads();
    if (kc < 3) { LOADC((kc + 1) * 32) }   // in flight during MFMA below

    bf16x8 afh[4], afl[4];
    #pragma unroll
    for (int mi = 0; mi < 4; mi++) {
      const int row = wm + mi * 16 + l15;
      afh[mi] = *(const bf16x8*)&Ah_s[row][kb];
      afl[mi] = *(const bf16x8*)&Al_s[row][kb];
    }
    #pragma unroll
    for (int ni = 0; ni < 4; ni++) {
      const int rown = wn + ni * 16 + l15;
      bf16x8 bh = *(const bf16x8*)&Wh_s[rown][kb];
      bf16x8 bl = *(const bf16x8*)&Wl_s[rown][kb];
      #pragma unroll
      for (int mi = 0; mi < 4; mi++) {
        acc[mi][ni] = __builtin_amdgcn_mfma_f32_16x16x32_bf16(afh[mi], bh, acc[mi][ni], 0, 0, 0);
        acc[mi][ni] = __builtin_amdgcn_mfma_f32_16x16x32_bf16(afl[mi], bh, acc[mi][ni], 0, 0, 0);
        acc[mi][ni] = __builtin_amdgcn_mfma_f32_16x16x32_bf16(afh[mi], bl, acc[mi][ni], 0, 0, 0);
      }
    }
    __syncthreads();
  }
  #undef LOADC
  const int col = l15, rbase = (lane >> 4) * 4;
  #pragma unroll
  for (int ni = 0; ni < 4; ni++) {
    const int gn = wn + ni * 16 + col;
    const float bv = bias[gn];
    #pragma unroll
    for (int mi = 0; mi < 4; mi++) {
      #pragma unroll
      for (int q = 0; q < 4; q++) {
        const int gm = m0 + wm + mi * 16 + rbase + q;
        if (gm < N) {
          float v = acc[mi][ni][q] + bv;
          if (out_half) ((__half*)Cp)[(size_t)gm * ldC + coloff + gn] = __float2half(v);
          else          ((float*)Cp)[(size_t)gm * ldC + coloff + gn] = v;
        }
      }
    }
  }
}

// ---------------- fp16 single-term MFMA GEMM (all fused-path GEMMs) ---------
// A fp16 [N,128], W fp16 transposed [outcols][128]. blockIdx.y = l/r,
// blockIdx.z = head slice (0 for 128-wide). fp32 accum, fp16 out.
__global__ __launch_bounds__(256) void k_gemm2h(
    const __half* __restrict__ A16,
    const __half* __restrict__ Wfl, const __half* __restrict__ Wfr,
    const float* __restrict__ bias_l, const float* __restrict__ bias_r,
    __half* __restrict__ Clp, __half* __restrict__ Crp, int N, int ldC) {
  __shared__ __half A_s[128][40];
  __shared__ __half W_s[128][40];
  const int hsel = blockIdx.z;
  const __half* __restrict__ Wt = (blockIdx.y ? Wfr : Wfl) + hsel * 128 * 128;
  const float* __restrict__ bias = (blockIdx.y ? bias_r : bias_l) + hsel * 128;
  __half* __restrict__ Cp = blockIdx.y ? Crp : Clp;
  const int coloff = hsel * 128;

  const int tid = threadIdx.x;
  const int m0 = blockIdx.x * 128;
  const int wv = tid >> 6, lane = tid & 63;
  const int wm = (wv >> 1) * 64, wn = (wv & 1) * 64;
  const int l15 = lane & 15, kb = (lane >> 4) * 8;
  f32x4 acc[4][4] = {};

  const int r = tid >> 1;              // staging row 0..127
  const int cb = (tid & 1) * 16;       // staging col base 0/16
  const bool arow_ok = (m0 + r) < N;
  const __half* ap = A16 + (size_t)(m0 + r) * 128 + cb;
  const __half* wp = Wt + r * 128 + cb;
  const uint4 z4 = make_uint4(0, 0, 0, 0);

  uint4 pa0, pa1, pw0, pw1;
  #define LOADH(K0)                                                           \
    pa0 = arow_ok ? *(const uint4*)(ap + (K0))     : z4;                      \
    pa1 = arow_ok ? *(const uint4*)(ap + (K0) + 8) : z4;                      \
    pw0 = *(const uint4*)(wp + (K0));                                         \
    pw1 = *(const uint4*)(wp + (K0) + 8);
  LOADH(0)
  for (int kc = 0; kc < 4; kc++) {
    *(uint4*)&A_s[r][cb]     = pa0;
    *(uint4*)&A_s[r][cb + 8] = pa1;
    *(uint4*)&W_s[r][cb]     = pw0;
    *(uint4*)&W_s[r][cb + 8] = pw1;
    __syncthreads();
    if (kc < 3) { LOADH((kc + 1) * 32) }   // in flight during MFMA below

    f16x8 af[4];
    #pragma unroll
    for (int mi = 0; mi < 4; mi++)
      af[mi] = *(const f16x8*)&A_s[wm + mi * 16 + l15][kb];
    #pragma unroll
    for (int ni = 0; ni < 4; ni++) {
      f16x8 bh = *(const f16x8*)&W_s[wn + ni * 16 + l15][kb];
      #pragma unroll
      for (int mi = 0; mi < 4; mi++)
        acc[mi][ni] = __builtin_amdgcn_mfma_f32_16x16x32_f16(af[mi], bh, acc[mi][ni], 0, 0, 0);
    }
    __syncthreads();
  }
  #undef LOADH
  const int col = l15, rbase = (lane >> 4) * 4;
  #pragma unroll
  for (int ni = 0; ni < 4; ni++) {
    const int gn = wn + ni * 16 + col;
    const float bv = bias[gn];
    #pragma unroll
    for (int mi = 0; mi < 4; mi++) {
      #pragma unroll
      for (int q = 0; q < 4; q++) {
        const int gm = m0 + wm + mi * 16 + rbase + q;
        if (gm < N)
          Cp[(size_t)gm * ldC + coloff + gn] = __float2half(acc[mi][ni][q] + bv);
      }
    }
  }
}

// -------- butterfly ADD merge of per-group partials (plain-exp softmax) -----
#define MERGE_ADD(d)                                                          \
  {                                                                           \
    l += __shfl_xor(l, d);                                                    \
    aca.x += __shfl_xor(aca.x, d); aca.y += __shfl_xor(aca.y, d);             \
    aca.z += __shfl_xor(aca.z, d); aca.w += __shfl_xor(aca.w, d);             \
    acb.x += __shfl_xor(acb.x, d); acb.y += __shfl_xor(acb.y, d);             \
    acb.z += __shfl_xor(acb.z, d); acb.w += __shfl_xor(acb.w, d);             \
  }

// ---------------- fused GATv2 gather, layers 0/1 (fp32 fallback) ------------
__global__ __launch_bounds__(256) void k_gat_small(
    const float* __restrict__ xl, const float* __restrict__ xr,
    const float* __restrict__ att, const float* __restrict__ bias,
    const int* __restrict__ offs, const int* __restrict__ degree,
    const int* __restrict__ csr_src,
    unsigned short* __restrict__ Ah, unsigned short* __restrict__ Al, int N) {
  const int node = blockIdx.x * 4 + (threadIdx.x >> 6);
  if (node >= N) return;
  const int lane = threadIdx.x & 63;
  const int g = lane >> 4;
  const int c = lane & 15;
  const int d0 = c * 8;
  const size_t nb = (size_t)node * 128 + d0;
  const float4 xra = *(const float4*)&xr[nb];
  const float4 xrb = *(const float4*)&xr[nb + 4];
  const float4 ata = *(const float4*)&att[d0];
  const float4 atb = *(const float4*)&att[d0 + 4];
  const int off = offs[node];
  const int deg = degree[node];
  float l = 0.f;
  float4 aca = make_float4(0.f, 0.f, 0.f, 0.f);
  float4 acb = make_float4(0.f, 0.f, 0.f, 0.f);
  int s0 = (g < deg) ? csr_src[off + g] : 0;
  int s1 = (g + 4 < deg) ? csr_src[off + g + 4] : 0;
  for (int j = g; j < deg; j += 8) {
    int sn0 = (j + 8 < deg) ? csr_src[off + j + 8] : 0;
    int sn1 = (j + 12 < deg) ? csr_src[off + j + 12] : 0;
    const size_t sb0 = (size_t)s0 * 128 + d0;
    const size_t sb1 = (size_t)s1 * 128 + d0;
    float4 xa0 = *(const float4*)&xl[sb0];
    float4 xb0 = *(const float4*)&xl[sb0 + 4];
    float4 xa1 = *(const float4*)&xl[sb1];
    float4 xb1 = *(const float4*)&xl[sb1 + 4];
    float t0 = lrelu(xa0.x + xra.x) * ata.x + lrelu(xa0.y + xra.y) * ata.y +
               lrelu(xa0.z + xra.z) * ata.z + lrelu(xa0.w + xra.w) * ata.w +
               lrelu(xb0.x + xrb.x) * atb.x + lrelu(xb0.y + xrb.y) * atb.y +
               lrelu(xb0.z + xrb.z) * atb.z + lrelu(xb0.w + xrb.w) * atb.w;
    float t1 = lrelu(xa1.x + xra.x) * ata.x + lrelu(xa1.y + xra.y) * ata.y +
               lrelu(xa1.z + xra.z) * ata.z + lrelu(xa1.w + xra.w) * ata.w +
               lrelu(xb1.x + xrb.x) * atb.x + lrelu(xb1.y + xrb.y) * atb.y +
               lrelu(xb1.z + xrb.z) * atb.z + lrelu(xb1.w + xrb.w) * atb.w;
    t0 += __shfl_xor(t0, 1);
    t0 += __shfl_xor(t0, 2);       // 4-lane head cluster -> per-head logit
    t1 += __shfl_xor(t1, 1);
    t1 += __shfl_xor(t1, 2);
    float p0 = __expf(t0);
    float p1 = (j + 4 < deg) ? __expf(t1) : 0.f;
    aca.x += p0 * xa0.x + p1 * xa1.x; aca.y += p0 * xa0.y + p1 * xa1.y;
    aca.z += p0 * xa0.z + p1 * xa1.z; aca.w += p0 * xa0.w + p1 * xa1.w;
    acb.x += p0 * xb0.x + p1 * xb1.x; acb.y += p0 * xb0.y + p1 * xb1.y;
    acb.z += p0 * xb0.z + p1 * xb1.z; acb.w += p0 * xb0.w + p1 * xb1.w;
    l += p0 + p1;
    s0 = sn0; s1 = sn1;
  }
  MERGE_ADD(16)
  MERGE_ADD(32)
  if (lane < 16) {
    const float inv = 1.f / l;
    const float4 b0 = *(const float4*)&bias[d0];
    const float4 b1 = *(const float4*)&bias[d0 + 4];
    float o[8] = {aca.x * inv + b0.x, aca.y * inv + b0.y,
                  aca.z * inv + b0.z, aca.w * inv + b0.w,
                  acb.x * inv + b1.x, acb.y * inv + b1.y,
                  acb.z * inv + b1.z, acb.w * inv + b1.w};
    unsigned short hs[8], ls[8];
    #pragma unroll
    for (int i = 0; i < 8; i++) {
      o[i] = o[i] > 0.f ? o[i] : __expf(o[i]) - 1.f;   // ELU
      split2(o[i], hs[i], ls[i]);
    }
    uint4 hv, lv;
    hv.x = (unsigned)hs[0] | ((unsigned)hs[1] << 16);
    hv.y = (unsigned)hs[2] | ((unsigned)hs[3] << 16);
    hv.z = (unsigned)hs[4] | ((unsigned)hs[5] << 16);
    hv.w = (unsigned)hs[6] | ((unsigned)hs[7] << 16);
    lv.x = (unsigned)ls[0] | ((unsigned)ls[1] << 16);
    lv.y = (unsigned)ls[2] | ((unsigned)ls[3] << 16);
    lv.z = (unsigned)ls[4] | ((unsigned)ls[5] << 16);
    lv.w = (unsigned)ls[6] | ((unsigned)ls[7] << 16);
    *(uint4*)&Ah[nb] = hv;
    *(uint4*)&Al[nb] = lv;
  }
}

// ---------------- packed-fp16 edge steps ------------------------------------
// 512-wide (layer 2): 16-lane head group reduce (4 shfl)
__device__ __forceinline__ void edge_step(uint4 vv, bool valid,
                                          const f16x2* xrh, const f16x2* ath,
                                          f32x2* accv, float& l) {
  union { uint4 u; f16x2 h[4]; } xu; xu.u = vv;
  const f16x2 c02 = {(_Float16)0.2f, (_Float16)0.2f};
  float t = 0.f;
#if defined(HAS_FDOT2)
  #pragma unroll
  for (int i = 0; i < 4; i++) {
    f16x2 s = xu.h[i] + xrh[i];
    f16x2 lr = __builtin_elementwise_max(s, s * c02);
    t = __builtin_amdgcn_fdot2(lr, ath[i], t, false);
  }
#else
  #pragma unroll
  for (int i = 0; i < 4; i++) {
    f32x2 s = __builtin_convertvector(xu.h[i], f32x2) +
              __builtin_convertvector(xrh[i], f32x2);
    f32x2 a = __builtin_convertvector(ath[i], f32x2);
    t += fmaxf(s.x, 0.2f * s.x) * a.x + fmaxf(s.y, 0.2f * s.y) * a.y;
  }
#endif
  t += __shfl_xor(t, 1);
  t += __shfl_xor(t, 2);
  t += __shfl_xor(t, 4);
  t += __shfl_xor(t, 8);         // 16-lane head group -> head logit
  float p = valid ? __expf(t) : 0.f;
  l += p;
  f32x2 p2 = {p, p};
  #pragma unroll
  for (int i = 0; i < 4; i++)
    accv[i] += p2 * __builtin_convertvector(xu.h[i], f32x2);  // v_pk_fma_f32
}

// 128-wide (layers 0/1): 4-lane head cluster reduce (2 shfl), all edges valid
__device__ __forceinline__ void edge_step_small(uint4 vv,
                                                const f16x2* xrh, const f16x2* ath,
                                                f32x2* accv, float& l) {
  union { uint4 u; f16x2 h[4]; } xu; xu.u = vv;
  const f16x2 c02 = {(_Float16)0.2f, (_Float16)0.2f};
  float t = 0.f;
#if defined(HAS_FDOT2)
  #pragma unroll
  for (int i = 0; i < 4; i++) {
    f16x2 s = xu.h[i] + xrh[i];
    f16x2 lr = __builtin_elementwise_max(s, s * c02);
    t = __builtin_amdgcn_fdot2(lr, ath[i], t, false);
  }
#else
  #pragma unroll
  for (int i = 0; i < 4; i++) {
    f32x2 s = __builtin_convertvector(xu.h[i], f32x2) +
              __builtin_convertvector(xrh[i], f32x2);
    f32x2 a = __builtin_convertvector(ath[i], f32x2);
    t += fmaxf(s.x, 0.2f * s.x) * a.x + fmaxf(s.y, 0.2f * s.y) * a.y;
  }
#endif
  t += __shfl_xor(t, 1);
  t += __shfl_xor(t, 2);         // 4-lane head cluster -> per-head logit
  float p = __expf(t);
  l += p;
  f32x2 p2 = {p, p};
  #pragma unroll
  for (int i = 0; i < 4; i++)
    accv[i] += p2 * __builtin_convertvector(xu.h[i], f32x2);
}

// ---------------- layers 0/1 gather over fp16 [N,128] -----------------------
// mode 0: write split-bf16 Ah/Al.  mode 1: write fp16 A16 (fused path).
__global__ __launch_bounds__(256) void k_gat_small16(
    const __half* __restrict__ xl, const __half* __restrict__ xr,
    const float* __restrict__ att, const float* __restrict__ bias,
    const int* __restrict__ offs, const int* __restrict__ degree,
    const int* __restrict__ csr_src,
    unsigned short* __restrict__ Ah, unsigned short* __restrict__ Al,
    __half* __restrict__ A16, int mode, int N) {
  const int node = blockIdx.x * 4 + (threadIdx.x >> 6);
  if (node >= N) return;
  const int lane = threadIdx.x & 63;
  const int g = lane >> 4;        // edge slot
  const int c = lane & 15;        // channel group (8 ch)
  const int d0 = c * 8;
  f16x2 xrh[4], ath[4];
  {
    union { uint4 u; f16x2 h[4]; } ru;
    ru.u = *(const uint4*)&xr[(size_t)node * 128 + d0];
    float4 a0 = *(const float4*)&att[d0];
    float4 a1 = *(const float4*)&att[d0 + 4];
    #pragma unroll
    for (int i = 0; i < 4; i++) xrh[i] = ru.h[i];
    ath[0] = (f16x2){(_Float16)a0.x, (_Float16)a0.y};
    ath[1] = (f16x2){(_Float16)a0.z, (_Float16)a0.w};
    ath[2] = (f16x2){(_Float16)a1.x, (_Float16)a1.y};
    ath[3] = (f16x2){(_Float16)a1.z, (_Float16)a1.w};
  }
  const int off = offs[node];
  const int deg = degree[node];
  const unsigned lb = (unsigned)d0 * 2u;        // byte offset in 256 B row
  f32x2 accv[4] = {};
  float l = 0.f;
  int ia = (g < deg)     ? csr_src[off + g]     : 0;
  int ib = (g + 4 < deg) ? csr_src[off + g + 4] : 0;
  int ic = (g + 8 < deg) ? csr_src[off + g + 8] : 0;
  uint4 v0 = make_uint4(0, 0, 0, 0), v1 = v0;
  if (g < deg)     v0 = ldrow(xl, (unsigned)ia * 256u + lb);
  if (g + 4 < deg) v1 = ldrow(xl, (unsigned)ib * 256u + lb);
  for (int j = g; j < deg; j += 4) {
    uint4 vn = v0;
    if (j + 8 < deg) vn = ldrow(xl, (unsigned)ic * 256u + lb);
    int id = (j + 12 < deg) ? csr_src[off + j + 12] : 0;
    edge_step_small(v0, xrh, ath, accv, l);
    v0 = v1; v1 = vn; ic = id;
  }
  // merge the 4 slots (lanes differ in bits 4-5)
  #pragma unroll
  for (int d = 16; d < 64; d <<= 1) {
    l += __shfl_xor(l, d);
    #pragma unroll
    for (int i = 0; i < 4; i++) {
      accv[i].x += __shfl_xor(accv[i].x, d);
      accv[i].y += __shfl_xor(accv[i].y, d);
    }
  }
  if (lane < 16) {
    const float inv = 1.f / l;
    const float4 b0 = *(const float4*)&bias[d0];
    const float4 b1 = *(const float4*)&bias[d0 + 4];
    float o[8] = {accv[0].x * inv + b0.x, accv[0].y * inv + b0.y,
                  accv[1].x * inv + b0.z, accv[1].y * inv + b0.w,
                  accv[2].x * inv + b1.x, accv[2].y * inv + b1.y,
                  accv[3].x * inv + b1.z, accv[3].y * inv + b1.w};
    #pragma unroll
    for (int i = 0; i < 8; i++)
      o[i] = o[i] > 0.f ? o[i] : __expf(o[i]) - 1.f;   // ELU
    const size_t nb = (size_t)node * 128 + d0;
    if (mode == 1) {
      union { uint4 u; __half h[8]; } ou;
      #pragma unroll
      for (int i = 0; i < 8; i++) ou.h[i] = __float2half(o[i]);
      *(uint4*)&A16[nb] = ou.u;
    } else {
      unsigned short hs[8], ls[8];
      #pragma unroll
      for (int i = 0; i < 8; i++) split2(o[i], hs[i], ls[i]);
      uint4 hv, lv;
      hv.x = (unsigned)hs[0] | ((unsigned)hs[1] << 16);
      hv.y = (unsigned)hs[2] | ((unsigned)hs[3] << 16);
      hv.z = (unsigned)hs[4] | ((unsigned)hs[5] << 16);
      hv.w = (unsigned)hs[6] | ((unsigned)hs[7] << 16);
      lv.x = (unsigned)ls[0] | ((unsigned)ls[1] << 16);
      lv.y = (unsigned)ls[2] | ((unsigned)ls[3] << 16);
      lv.z = (unsigned)ls[4] | ((unsigned)ls[5] << 16);
      lv.w = (unsigned)ls[6] | ((unsigned)ls[7] << 16);
      *(uint4*)&Ah[nb] = hv;
      *(uint4*)&Al[nb] = lv;
    }
  }
}

// ---------------- layer 2 FUSED gather: rotating prefetch -------------------
__global__ __launch_bounds__(256) void k_gat_fused4(
    const __half* __restrict__ xl4, const __half* __restrict__ xr4,
    const float* __restrict__ att2, const float* __restrict__ bias,
    const int* __restrict__ offs, const int* __restrict__ degree,
    const int* __restrict__ csr_src, float* __restrict__ out, int N) {
  const int node = blockIdx.x * 4 + (threadIdx.x >> 6);
  if (node >= N) return;
  const int lane = threadIdx.x & 63;
  f16x2 xrh[4], ath[4];
  {
    union { uint4 u; f16x2 h[4]; } ru;
    ru.u = *(const uint4*)&xr4[(size_t)node * 512 + lane * 8];
    float4 a0 = *(const float4*)&att2[lane * 8];
    float4 a1 = *(const float4*)&att2[lane * 8 + 4];
    #pragma unroll
    for (int i = 0; i < 4; i++) xrh[i] = ru.h[i];
    ath[0] = (f16x2){(_Float16)a0.x, (_Float16)a0.y};
    ath[1] = (f16x2){(_Float16)a0.z, (_Float16)a0.w};
    ath[2] = (f16x2){(_Float16)a1.x, (_Float16)a1.y};
    ath[3] = (f16x2){(_Float16)a1.z, (_Float16)a1.w};
  }
  const int off = offs[node];
  const int deg = degree[node];
  const unsigned lb = (unsigned)lane * 16u;     // byte offset in 1 KB row
  f32x2 accv[4] = {};
  float l = 0.f;
  int s0 = csr_src[off];
  int s1 = (1 < deg) ? csr_src[off + 1] : 0;
  int s2 = (2 < deg) ? csr_src[off + 2] : 0;
  int s3 = (3 < deg) ? csr_src[off + 3] : 0;
  uint4 v0 = ldrow(xl4, (unsigned)s0 * 1024u + lb);
  uint4 v1 = (1 < deg) ? ldrow(xl4, (unsigned)s1 * 1024u + lb) : v0;
  uint4 v2 = (2 < deg) ? ldrow(xl4, (unsigned)s2 * 1024u + lb) : v0;
  uint4 v3 = (3 < deg) ? ldrow(xl4, (unsigned)s3 * 1024u + lb) : v0;
  s0 = (4 < deg) ? csr_src[off + 4] : 0;        // indices one iter ahead
  s1 = (5 < deg) ? csr_src[off + 5] : 0;
  s2 = (6 < deg) ? csr_src[off + 6] : 0;
  s3 = (7 < deg) ? csr_src[off + 7] : 0;
  for (int j = 0; j < deg; j += 4) {
    edge_step(v0, true, xrh, ath, accv, l);     // j < deg guaranteed
    if (j + 4 < deg) v0 = ldrow(xl4, (unsigned)s0 * 1024u + lb);
    s0 = (j + 8 < deg) ? csr_src[off + j + 8] : 0;
    edge_step(v1, j + 1 < deg, xrh, ath, accv, l);
    if (j + 5 < deg) v1 = ldrow(xl4, (unsigned)s1 * 1024u + lb);
    s1 = (j + 9 < deg) ? csr_src[off + j + 9] : 0;
    edge_step(v2, j + 2 < deg, xrh, ath, accv, l);
    if (j + 6 < deg) v2 = ldrow(xl4, (unsigned)s2 * 1024u + lb);
    s2 = (j + 10 < deg) ? csr_src[off + j + 10] : 0;
    edge_step(v3, j + 3 < deg, xrh, ath, accv, l);
    if (j + 7 < deg) v3 = ldrow(xl4, (unsigned)s3 * 1024u + lb);
    s3 = (j + 11 < deg) ? csr_src[off + j + 11] : 0;
  }
  // scale by own head's softmax-mean weight, then sum heads via butterfly
  const float w = 0.25f / l;
  const f32x2 w2 = {w, w};
  #pragma unroll
  for (int i = 0; i < 4; i++) accv[i] *= w2;
  #pragma unroll
  for (int d = 16; d < 64; d <<= 1) {
    #pragma unroll
    for (int i = 0; i < 4; i++) {
      accv[i].x += __shfl_xor(accv[i].x, d);
      accv[i].y += __shfl_xor(accv[i].y, d);
    }
  }
  if (lane < 16) {
    const int d0 = lane * 8;
    float4 b0 = *(const float4*)&bias[d0];
    float4 b1 = *(const float4*)&bias[d0 + 4];
    float* op = &out[(size_t)node * 128 + d0];
    *(float4*)op       = make_float4(accv[0].x + b0.x, accv[0].y + b0.y,
                                     accv[1].x + b0.z, accv[1].y + b0.w);
    *(float4*)(op + 4) = make_float4(accv[2].x + b1.x, accv[2].y + b1.y,
                                     accv[3].x + b1.z, accv[3].y + b1.w);
  }
}

// ---------------- fallback: layer 2 per-head fp32 gather --------------------
__global__ __launch_bounds__(256) void k_gat_head(
    const float* __restrict__ xl, const float* __restrict__ xr,
    const float* __restrict__ att_h, const float* __restrict__ bias,
    const int* __restrict__ offs, const int* __restrict__ degree,
    const int* __restrict__ csr_src, float* __restrict__ out, int N,
    int first, int last) {
  const int node = blockIdx.x * 4 + (threadIdx.x >> 6);
  if (node >= N) return;
  const int lane = threadIdx.x & 63;
  const int g = lane >> 4;
  const int c = lane & 15;
  const int d0 = c * 8;
  const size_t nb = (size_t)node * 128 + d0;
  const float4 xra = *(const float4*)&xr[nb];
  const float4 xrb = *(const float4*)&xr[nb + 4];
  const float4 ata = *(const float4*)&att_h[d0];
  const float4 atb = *(const float4*)&att_h[d0 + 4];
  const int off = offs[node];
  const int deg = degree[node];
  float l = 0.f;
  float4 aca = make_float4(0.f, 0.f, 0.f, 0.f);
  float4 acb = make_float4(0.f, 0.f, 0.f, 0.f);
  int s0 = (g < deg) ? csr_src[off + g] : 0;
  int s1 = (g + 4 < deg) ? csr_src[off + g + 4] : 0;
  for (int j = g; j < deg; j += 8) {
    int sn0 = (j + 8 < deg) ? csr_src[off + j + 8] : 0;
    int sn1 = (j + 12 < deg) ? csr_src[off + j + 12] : 0;
    const size_t sb0 = (size_t)s0 * 128 + d0;
    const size_t sb1 = (size_t)s1 * 128 + d0;
    float4 xa0 = *(const float4*)&xl[sb0];
    float4 xb0 = *(const float4*)&xl[sb0 + 4];
    float4 xa1 = *(const float4*)&xl[sb1];
    float4 xb1 = *(const float4*)&xl[sb1 + 4];
    float t0 = lrelu(xa0.x + xra.x) * ata.x + lrelu(xa0.y + xra.y) * ata.y +
               lrelu(xa0.z + xra.z) * ata.z + lrelu(xa0.w + xra.w) * ata.w +
               lrelu(xb0.x + xrb.x) * atb.x + lrelu(xb0.y + xrb.y) * atb.y +
               lrelu(xb0.z + xrb.z) * atb.z + lrelu(xb0.w + xrb.w) * atb.w;
    float t1 = lrelu(xa1.x + xra.x) * ata.x + lrelu(xa1.y + xra.y) * ata.y +
               lrelu(xa1.z + xra.z) * ata.z + lrelu(xa1.w + xra.w) * ata.w +
               lrelu(xb1.x + xrb.x) * atb.x + lrelu(xb1.y + xrb.y) * atb.y +
               lrelu(xb1.z + xrb.z) * atb.z + lrelu(xb1.w + xrb.w) * atb.w;
    t0 += __shfl_xor(t0, 1);
    t0 += __shfl_xor(t0, 2);
    t0 += __shfl_xor(t0, 4);
    t0 += __shfl_xor(t0, 8);
    t1 += __shfl_xor(t1, 1);
    t1 += __shfl_xor(t1, 2);
    t1 += __shfl_xor(t1, 4);
    t1 += __shfl_xor(t1, 8);
    float p0 = __expf(t0);
    float p1 = (j + 4 < deg) ? __expf(t1) : 0.f;
    aca.x += p0 * xa0.x + p1 * xa1.x; aca.y += p0 * xa0.y + p1 * xa1.y;
    aca.z += p0 * xa0.z + p1 * xa1.z; aca.w += p0 * xa0.w + p1 * xa1.w;
    acb.x += p0 * xb0.x + p1 * xb1.x; acb.y += p0 * xb0.y + p1 * xb1.y;
    acb.z += p0 * xb0.z + p1 * xb1.z; acb.w += p0 * xb0.w + p1 * xb1.w;
    l += p0 + p1;
    s0 = sn0; s1 = sn1;
  }
  MERGE_ADD(16)
  MERGE_ADD(32)
  if (lane < 16) {
    const float inv = 0.25f / l;
    float o[8] = {aca.x * inv, aca.y * inv, aca.z * inv, aca.w * inv,
                  acb.x * inv, acb.y * inv, acb.z * inv, acb.w * inv};
    float* op = &out[nb];
    if (!first) {
      float4 p0 = *(const float4*)op;
      float4 p1 = *(const float4*)(op + 4);
      o[0] += p0.x; o[1] += p0.y; o[2] += p0.z; o[3] += p0.w;
      o[4] += p1.x; o[5] += p1.y; o[6] += p1.z; o[7] += p1.w;
    }
    if (last) {
      float4 b0 = *(const float4*)&bias[d0];
      float4 b1 = *(const float4*)&bias[d0 + 4];
      o[0] += b0.x; o[1] += b0.y; o[2] += b0.z; o[3] += b0.w;
      o[4] += b1.x; o[5] += b1.y; o[6] += b1.z; o[7] += b1.w;
    }
    *(float4*)op       = make_float4(o[0], o[1], o[2], o[3]);
    *(float4*)(op + 4) = make_float4(o[4], o[5], o[6], o[7]);
  }
}

// ---------------------------------------------------------------------------
extern "C" void kernel_launch(void* const* d_in, const int* in_sizes, int n_in,
                              void* d_out, int out_size, void* d_ws, size_t ws_size,
                              hipStream_t stream) {
  const float* x     = (const float*)d_in[0];
  const int*   ei    = (const int*)  d_in[1];
  const float* Wl0   = (const float*)d_in[2];
  const float* bl0   = (const float*)d_in[3];
  const float* Wr0   = (const float*)d_in[4];
  const float* br0   = (const float*)d_in[5];
  const float* att0  = (const float*)d_in[6];
  const float* bias0 = (const float*)d_in[7];
  const float* Wl1   = (const float*)d_in[8];
  const float* bl1   = (const float*)d_in[9];
  const float* Wr1   = (const float*)d_in[10];
  const float* br1   = (const float*)d_in[11];
  const float* att1  = (const float*)d_in[12];
  const float* bias1 = (const float*)d_in[13];
  const float* Wl2   = (const float*)d_in[14];
  const float* bl2   = (const float*)d_in[15];
  const float* Wr2   = (const float*)d_in[16];
  const float* br2   = (const float*)d_in[17];
  const float* att2  = (const float*)d_in[18];
  const float* bias2 = (const float*)d_in[19];

  const int N = in_sizes[0] / 128;
  const int E = in_sizes[1] / 2;

  char* p = (char*)d_ws;
  auto alloc = [&](size_t bytes) {
    void* q = (void*)p;
    p += (bytes + 255) & ~(size_t)255;
    return q;
  };
  auto al = [](size_t b) { return (b + 255) & ~(size_t)255; };
  const size_t common = al((size_t)(N + 1) * 4) + 2 * al((size_t)N * 4) +
                        al((size_t)(E + N) * 4) + al((size_t)512) +
                        2 * al((size_t)N * 128 * 2) +
                        8 * al((size_t)128 * 128 * 2) +
                        4 * al((size_t)512 * 128 * 2) +
                        2 * al((size_t)512 * 128 * 2) +
                        4 * al((size_t)128 * 128 * 2);
  const size_t need_fused = common + 2 * al((size_t)N * 512 * 2);
  const bool fused = ws_size >= need_fused;   // deterministic across calls

  int* offs    = (int*)alloc((size_t)(N + 1) * 4);
  int* degree  = (int*)alloc((size_t)N * 4);
  int* cursor  = (int*)alloc((size_t)N * 4);
  int* csr_src = (int*)alloc((size_t)(E + N) * 4);
  int* partial = (int*)alloc((size_t)512);
  unsigned short* Agh = (unsigned short*)alloc((size_t)N * 128 * 2);
  unsigned short* Agl = (unsigned short*)alloc((size_t)N * 128 * 2);
  unsigned short* W0hl = (unsigned short*)alloc((size_t)128 * 128 * 2);
  unsigned short* W0ll = (unsigned short*)alloc((size_t)128 * 128 * 2);
  unsigned short* W0hr = (unsigned short*)alloc((size_t)128 * 128 * 2);
  unsigned short* W0lr = (unsigned short*)alloc((size_t)128 * 128 * 2);
  unsigned short* W1hl = (unsigned short*)alloc((size_t)128 * 128 * 2);
  unsigned short* W1ll = (unsigned short*)alloc((size_t)128 * 128 * 2);
  unsigned short* W1hr = (unsigned short*)alloc((size_t)128 * 128 * 2);
  unsigned short* W1lr = (unsigned short*)alloc((size_t)128 * 128 * 2);
  unsigned short* W2hl = (unsigned short*)alloc((size_t)512 * 128 * 2);
  unsigned short* W2ll = (unsigned short*)alloc((size_t)512 * 128 * 2);
  unsigned short* W2hr = (unsigned short*)alloc((size_t)512 * 128 * 2);
  unsigned short* W2lr = (unsigned short*)alloc((size_t)512 * 128 * 2);
  __half* W2fl = (__half*)alloc((size_t)512 * 128 * 2);   // fp16 W2
  __half* W2fr = (__half*)alloc((size_t)512 * 128 * 2);
  __half* W0fl = (__half*)alloc((size_t)128 * 128 * 2);   // fp16 W0/W1
  __half* W0fr = (__half*)alloc((size_t)128 * 128 * 2);
  __half* W1fl = (__half*)alloc((size_t)128 * 128 * 2);
  __half* W1fr = (__half*)alloc((size_t)128 * 128 * 2);
  __half* xl4 = nullptr; __half* xr4 = nullptr;   // fused: fp16 [N,512]
  float* xl = nullptr; float* xr = nullptr;       // fallback fp32 [N,128]
  __half* xl16 = nullptr; __half* xr16 = nullptr; // fused: fp16 [N,128] views
  if (fused) {
    xl4 = (__half*)alloc((size_t)N * 512 * 2);
    xr4 = (__half*)alloc((size_t)N * 512 * 2);
    xl16 = xl4;              // layers 0/1 alias the big buffers ([N,128] fp16)
    xr16 = xr4;
  } else {
    xl = (float*)alloc((size_t)N * 128 * 4);
    xr = (float*)alloc((size_t)N * 128 * 4);
  }
  // fp16 A rotation (fused): A16x (from x) -> A16a (L0 out) -> A16b (L1 out)
  __half* A16x = (__half*)Agl;
  __half* A16a = (__half*)Agh;
  __half* A16b = (__half*)Agl;   // A16x dead after layer-0 GEMM
  (void)n_in; (void)out_size;

  const int nb = (N + 1023) / 1024;

  // CSR build (ws is re-poisoned each call, so rebuild every launch)
  k_init<<<(N + 255) / 256, 256, 0, stream>>>(degree, cursor, N);
  k_hist<<<(E + 255) / 256, 256, 0, stream>>>(ei, E, degree);
  k_scan1<<<nb, 256, 0, stream>>>(degree, partial, N);
  k_scan2<<<1, 256, 0, stream>>>(partial, nb);
  k_scan3<<<nb, 256, 0, stream>>>(degree, partial, offs, N);
  k_scatter<<<(E + N + 255) / 256, 256, 0, stream>>>(ei, E, N, offs, cursor, csr_src);

  // one prep dispatch: weight preps + x conversion
  const int prepT = 393216 + (N * 128 + 3) / 4;
  k_prep<<<(prepT + 255) / 256, 256, 0, stream>>>(
      Wl0, Wr0, Wl1, Wr1, Wl2, Wr2,
      W0hl, W0ll, W0hr, W0lr, W1hl, W1ll, W1hr, W1lr,
      W2hl, W2ll, W2hr, W2lr,
      W0fl, W0fr, W1fl, W1fr, W2fl, W2fr,
      x, A16x, Agh, Agl, N * 128, fused ? 1 : 0);

  const int mb = (N + 127) / 128;        // M tiles
  const dim3 gg(mb, 2);                  // 128-wide GEMM grid
  const dim3 gg4(mb, 2, 4);              // layer-2 GEMM grid (z = head)
  const int gb = (N + 3) / 4;            // gather grid (4 nodes / block)

  if (fused) {
    // layer 0: fp16 GEMM from fp16 x
    k_gemm2h<<<gg, 256, 0, stream>>>(A16x, W0fl, W0fr, bl0, br0,
                                     xl16, xr16, N, 128);
    k_gat_small16<<<gb, 256, 0, stream>>>(xl16, xr16, att0, bias0, offs, degree,
                                          csr_src, nullptr, nullptr, A16a, 1, N);
    // layer 1: fp16 GEMM
    k_gemm2h<<<gg, 256, 0, stream>>>(A16a, W1fl, W1fr, bl1, br1,
                                     xl16, xr16, N, 128);
    k_gat_small16<<<gb, 256, 0, stream>>>(xl16, xr16, att1, bias1, offs, degree,
                                          csr_src, nullptr, nullptr, A16b, 1, N);
    // layer 2: fp16 GEMM, z = head slice
    k_gemm2h<<<gg4, 256, 0, stream>>>(A16b, W2fl, W2fr, bl2, br2,
                                      xl4, xr4, N, 512);
    k_gat_fused4<<<gb, 256, 0, stream>>>(xl4, xr4, att2, bias2, offs, degree,
                                         csr_src, (float*)d_out, N);
  } else {
    // layer 0
    k_gemm2s<<<gg, 256, 0, stream>>>(Agh, Agl, W0hl, W0ll, W0hr, W0lr,
                                     bl0, br0, xl, xr, N, 128, 0, 0);
    k_gat_small<<<gb, 256, 0, stream>>>(xl, xr, att0, bias0, offs, degree, csr_src,
                                        Agh, Agl, N);
    // layer 1
    k_gemm2s<<<gg, 256, 0, stream>>>(Agh, Agl, W1hl, W1ll, W1hr, W1lr,
                                     bl1, br1, xl, xr, N, 128, 0, 0);
    k_gat_small<<<gb, 256, 0, stream>>>(xl, xr, att1, bias1, offs, degree, csr_src,
                                        Agh, Agl, N);
    // layer 2 per head (full 3-term precision)
    for (int h = 0; h < 4; h++) {
      const int wo = h * 128 * 128;
      k_gemm2s<<<gg, 256, 0, stream>>>(Agh, Agl, W2hl + wo, W2ll + wo,
                                       W2hr + wo, W2lr + wo,
                                       bl2 + h * 128, br2 + h * 128,
                                       xl, xr, N, 128, 0, 0);
      k_gat_head<<<gb, 256, 0, stream>>>(xl, xr, att2 + h * 128, bias2, offs, degree,
                                         csr_src, (float*)d_out, N,
                                         h == 0 ? 1 : 0, h == 3 ? 1 : 0);
    }
  }
}

// Round 8
// 808.949 us; speedup vs baseline: 1.4065x; 1.1425x over previous
//
#include <hip/hip_runtime.h>
#include <hip/hip_fp16.h>
#include <cstddef>

// ---------------------------------------------------------------------------
// GATv2 backbone: 3 layers, N=100k nodes, E=1.6M edges (+self loops), H=4.
//   - CSR by dst built once (histogram + 3-kernel multi-block scan + scatter).
//   - ALL GEMMs (fused path): single-term fp16 MFMA k_gemm2h (A fp16, W fp16,
//     fp32 accum). r5/r6: numerically invisible vs 3-term split-bf16.
//     C stores restaged through the SAME 20 KB LDS (two 64-row passes) ->
//     256 B/row coalesced uint4 stores (r2: scalar __half stores amplified
//     writes 205->367 MB). Occupancy unchanged.
//   - Gathers: fp16 rows, packed-fp16 logits, fp16 value acc (v_pk_fma_f16;
//     p<=~2, acc<=~20 -> no fp16 overflow), fp16 A out.
//   - Layer 2: ONE fused gather over fp16 [N,512]. r1/r4/r5/r6: ~3.7 TB/s /
//     878 MB L2-miss invariant across schedules -> memory-path bound.
//   - One k_prep dispatch (launched FIRST): weight preps + x conversion +
//     degree/cursor init (k_init folded in). Fused path skips dead splits.
//   - Fallback path (tiny ws): original fp32 3-term pipeline, unchanged.
//   - r7 NOTE: identical resubmission — r7 bench died to container infra
//     failure with no measurement; barrier/alias audit found no hang risk.
// ---------------------------------------------------------------------------

typedef __attribute__((ext_vector_type(8))) short bf16x8;
typedef _Float16 f16x8 __attribute__((ext_vector_type(8)));
typedef __attribute__((ext_vector_type(4))) float f32x4;
typedef _Float16 f16x2 __attribute__((ext_vector_type(2)));
typedef float f32x2 __attribute__((ext_vector_type(2)));

#if defined(__has_builtin)
#if __has_builtin(__builtin_amdgcn_fdot2)
#define HAS_FDOT2 1
#endif
#endif

__device__ __forceinline__ float lrelu(float x) { return fmaxf(x, 0.2f * x); }

// 16B row-fragment load at 32-bit byte offset
__device__ __forceinline__ uint4 ldrow(const void* base, unsigned byteoff) {
  return *(const uint4*)((const char*)base + byteoff);
}

// RNE fp32 -> bf16 hi + bf16 residual
__device__ __forceinline__ void split2(float x, unsigned short& h, unsigned short& l) {
  unsigned b = __float_as_uint(x);
  unsigned r = b + 0x7fffu + ((b >> 16) & 1u);
  h = (unsigned short)(r >> 16);
  float hf = __uint_as_float((unsigned)h << 16);
  float res = x - hf;
  unsigned b2 = __float_as_uint(res);
  unsigned r2 = b2 + 0x7fffu + ((b2 >> 16) & 1u);
  l = (unsigned short)(r2 >> 16);
}

// ---------------- CSR build ----------------
__global__ void k_hist(const int* __restrict__ ei, int E, int* __restrict__ degree) {
  int e = blockIdx.x * blockDim.x + threadIdx.x;
  if (e < E) atomicAdd(&degree[ei[E + e]], 1);
}

// --- 3-kernel scan: per-block sums -> scan of sums -> per-block scan+base ---
__global__ __launch_bounds__(256) void k_scan1(const int* __restrict__ degree,
                                               int* __restrict__ partial, int N) {
  __shared__ int ws[4];
  const int i0 = blockIdx.x * 1024 + threadIdx.x * 4;
  int s = 0;
  if (i0 + 3 < N) {
    int4 v = *(const int4*)&degree[i0];
    s = v.x + v.y + v.z + v.w;
  } else {
    #pragma unroll
    for (int k = 0; k < 4; k++) if (i0 + k < N) s += degree[i0 + k];
  }
  #pragma unroll
  for (int d = 1; d < 64; d <<= 1) s += __shfl_xor(s, d);
  const int lane = threadIdx.x & 63, wid = threadIdx.x >> 6;
  if (lane == 0) ws[wid] = s;
  __syncthreads();
  if (threadIdx.x == 0) partial[blockIdx.x] = ws[0] + ws[1] + ws[2] + ws[3];
}

__global__ __launch_bounds__(256) void k_scan2(int* __restrict__ partial, int nb) {
  __shared__ int sh[256];
  const int tid = threadIdx.x;
  int v = (tid < nb) ? partial[tid] : 0;
  sh[tid] = v;
  __syncthreads();
  for (int d = 1; d < 256; d <<= 1) {
    int t = (tid >= d) ? sh[tid - d] : 0;
    __syncthreads();
    sh[tid] += t;
    __syncthreads();
  }
  if (tid < nb) partial[tid] = sh[tid] - v;   // exclusive base per block
}

__global__ __launch_bounds__(256) void k_scan3(const int* __restrict__ degree,
                                               const int* __restrict__ partial,
                                               int* __restrict__ offs, int N) {
  __shared__ int wsum[4];
  const int tid = threadIdx.x, lane = tid & 63, wid = tid >> 6;
  const int i0 = blockIdx.x * 1024 + tid * 4;
  int v0 = 0, v1 = 0, v2 = 0, v3 = 0;
  if (i0 + 3 < N) {
    int4 v = *(const int4*)&degree[i0];
    v0 = v.x; v1 = v.y; v2 = v.z; v3 = v.w;
  } else {
    if (i0     < N) v0 = degree[i0];
    if (i0 + 1 < N) v1 = degree[i0 + 1];
    if (i0 + 2 < N) v2 = degree[i0 + 2];
    if (i0 + 3 < N) v3 = degree[i0 + 3];
  }
  int s = v0 + v1 + v2 + v3, x = s;
  #pragma unroll
  for (int d = 1; d < 64; d <<= 1) {
    int y = __shfl_up(x, d);
    if (lane >= d) x += y;
  }
  if (lane == 63) wsum[wid] = x;
  __syncthreads();
  if (tid < 4) {
    int t = wsum[tid];
    #pragma unroll
    for (int d = 1; d < 4; d <<= 1) {
      int y = __shfl_up(t, d);
      if (tid >= d) t += y;
    }
    wsum[tid] = t;
  }
  __syncthreads();
  const int wbase = wid ? wsum[wid - 1] : 0;
  int e = partial[blockIdx.x] + wbase + (x - s);
  if (i0     < N) offs[i0]     = e;  e += v0;  if (i0     == N - 1) offs[N] = e;
  if (i0 + 1 < N) offs[i0 + 1] = e;  e += v1;  if (i0 + 1 == N - 1) offs[N] = e;
  if (i0 + 2 < N) offs[i0 + 2] = e;  e += v2;  if (i0 + 2 == N - 1) offs[N] = e;
  if (i0 + 3 < N) offs[i0 + 3] = e;  e += v3;  if (i0 + 3 == N - 1) offs[N] = e;
}

__global__ void k_scatter(const int* __restrict__ ei, int E, int N,
                          const int* __restrict__ offs, int* __restrict__ cursor,
                          int* __restrict__ csr_src) {
  int t = blockIdx.x * blockDim.x + threadIdx.x;
  int ET = E + N;
  if (t >= ET) return;
  int s, d;
  if (t < E) { s = ei[t]; d = ei[E + t]; }
  else       { s = t - E; d = s; }
  int pos = offs[d] + atomicAdd(&cursor[d], 1);
  csr_src[pos] = s;
}

// ---- ONE prep dispatch (launched first) ------------------------------------
// fused:    [0,196608) W fp16 transposes, [196608,+NA4) x->fp16, [+N) init.
// fallback: [0,196608) W bf16 splits,     [196608,+NA4) x->split, [+N) init.
__global__ __launch_bounds__(256) void k_prep(
    const float* __restrict__ Wl0, const float* __restrict__ Wr0,
    const float* __restrict__ Wl1, const float* __restrict__ Wr1,
    const float* __restrict__ Wl2, const float* __restrict__ Wr2,
    unsigned short* __restrict__ W0hl, unsigned short* __restrict__ W0ll,
    unsigned short* __restrict__ W0hr, unsigned short* __restrict__ W0lr,
    unsigned short* __restrict__ W1hl, unsigned short* __restrict__ W1ll,
    unsigned short* __restrict__ W1hr, unsigned short* __restrict__ W1lr,
    unsigned short* __restrict__ W2hl, unsigned short* __restrict__ W2ll,
    unsigned short* __restrict__ W2hr, unsigned short* __restrict__ W2lr,
    __half* __restrict__ W0fl, __half* __restrict__ W0fr,
    __half* __restrict__ W1fl, __half* __restrict__ W1fr,
    __half* __restrict__ W2fl, __half* __restrict__ W2fr,
    const float* __restrict__ X, __half* __restrict__ A16x,
    unsigned short* __restrict__ Ah, unsigned short* __restrict__ Al,
    int totalA, int N, int fusedF,
    int* __restrict__ degree, int* __restrict__ cursor) {
  const int t = blockIdx.x * blockDim.x + threadIdx.x;
  const int NA4 = totalA >> 2;
  if (t < 196608) {
    if (fusedF) {
      // fp16 transposes only (splits dead on fused path)
      const float* W; __half* O; int idx, sh;
      if (t < 16384)       { W = Wl0; O = W0fl; idx = t;          sh = 7; }
      else if (t < 32768)  { W = Wr0; O = W0fr; idx = t - 16384;  sh = 7; }
      else if (t < 49152)  { W = Wl1; O = W1fl; idx = t - 32768;  sh = 7; }
      else if (t < 65536)  { W = Wr1; O = W1fr; idx = t - 49152;  sh = 7; }
      else if (t < 131072) { W = Wl2; O = W2fl; idx = t - 65536;  sh = 9; }
      else                 { W = Wr2; O = W2fr; idx = t - 131072; sh = 9; }
      const int n = idx & ((1 << sh) - 1), k = idx >> sh;
      O[(size_t)n * 128 + k] = __float2half(W[idx]);
    } else {
      const float* W; unsigned short *Whp, *Wlp; int idx, sh;
      if (t < 16384)       { W = Wl0; Whp = W0hl; Wlp = W0ll; idx = t;          sh = 7; }
      else if (t < 32768)  { W = Wr0; Whp = W0hr; Wlp = W0lr; idx = t - 16384;  sh = 7; }
      else if (t < 49152)  { W = Wl1; Whp = W1hl; Wlp = W1ll; idx = t - 32768;  sh = 7; }
      else if (t < 65536)  { W = Wr1; Whp = W1hr; Wlp = W1lr; idx = t - 49152;  sh = 7; }
      else if (t < 131072) { W = Wl2; Whp = W2hl; Wlp = W2ll; idx = t - 65536;  sh = 9; }
      else                 { W = Wr2; Whp = W2hr; Wlp = W2lr; idx = t - 131072; sh = 9; }
      const int n = idx & ((1 << sh) - 1), k = idx >> sh;
      unsigned short h, l;
      split2(W[idx], h, l);
      Whp[(size_t)n * 128 + k] = h;
      Wlp[(size_t)n * 128 + k] = l;
    }
    return;
  }
  if (t < 196608 + NA4) {
    const int t4 = (t - 196608) * 4;
    float4 v = *(const float4*)&X[t4];
    if (fusedF) {
      union { uint2 u; __half h[4]; } ou;
      ou.h[0] = __float2half(v.x); ou.h[1] = __float2half(v.y);
      ou.h[2] = __float2half(v.z); ou.h[3] = __float2half(v.w);
      *(uint2*)&A16x[t4] = ou.u;
    } else {
      unsigned short h0, h1, h2, h3, l0, l1, l2, l3;
      split2(v.x, h0, l0); split2(v.y, h1, l1);
      split2(v.z, h2, l2); split2(v.w, h3, l3);
      uint2 hv, lv;
      hv.x = (unsigned)h0 | ((unsigned)h1 << 16);
      hv.y = (unsigned)h2 | ((unsigned)h3 << 16);
      lv.x = (unsigned)l0 | ((unsigned)l1 << 16);
      lv.y = (unsigned)l2 | ((unsigned)l3 << 16);
      *(uint2*)&Ah[t4] = hv;
      *(uint2*)&Al[t4] = lv;
    }
    return;
  }
  const int i = t - 196608 - NA4;
  if (i < N) { degree[i] = 1; cursor[i] = 0; }   // self-loop counts as 1
}

// ---------------- split-bf16 MFMA GEMM (3-term, FALLBACK only) --------------
__global__ __launch_bounds__(256) void k_gemm2s(
    const unsigned short* __restrict__ Agh, const unsigned short* __restrict__ Agl,
    const unsigned short* __restrict__ Whl, const unsigned short* __restrict__ Wll,
    const unsigned short* __restrict__ Whr, const unsigned short* __restrict__ Wlr,
    const float* __restrict__ bias_l, const float* __restrict__ bias_r,
    void* __restrict__ Clp, void* __restrict__ Crp, int N,
    int ldC, int coloff, int out_half) {
  __shared__ unsigned short Ah_s[128][40];   // row pad 40 (80 B = 5 superbanks)
  __shared__ unsigned short Al_s[128][40];
  __shared__ unsigned short Wh_s[128][40];
  __shared__ unsigned short Wl_s[128][40];
  const int hsel = blockIdx.z;
  const unsigned short* __restrict__ Wth = (blockIdx.y ? Whr : Whl) + hsel * 128 * 128;
  const unsigned short* __restrict__ Wtl = (blockIdx.y ? Wlr : Wll) + hsel * 128 * 128;
  const float* __restrict__ bias = (blockIdx.y ? bias_r : bias_l) + hsel * 128;
  void* __restrict__ Cp = blockIdx.y ? Crp : Clp;
  coloff += hsel * 128;

  const int tid = threadIdx.x;
  const int m0 = blockIdx.x * 128;
  const int wv = tid >> 6, lane = tid & 63;
  const int wm = (wv >> 1) * 64, wn = (wv & 1) * 64;
  const int l15 = lane & 15, kb = (lane >> 4) * 8;
  f32x4 acc[4][4] = {};

  const int r = tid >> 1;              // staging row 0..127
  const int cb = (tid & 1) * 16;       // staging col base 0/16
  const bool arow_ok = (m0 + r) < N;
  const unsigned short* ahp = Agh + (size_t)(m0 + r) * 128 + cb;
  const unsigned short* alp = Agl + (size_t)(m0 + r) * 128 + cb;
  const unsigned short* whp = Wth + r * 128 + cb;
  const unsigned short* wlp = Wtl + r * 128 + cb;
  const uint4 z4 = make_uint4(0, 0, 0, 0);

  uint4 pa0, pa1, pl0, pl1, pw0, pw1, pq0, pq1;
  #define LOADC(K0)                                                           \
    pa0 = arow_ok ? *(const uint4*)(ahp + (K0))     : z4;                     \
    pa1 = arow_ok ? *(const uint4*)(ahp + (K0) + 8) : z4;                     \
    pl0 = arow_ok ? *(const uint4*)(alp + (K0))     : z4;                     \
    pl1 = arow_ok ? *(const uint4*)(alp + (K0) + 8) : z4;                     \
    pw0 = *(const uint4*)(whp + (K0));                                        \
    pw1 = *(const uint4*)(whp + (K0) + 8);                                    \
    pq0 = *(const uint4*)(wlp + (K0));                                        \
    pq1 = *(const uint4*)(wlp + (K0) + 8);
  LOADC(0)
  for (int kc = 0; kc < 4; kc++) {
    *(uint4*)&Ah_s[r][cb]     = pa0;
    *(uint4*)&Ah_s[r][cb + 8] = pa1;
    *(uint4*)&Al_s[r][cb]     = pl0;
    *(uint4*)&Al_s[r][cb + 8] = pl1;
    *(uint4*)&Wh_s[r][cb]     = pw0;
    *(uint4*)&Wh_s[r][cb + 8] = pw1;
    *(uint4*)&Wl_s[r][cb]     = pq0;
    *(uint4*)&Wl_s[r][cb + 8] = pq1;
    __syncthreads();
    if (kc < 3) { LOADC((kc + 1) * 32) }   // in flight during MFMA below

    bf16x8 afh[4], afl[4];
    #pragma unroll
    for (int mi = 0; mi < 4; mi++) {
      const int row = wm + mi * 16 + l15;
      afh[mi] = *(const bf16x8*)&Ah_s[row][kb];
      afl[mi] = *(const bf16x8*)&Al_s[row][kb];
    }
    #pragma unroll
    for (int ni = 0; ni < 4; ni++) {
      const int rown = wn + ni * 16 + l15;
      bf16x8 bh = *(const bf16x8*)&Wh_s[rown][kb];
      bf16x8 bl = *(const bf16x8*)&Wl_s[rown][kb];
      #pragma unroll
      for (int mi = 0; mi < 4; mi++) {
        acc[mi][ni] = __builtin_amdgcn_mfma_f32_16x16x32_bf16(afh[mi], bh, acc[mi][ni], 0, 0, 0);
        acc[mi][ni] = __builtin_amdgcn_mfma_f32_16x16x32_bf16(afl[mi], bh, acc[mi][ni], 0, 0, 0);
        acc[mi][ni] = __builtin_amdgcn_mfma_f32_16x16x32_bf16(afh[mi], bl, acc[mi][ni], 0, 0, 0);
      }
    }
    __syncthreads();
  }
  #undef LOADC
  const int col = l15, rbase = (lane >> 4) * 4;
  #pragma unroll
  for (int ni = 0; ni < 4; ni++) {
    const int gn = wn + ni * 16 + col;
    const float bv = bias[gn];
    #pragma unroll
    for (int mi = 0; mi < 4; mi++) {
      #pragma unroll
      for (int q = 0; q < 4; q++) {
        const int gm = m0 + wm + mi * 16 + rbase + q;
        if (gm < N) {
          float v = acc[mi][ni][q] + bv;
          if (out_half) ((__half*)Cp)[(size_t)gm * ldC + coloff + gn] = __float2half(v);
          else          ((float*)Cp)[(size_t)gm * ldC + coloff + gn] = v;
        }
      }
    }
  }
}

// ---------------- fp16 single-term MFMA GEMM (all fused-path GEMMs) ---------
// A fp16 [N,128], W fp16 transposed [outcols][128]. blockIdx.y = l/r,
// blockIdx.z = head slice (0 for 128-wide). fp32 accum, fp16 out.
// C restaged through the SAME 20 KB LDS in two 64-row passes -> 256 B/row
// coalesced uint4 stores (kills r2's 1.8x partial-sector write amplification)
// with occupancy unchanged.
__global__ __launch_bounds__(256) void k_gemm2h(
    const __half* __restrict__ A16,
    const __half* __restrict__ Wfl, const __half* __restrict__ Wfr,
    const float* __restrict__ bias_l, const float* __restrict__ bias_r,
    __half* __restrict__ Clp, __half* __restrict__ Crp, int N, int ldC) {
  __shared__ __align__(16) unsigned char smem[20480];
  __half (* __restrict__ A_s)[40] = (__half(*)[40])smem;
  __half (* __restrict__ W_s)[40] = (__half(*)[40])(smem + 10240);
  const int hsel = blockIdx.z;
  const __half* __restrict__ Wt = (blockIdx.y ? Wfr : Wfl) + hsel * 128 * 128;
  const float* __restrict__ bias = (blockIdx.y ? bias_r : bias_l) + hsel * 128;
  __half* __restrict__ Cp = blockIdx.y ? Crp : Clp;
  const int coloff = hsel * 128;

  const int tid = threadIdx.x;
  const int m0 = blockIdx.x * 128;
  const int wv = tid >> 6, lane = tid & 63;
  const int wm = (wv >> 1) * 64, wn = (wv & 1) * 64;
  const int l15 = lane & 15, kb = (lane >> 4) * 8;
  f32x4 acc[4][4] = {};

  const int r = tid >> 1;              // staging row 0..127
  const int cb = (tid & 1) * 16;       // staging col base 0/16
  const bool arow_ok = (m0 + r) < N;
  const __half* ap = A16 + (size_t)(m0 + r) * 128 + cb;
  const __half* wp = Wt + r * 128 + cb;
  const uint4 z4 = make_uint4(0, 0, 0, 0);

  uint4 pa0, pa1, pw0, pw1;
  #define LOADH(K0)                                                           \
    pa0 = arow_ok ? *(const uint4*)(ap + (K0))     : z4;                      \
    pa1 = arow_ok ? *(const uint4*)(ap + (K0) + 8) : z4;                      \
    pw0 = *(const uint4*)(wp + (K0));                                         \
    pw1 = *(const uint4*)(wp + (K0) + 8);
  LOADH(0)
  for (int kc = 0; kc < 4; kc++) {
    *(uint4*)&A_s[r][cb]     = pa0;
    *(uint4*)&A_s[r][cb + 8] = pa1;
    *(uint4*)&W_s[r][cb]     = pw0;
    *(uint4*)&W_s[r][cb + 8] = pw1;
    __syncthreads();
    if (kc < 3) { LOADH((kc + 1) * 32) }   // in flight during MFMA below

    f16x8 af[4];
    #pragma unroll
    for (int mi = 0; mi < 4; mi++)
      af[mi] = *(const f16x8*)&A_s[wm + mi * 16 + l15][kb];
    #pragma unroll
    for (int ni = 0; ni < 4; ni++) {
      f16x8 bh = *(const f16x8*)&W_s[wn + ni * 16 + l15][kb];
      #pragma unroll
      for (int mi = 0; mi < 4; mi++)
        acc[mi][ni] = __builtin_amdgcn_mfma_f32_16x16x32_f16(af[mi], bh, acc[mi][ni], 0, 0, 0);
    }
    __syncthreads();
  }
  #undef LOADH
  // ---- coalesced epilogue: two 64-row passes through LDS ----
  __half* C_s = (__half*)smem;         // [64][136] = 17408 B <= 20480
  const int col = l15, rbase = (lane >> 4) * 4;
  #pragma unroll
  for (int hp = 0; hp < 2; hp++) {
    if ((wv >> 1) == hp) {             // waves owning rows hp*64 .. hp*64+63
      #pragma unroll
      for (int ni = 0; ni < 4; ni++) {
        const int gn = wn + ni * 16 + col;
        const float bv = bias[gn];
        #pragma unroll
        for (int mi = 0; mi < 4; mi++) {
          #pragma unroll
          for (int q = 0; q < 4; q++)
            C_s[(mi * 16 + rbase + q) * 136 + gn] = __float2half(acc[mi][ni][q] + bv);
        }
      }
    }
    __syncthreads();
    #pragma unroll
    for (int i = 0; i < 4; i++) {
      const int flat = tid + i * 256;  // 0..1023 = 64 rows x 16 uint4
      const int row = flat >> 4, c16 = flat & 15;
      const int gm = m0 + hp * 64 + row;
      if (gm < N)
        *(uint4*)(Cp + (size_t)gm * ldC + coloff + c16 * 8) =
            *(const uint4*)(C_s + row * 136 + c16 * 8);
    }
    __syncthreads();
  }
}

// -------- butterfly ADD merge of per-group partials (plain-exp softmax) -----
#define MERGE_ADD(d)                                                          \
  {                                                                           \
    l += __shfl_xor(l, d);                                                    \
    aca.x += __shfl_xor(aca.x, d); aca.y += __shfl_xor(aca.y, d);             \
    aca.z += __shfl_xor(aca.z, d); aca.w += __shfl_xor(aca.w, d);             \
    acb.x += __shfl_xor(acb.x, d); acb.y += __shfl_xor(acb.y, d);             \
    acb.z += __shfl_xor(acb.z, d); acb.w += __shfl_xor(acb.w, d);             \
  }

// ---------------- fused GATv2 gather, layers 0/1 (fp32 fallback) ------------
__global__ __launch_bounds__(256) void k_gat_small(
    const float* __restrict__ xl, const float* __restrict__ xr,
    const float* __restrict__ att, const float* __restrict__ bias,
    const int* __restrict__ offs, const int* __restrict__ degree,
    const int* __restrict__ csr_src,
    unsigned short* __restrict__ Ah, unsigned short* __restrict__ Al, int N) {
  const int node = blockIdx.x * 4 + (threadIdx.x >> 6);
  if (node >= N) return;
  const int lane = threadIdx.x & 63;
  const int g = lane >> 4;
  const int c = lane & 15;
  const int d0 = c * 8;
  const size_t nb = (size_t)node * 128 + d0;
  const float4 xra = *(const float4*)&xr[nb];
  const float4 xrb = *(const float4*)&xr[nb + 4];
  const float4 ata = *(const float4*)&att[d0];
  const float4 atb = *(const float4*)&att[d0 + 4];
  const int off = offs[node];
  const int deg = degree[node];
  float l = 0.f;
  float4 aca = make_float4(0.f, 0.f, 0.f, 0.f);
  float4 acb = make_float4(0.f, 0.f, 0.f, 0.f);
  int s0 = (g < deg) ? csr_src[off + g] : 0;
  int s1 = (g + 4 < deg) ? csr_src[off + g + 4] : 0;
  for (int j = g; j < deg; j += 8) {
    int sn0 = (j + 8 < deg) ? csr_src[off + j + 8] : 0;
    int sn1 = (j + 12 < deg) ? csr_src[off + j + 12] : 0;
    const size_t sb0 = (size_t)s0 * 128 + d0;
    const size_t sb1 = (size_t)s1 * 128 + d0;
    float4 xa0 = *(const float4*)&xl[sb0];
    float4 xb0 = *(const float4*)&xl[sb0 + 4];
    float4 xa1 = *(const float4*)&xl[sb1];
    float4 xb1 = *(const float4*)&xl[sb1 + 4];
    float t0 = lrelu(xa0.x + xra.x) * ata.x + lrelu(xa0.y + xra.y) * ata.y +
               lrelu(xa0.z + xra.z) * ata.z + lrelu(xa0.w + xra.w) * ata.w +
               lrelu(xb0.x + xrb.x) * atb.x + lrelu(xb0.y + xrb.y) * atb.y +
               lrelu(xb0.z + xrb.z) * atb.z + lrelu(xb0.w + xrb.w) * atb.w;
    float t1 = lrelu(xa1.x + xra.x) * ata.x + lrelu(xa1.y + xra.y) * ata.y +
               lrelu(xa1.z + xra.z) * ata.z + lrelu(xa1.w + xra.w) * ata.w +
               lrelu(xb1.x + xrb.x) * atb.x + lrelu(xb1.y + xrb.y) * atb.y +
               lrelu(xb1.z + xrb.z) * atb.z + lrelu(xb1.w + xrb.w) * atb.w;
    t0 += __shfl_xor(t0, 1);
    t0 += __shfl_xor(t0, 2);       // 4-lane head cluster -> per-head logit
    t1 += __shfl_xor(t1, 1);
    t1 += __shfl_xor(t1, 2);
    float p0 = __expf(t0);
    float p1 = (j + 4 < deg) ? __expf(t1) : 0.f;
    aca.x += p0 * xa0.x + p1 * xa1.x; aca.y += p0 * xa0.y + p1 * xa1.y;
    aca.z += p0 * xa0.z + p1 * xa1.z; aca.w += p0 * xa0.w + p1 * xa1.w;
    acb.x += p0 * xb0.x + p1 * xb1.x; acb.y += p0 * xb0.y + p1 * xb1.y;
    acb.z += p0 * xb0.z + p1 * xb1.z; acb.w += p0 * xb0.w + p1 * xb1.w;
    l += p0 + p1;
    s0 = sn0; s1 = sn1;
  }
  MERGE_ADD(16)
  MERGE_ADD(32)
  if (lane < 16) {
    const float inv = 1.f / l;
    const float4 b0 = *(const float4*)&bias[d0];
    const float4 b1 = *(const float4*)&bias[d0 + 4];
    float o[8] = {aca.x * inv + b0.x, aca.y * inv + b0.y,
                  aca.z * inv + b0.z, aca.w * inv + b0.w,
                  acb.x * inv + b1.x, acb.y * inv + b1.y,
                  acb.z * inv + b1.z, acb.w * inv + b1.w};
    unsigned short hs[8], ls[8];
    #pragma unroll
    for (int i = 0; i < 8; i++) {
      o[i] = o[i] > 0.f ? o[i] : __expf(o[i]) - 1.f;   // ELU
      split2(o[i], hs[i], ls[i]);
    }
    uint4 hv, lv;
    hv.x = (unsigned)hs[0] | ((unsigned)hs[1] << 16);
    hv.y = (unsigned)hs[2] | ((unsigned)hs[3] << 16);
    hv.z = (unsigned)hs[4] | ((unsigned)hs[5] << 16);
    hv.w = (unsigned)hs[6] | ((unsigned)hs[7] << 16);
    lv.x = (unsigned)ls[0] | ((unsigned)ls[1] << 16);
    lv.y = (unsigned)ls[2] | ((unsigned)ls[3] << 16);
    lv.z = (unsigned)ls[4] | ((unsigned)ls[5] << 16);
    lv.w = (unsigned)ls[6] | ((unsigned)ls[7] << 16);
    *(uint4*)&Ah[nb] = hv;
    *(uint4*)&Al[nb] = lv;
  }
}

// ---------------- packed-fp16 edge steps ------------------------------------
// Value accumulation in fp16 (v_pk_fma_f16). Bounds: |t|~0.3 -> p in [0.5,2],
// acc <= ~20 -> no fp16 overflow; acc error ~1e-4 (below verif threshold).
// 512-wide (layer 2): 16-lane head group reduce (4 shfl)
__device__ __forceinline__ void edge_step(uint4 vv, bool valid,
                                          const f16x2* xrh, const f16x2* ath,
                                          f16x2* acc16, float& l) {
  union { uint4 u; f16x2 h[4]; } xu; xu.u = vv;
  const f16x2 c02 = {(_Float16)0.2f, (_Float16)0.2f};
  float t = 0.f;
#if defined(HAS_FDOT2)
  #pragma unroll
  for (int i = 0; i < 4; i++) {
    f16x2 s = xu.h[i] + xrh[i];
    f16x2 lr = __builtin_elementwise_max(s, s * c02);
    t = __builtin_amdgcn_fdot2(lr, ath[i], t, false);
  }
#else
  #pragma unroll
  for (int i = 0; i < 4; i++) {
    f32x2 s = __builtin_convertvector(xu.h[i], f32x2) +
              __builtin_convertvector(xrh[i], f32x2);
    f32x2 a = __builtin_convertvector(ath[i], f32x2);
    t += fmaxf(s.x, 0.2f * s.x) * a.x + fmaxf(s.y, 0.2f * s.y) * a.y;
  }
#endif
  t += __shfl_xor(t, 1);
  t += __shfl_xor(t, 2);
  t += __shfl_xor(t, 4);
  t += __shfl_xor(t, 8);         // 16-lane head group -> head logit
  float p = valid ? __expf(t) : 0.f;
  l += p;
  const _Float16 ph = (_Float16)p;
  const f16x2 p2 = {ph, ph};
  #pragma unroll
  for (int i = 0; i < 4; i++)
    acc16[i] += p2 * xu.h[i];    // v_pk_fma_f16
}

// 128-wide (layers 0/1): 4-lane head cluster reduce (2 shfl), all edges valid
__device__ __forceinline__ void edge_step_small(uint4 vv,
                                                const f16x2* xrh, const f16x2* ath,
                                                f16x2* acc16, float& l) {
  union { uint4 u; f16x2 h[4]; } xu; xu.u = vv;
  const f16x2 c02 = {(_Float16)0.2f, (_Float16)0.2f};
  float t = 0.f;
#if defined(HAS_FDOT2)
  #pragma unroll
  for (int i = 0; i < 4; i++) {
    f16x2 s = xu.h[i] + xrh[i];
    f16x2 lr = __builtin_elementwise_max(s, s * c02);
    t = __builtin_amdgcn_fdot2(lr, ath[i], t, false);
  }
#else
  #pragma unroll
  for (int i = 0; i < 4; i++) {
    f32x2 s = __builtin_convertvector(xu.h[i], f32x2) +
              __builtin_convertvector(xrh[i], f32x2);
    f32x2 a = __builtin_convertvector(ath[i], f32x2);
    t += fmaxf(s.x, 0.2f * s.x) * a.x + fmaxf(s.y, 0.2f * s.y) * a.y;
  }
#endif
  t += __shfl_xor(t, 1);
  t += __shfl_xor(t, 2);         // 4-lane head cluster -> per-head logit
  float p = __expf(t);
  l += p;
  const _Float16 ph = (_Float16)p;
  const f16x2 p2 = {ph, ph};
  #pragma unroll
  for (int i = 0; i < 4; i++)
    acc16[i] += p2 * xu.h[i];
}

// ---------------- layers 0/1 gather over fp16 [N,128] -----------------------
// mode 0: write split-bf16 Ah/Al.  mode 1: write fp16 A16 (fused path).
__global__ __launch_bounds__(256) void k_gat_small16(
    const __half* __restrict__ xl, const __half* __restrict__ xr,
    const float* __restrict__ att, const float* __restrict__ bias,
    const int* __restrict__ offs, const int* __restrict__ degree,
    const int* __restrict__ csr_src,
    unsigned short* __restrict__ Ah, unsigned short* __restrict__ Al,
    __half* __restrict__ A16, int mode, int N) {
  const int node = blockIdx.x * 4 + (threadIdx.x >> 6);
  if (node >= N) return;
  const int lane = threadIdx.x & 63;
  const int g = lane >> 4;        // edge slot
  const int c = lane & 15;        // channel group (8 ch)
  const int d0 = c * 8;
  f16x2 xrh[4], ath[4];
  {
    union { uint4 u; f16x2 h[4]; } ru;
    ru.u = *(const uint4*)&xr[(size_t)node * 128 + d0];
    float4 a0 = *(const float4*)&att[d0];
    float4 a1 = *(const float4*)&att[d0 + 4];
    #pragma unroll
    for (int i = 0; i < 4; i++) xrh[i] = ru.h[i];
    ath[0] = (f16x2){(_Float16)a0.x, (_Float16)a0.y};
    ath[1] = (f16x2){(_Float16)a0.z, (_Float16)a0.w};
    ath[2] = (f16x2){(_Float16)a1.x, (_Float16)a1.y};
    ath[3] = (f16x2){(_Float16)a1.z, (_Float16)a1.w};
  }
  const int off = offs[node];
  const int deg = degree[node];
  const unsigned lb = (unsigned)d0 * 2u;        // byte offset in 256 B row
  f16x2 acc16[4] = {};
  float l = 0.f;
  int ia = (g < deg)     ? csr_src[off + g]     : 0;
  int ib = (g + 4 < deg) ? csr_src[off + g + 4] : 0;
  int ic = (g + 8 < deg) ? csr_src[off + g + 8] : 0;
  uint4 v0 = make_uint4(0, 0, 0, 0), v1 = v0;
  if (g < deg)     v0 = ldrow(xl, (unsigned)ia * 256u + lb);
  if (g + 4 < deg) v1 = ldrow(xl, (unsigned)ib * 256u + lb);
  for (int j = g; j < deg; j += 4) {
    uint4 vn = v0;
    if (j + 8 < deg) vn = ldrow(xl, (unsigned)ic * 256u + lb);
    int id = (j + 12 < deg) ? csr_src[off + j + 12] : 0;
    edge_step_small(v0, xrh, ath, acc16, l);
    v0 = v1; v1 = vn; ic = id;
  }
  f32x2 accv[4];
  #pragma unroll
  for (int i = 0; i < 4; i++) accv[i] = __builtin_convertvector(acc16[i], f32x2);
  // merge the 4 slots (lanes differ in bits 4-5)
  #pragma unroll
  for (int d = 16; d < 64; d <<= 1) {
    l += __shfl_xor(l, d);
    #pragma unroll
    for (int i = 0; i < 4; i++) {
      accv[i].x += __shfl_xor(accv[i].x, d);
      accv[i].y += __shfl_xor(accv[i].y, d);
    }
  }
  if (lane < 16) {
    const float inv = 1.f / l;
    const float4 b0 = *(const float4*)&bias[d0];
    const float4 b1 = *(const float4*)&bias[d0 + 4];
    float o[8] = {accv[0].x * inv + b0.x, accv[0].y * inv + b0.y,
                  accv[1].x * inv + b0.z, accv[1].y * inv + b0.w,
                  accv[2].x * inv + b1.x, accv[2].y * inv + b1.y,
                  accv[3].x * inv + b1.z, accv[3].y * inv + b1.w};
    #pragma unroll
    for (int i = 0; i < 8; i++)
      o[i] = o[i] > 0.f ? o[i] : __expf(o[i]) - 1.f;   // ELU
    const size_t nb = (size_t)node * 128 + d0;
    if (mode == 1) {
      union { uint4 u; __half h[8]; } ou;
      #pragma unroll
      for (int i = 0; i < 8; i++) ou.h[i] = __float2half(o[i]);
      *(uint4*)&A16[nb] = ou.u;
    } else {
      unsigned short hs[8], ls[8];
      #pragma unroll
      for (int i = 0; i < 8; i++) split2(o[i], hs[i], ls[i]);
      uint4 hv, lv;
      hv.x = (unsigned)hs[0] | ((unsigned)hs[1] << 16);
      hv.y = (unsigned)hs[2] | ((unsigned)hs[3] << 16);
      hv.z = (unsigned)hs[4] | ((unsigned)hs[5] << 16);
      hv.w = (unsigned)hs[6] | ((unsigned)hs[7] << 16);
      lv.x = (unsigned)ls[0] | ((unsigned)ls[1] << 16);
      lv.y = (unsigned)ls[2] | ((unsigned)ls[3] << 16);
      lv.z = (unsigned)ls[4] | ((unsigned)ls[5] << 16);
      lv.w = (unsigned)ls[6] | ((unsigned)ls[7] << 16);
      *(uint4*)&Ah[nb] = hv;
      *(uint4*)&Al[nb] = lv;
    }
  }
}

// ---------------- layer 2 FUSED gather: rotating prefetch -------------------
__global__ __launch_bounds__(256) void k_gat_fused4(
    const __half* __restrict__ xl4, const __half* __restrict__ xr4,
    const float* __restrict__ att2, const float* __restrict__ bias,
    const int* __restrict__ offs, const int* __restrict__ degree,
    const int* __restrict__ csr_src, float* __restrict__ out, int N) {
  const int node = blockIdx.x * 4 + (threadIdx.x >> 6);
  if (node >= N) return;
  const int lane = threadIdx.x & 63;
  f16x2 xrh[4], ath[4];
  {
    union { uint4 u; f16x2 h[4]; } ru;
    ru.u = *(const uint4*)&xr4[(size_t)node * 512 + lane * 8];
    float4 a0 = *(const float4*)&att2[lane * 8];
    float4 a1 = *(const float4*)&att2[lane * 8 + 4];
    #pragma unroll
    for (int i = 0; i < 4; i++) xrh[i] = ru.h[i];
    ath[0] = (f16x2){(_Float16)a0.x, (_Float16)a0.y};
    ath[1] = (f16x2){(_Float16)a0.z, (_Float16)a0.w};
    ath[2] = (f16x2){(_Float16)a1.x, (_Float16)a1.y};
    ath[3] = (f16x2){(_Float16)a1.z, (_Float16)a1.w};
  }
  const int off = offs[node];
  const int deg = degree[node];
  const unsigned lb = (unsigned)lane * 16u;     // byte offset in 1 KB row
  f16x2 acc16[4] = {};
  float l = 0.f;
  int s0 = csr_src[off];
  int s1 = (1 < deg) ? csr_src[off + 1] : 0;
  int s2 = (2 < deg) ? csr_src[off + 2] : 0;
  int s3 = (3 < deg) ? csr_src[off + 3] : 0;
  uint4 v0 = ldrow(xl4, (unsigned)s0 * 1024u + lb);
  uint4 v1 = (1 < deg) ? ldrow(xl4, (unsigned)s1 * 1024u + lb) : v0;
  uint4 v2 = (2 < deg) ? ldrow(xl4, (unsigned)s2 * 1024u + lb) : v0;
  uint4 v3 = (3 < deg) ? ldrow(xl4, (unsigned)s3 * 1024u + lb) : v0;
  s0 = (4 < deg) ? csr_src[off + 4] : 0;        // indices one iter ahead
  s1 = (5 < deg) ? csr_src[off + 5] : 0;
  s2 = (6 < deg) ? csr_src[off + 6] : 0;
  s3 = (7 < deg) ? csr_src[off + 7] : 0;
  for (int j = 0; j < deg; j += 4) {
    edge_step(v0, true, xrh, ath, acc16, l);    // j < deg guaranteed
    if (j + 4 < deg) v0 = ldrow(xl4, (unsigned)s0 * 1024u + lb);
    s0 = (j + 8 < deg) ? csr_src[off + j + 8] : 0;
    edge_step(v1, j + 1 < deg, xrh, ath, acc16, l);
    if (j + 5 < deg) v1 = ldrow(xl4, (unsigned)s1 * 1024u + lb);
    s1 = (j + 9 < deg) ? csr_src[off + j + 9] : 0;
    edge_step(v2, j + 2 < deg, xrh, ath, acc16, l);
    if (j + 6 < deg) v2 = ldrow(xl4, (unsigned)s2 * 1024u + lb);
    s2 = (j + 10 < deg) ? csr_src[off + j + 10] : 0;
    edge_step(v3, j + 3 < deg, xrh, ath, acc16, l);
    if (j + 7 < deg) v3 = ldrow(xl4, (unsigned)s3 * 1024u + lb);
    s3 = (j + 11 < deg) ? csr_src[off + j + 11] : 0;
  }
  f32x2 accv[4];
  #pragma unroll
  for (int i = 0; i < 4; i++) accv[i] = __builtin_convertvector(acc16[i], f32x2);
  // scale by own head's softmax-mean weight, then sum heads via butterfly
  const float w = 0.25f / l;
  const f32x2 w2 = {w, w};
  #pragma unroll
  for (int i = 0; i < 4; i++) accv[i] *= w2;
  #pragma unroll
  for (int d = 16; d < 64; d <<= 1) {
    #pragma unroll
    for (int i = 0; i < 4; i++) {
      accv[i].x += __shfl_xor(accv[i].x, d);
      accv[i].y += __shfl_xor(accv[i].y, d);
    }
  }
  if (lane < 16) {
    const int d0 = lane * 8;
    float4 b0 = *(const float4*)&bias[d0];
    float4 b1 = *(const float4*)&bias[d0 + 4];
    float* op = &out[(size_t)node * 128 + d0];
    *(float4*)op       = make_float4(accv[0].x + b0.x, accv[0].y + b0.y,
                                     accv[1].x + b0.z, accv[1].y + b0.w);
    *(float4*)(op + 4) = make_float4(accv[2].x + b1.x, accv[2].y + b1.y,
                                     accv[3].x + b1.z, accv[3].y + b1.w);
  }
}

// ---------------- fallback: layer 2 per-head fp32 gather --------------------
__global__ __launch_bounds__(256) void k_gat_head(
    const float* __restrict__ xl, const float* __restrict__ xr,
    const float* __restrict__ att_h, const float* __restrict__ bias,
    const int* __restrict__ offs, const int* __restrict__ degree,
    const int* __restrict__ csr_src, float* __restrict__ out, int N,
    int first, int last) {
  const int node = blockIdx.x * 4 + (threadIdx.x >> 6);
  if (node >= N) return;
  const int lane = threadIdx.x & 63;
  const int g = lane >> 4;
  const int c = lane & 15;
  const int d0 = c * 8;
  const size_t nb = (size_t)node * 128 + d0;
  const float4 xra = *(const float4*)&xr[nb];
  const float4 xrb = *(const float4*)&xr[nb + 4];
  const float4 ata = *(const float4*)&att_h[d0];
  const float4 atb = *(const float4*)&att_h[d0 + 4];
  const int off = offs[node];
  const int deg = degree[node];
  float l = 0.f;
  float4 aca = make_float4(0.f, 0.f, 0.f, 0.f);
  float4 acb = make_float4(0.f, 0.f, 0.f, 0.f);
  int s0 = (g < deg) ? csr_src[off + g] : 0;
  int s1 = (g + 4 < deg) ? csr_src[off + g + 4] : 0;
  for (int j = g; j < deg; j += 8) {
    int sn0 = (j + 8 < deg) ? csr_src[off + j + 8] : 0;
    int sn1 = (j + 12 < deg) ? csr_src[off + j + 12] : 0;
    const size_t sb0 = (size_t)s0 * 128 + d0;
    const size_t sb1 = (size_t)s1 * 128 + d0;
    float4 xa0 = *(const float4*)&xl[sb0];
    float4 xb0 = *(const float4*)&xl[sb0 + 4];
    float4 xa1 = *(const float4*)&xl[sb1];
    float4 xb1 = *(const float4*)&xl[sb1 + 4];
    float t0 = lrelu(xa0.x + xra.x) * ata.x + lrelu(xa0.y + xra.y) * ata.y +
               lrelu(xa0.z + xra.z) * ata.z + lrelu(xa0.w + xra.w) * ata.w +
               lrelu(xb0.x + xrb.x) * atb.x + lrelu(xb0.y + xrb.y) * atb.y +
               lrelu(xb0.z + xrb.z) * atb.z + lrelu(xb0.w + xrb.w) * atb.w;
    float t1 = lrelu(xa1.x + xra.x) * ata.x + lrelu(xa1.y + xra.y) * ata.y +
               lrelu(xa1.z + xra.z) * ata.z + lrelu(xa1.w + xra.w) * ata.w +
               lrelu(xb1.x + xrb.x) * atb.x + lrelu(xb1.y + xrb.y) * atb.y +
               lrelu(xb1.z + xrb.z) * atb.z + lrelu(xb1.w + xrb.w) * atb.w;
    t0 += __shfl_xor(t0, 1);
    t0 += __shfl_xor(t0, 2);
    t0 += __shfl_xor(t0, 4);
    t0 += __shfl_xor(t0, 8);
    t1 += __shfl_xor(t1, 1);
    t1 += __shfl_xor(t1, 2);
    t1 += __shfl_xor(t1, 4);
    t1 += __shfl_xor(t1, 8);
    float p0 = __expf(t0);
    float p1 = (j + 4 < deg) ? __expf(t1) : 0.f;
    aca.x += p0 * xa0.x + p1 * xa1.x; aca.y += p0 * xa0.y + p1 * xa1.y;
    aca.z += p0 * xa0.z + p1 * xa1.z; aca.w += p0 * xa0.w + p1 * xa1.w;
    acb.x += p0 * xb0.x + p1 * xb1.x; acb.y += p0 * xb0.y + p1 * xb1.y;
    acb.z += p0 * xb0.z + p1 * xb1.z; acb.w += p0 * xb0.w + p1 * xb1.w;
    l += p0 + p1;
    s0 = sn0; s1 = sn1;
  }
  MERGE_ADD(16)
  MERGE_ADD(32)
  if (lane < 16) {
    const float inv = 0.25f / l;
    float o[8] = {aca.x * inv, aca.y * inv, aca.z * inv, aca.w * inv,
                  acb.x * inv, acb.y * inv, acb.z * inv, acb.w * inv};
    float* op = &out[nb];
    if (!first) {
      float4 p0 = *(const float4*)op;
      float4 p1 = *(const float4*)(op + 4);
      o[0] += p0.x; o[1] += p0.y; o[2] += p0.z; o[3] += p0.w;
      o[4] += p1.x; o[5] += p1.y; o[6] += p1.z; o[7] += p1.w;
    }
    if (last) {
      float4 b0 = *(const float4*)&bias[d0];
      float4 b1 = *(const float4*)&bias[d0 + 4];
      o[0] += b0.x; o[1] += b0.y; o[2] += b0.z; o[3] += b0.w;
      o[4] += b1.x; o[5] += b1.y; o[6] += b1.z; o[7] += b1.w;
    }
    *(float4*)op       = make_float4(o[0], o[1], o[2], o[3]);
    *(float4*)(op + 4) = make_float4(o[4], o[5], o[6], o[7]);
  }
}

// ---------------------------------------------------------------------------
extern "C" void kernel_launch(void* const* d_in, const int* in_sizes, int n_in,
                              void* d_out, int out_size, void* d_ws, size_t ws_size,
                              hipStream_t stream) {
  const float* x     = (const float*)d_in[0];
  const int*   ei    = (const int*)  d_in[1];
  const float* Wl0   = (const float*)d_in[2];
  const float* bl0   = (const float*)d_in[3];
  const float* Wr0   = (const float*)d_in[4];
  const float* br0   = (const float*)d_in[5];
  const float* att0  = (const float*)d_in[6];
  const float* bias0 = (const float*)d_in[7];
  const float* Wl1   = (const float*)d_in[8];
  const float* bl1   = (const float*)d_in[9];
  const float* Wr1   = (const float*)d_in[10];
  const float* br1   = (const float*)d_in[11];
  const float* att1  = (const float*)d_in[12];
  const float* bias1 = (const float*)d_in[13];
  const float* Wl2   = (const float*)d_in[14];
  const float* bl2   = (const float*)d_in[15];
  const float* Wr2   = (const float*)d_in[16];
  const float* br2   = (const float*)d_in[17];
  const float* att2  = (const float*)d_in[18];
  const float* bias2 = (const float*)d_in[19];

  const int N = in_sizes[0] / 128;
  const int E = in_sizes[1] / 2;

  char* p = (char*)d_ws;
  auto alloc = [&](size_t bytes) {
    void* q = (void*)p;
    p += (bytes + 255) & ~(size_t)255;
    return q;
  };
  auto al = [](size_t b) { return (b + 255) & ~(size_t)255; };
  const size_t common = al((size_t)(N + 1) * 4) + 2 * al((size_t)N * 4) +
                        al((size_t)(E + N) * 4) + al((size_t)512) +
                        2 * al((size_t)N * 128 * 2) +
                        8 * al((size_t)128 * 128 * 2) +
                        4 * al((size_t)512 * 128 * 2) +
                        2 * al((size_t)512 * 128 * 2) +
                        4 * al((size_t)128 * 128 * 2);
  const size_t need_fused = common + 2 * al((size_t)N * 512 * 2);
  const bool fused = ws_size >= need_fused;   // deterministic across calls

  int* offs    = (int*)alloc((size_t)(N + 1) * 4);
  int* degree  = (int*)alloc((size_t)N * 4);
  int* cursor  = (int*)alloc((size_t)N * 4);
  int* csr_src = (int*)alloc((size_t)(E + N) * 4);
  int* partial = (int*)alloc((size_t)512);
  unsigned short* Agh = (unsigned short*)alloc((size_t)N * 128 * 2);
  unsigned short* Agl = (unsigned short*)alloc((size_t)N * 128 * 2);
  unsigned short* W0hl = (unsigned short*)alloc((size_t)128 * 128 * 2);
  unsigned short* W0ll = (unsigned short*)alloc((size_t)128 * 128 * 2);
  unsigned short* W0hr = (unsigned short*)alloc((size_t)128 * 128 * 2);
  unsigned short* W0lr = (unsigned short*)alloc((size_t)128 * 128 * 2);
  unsigned short* W1hl = (unsigned short*)alloc((size_t)128 * 128 * 2);
  unsigned short* W1ll = (unsigned short*)alloc((size_t)128 * 128 * 2);
  unsigned short* W1hr = (unsigned short*)alloc((size_t)128 * 128 * 2);
  unsigned short* W1lr = (unsigned short*)alloc((size_t)128 * 128 * 2);
  unsigned short* W2hl = (unsigned short*)alloc((size_t)512 * 128 * 2);
  unsigned short* W2ll = (unsigned short*)alloc((size_t)512 * 128 * 2);
  unsigned short* W2hr = (unsigned short*)alloc((size_t)512 * 128 * 2);
  unsigned short* W2lr = (unsigned short*)alloc((size_t)512 * 128 * 2);
  __half* W2fl = (__half*)alloc((size_t)512 * 128 * 2);   // fp16 W2
  __half* W2fr = (__half*)alloc((size_t)512 * 128 * 2);
  __half* W0fl = (__half*)alloc((size_t)128 * 128 * 2);   // fp16 W0/W1
  __half* W0fr = (__half*)alloc((size_t)128 * 128 * 2);
  __half* W1fl = (__half*)alloc((size_t)128 * 128 * 2);
  __half* W1fr = (__half*)alloc((size_t)128 * 128 * 2);
  __half* xl4 = nullptr; __half* xr4 = nullptr;   // fused: fp16 [N,512]
  float* xl = nullptr; float* xr = nullptr;       // fallback fp32 [N,128]
  __half* xl16 = nullptr; __half* xr16 = nullptr; // fused: fp16 [N,128] views
  if (fused) {
    xl4 = (__half*)alloc((size_t)N * 512 * 2);
    xr4 = (__half*)alloc((size_t)N * 512 * 2);
    xl16 = xl4;              // layers 0/1 alias the big buffers ([N,128] fp16)
    xr16 = xr4;
  } else {
    xl = (float*)alloc((size_t)N * 128 * 4);
    xr = (float*)alloc((size_t)N * 128 * 4);
  }
  // fp16 A rotation (fused): A16x (from x) -> A16a (L0 out) -> A16b (L1 out)
  __half* A16x = (__half*)Agl;
  __half* A16a = (__half*)Agh;
  __half* A16b = (__half*)Agl;   // A16x dead after layer-0 GEMM
  (void)n_in; (void)out_size;

  const int nb = (N + 1023) / 1024;

  // prep first: weights + x conversion + degree/cursor init (k_init folded in)
  const int NA4 = (N * 128) / 4;
  const int prepT = 196608 + NA4 + N;
  k_prep<<<(prepT + 255) / 256, 256, 0, stream>>>(
      Wl0, Wr0, Wl1, Wr1, Wl2, Wr2,
      W0hl, W0ll, W0hr, W0lr, W1hl, W1ll, W1hr, W1lr,
      W2hl, W2ll, W2hr, W2lr,
      W0fl, W0fr, W1fl, W1fr, W2fl, W2fr,
      x, A16x, Agh, Agl, N * 128, N, fused ? 1 : 0, degree, cursor);

  // CSR build (ws is re-poisoned each call, so rebuild every launch)
  k_hist<<<(E + 255) / 256, 256, 0, stream>>>(ei, E, degree);
  k_scan1<<<nb, 256, 0, stream>>>(degree, partial, N);
  k_scan2<<<1, 256, 0, stream>>>(partial, nb);
  k_scan3<<<nb, 256, 0, stream>>>(degree, partial, offs, N);
  k_scatter<<<(E + N + 255) / 256, 256, 0, stream>>>(ei, E, N, offs, cursor, csr_src);

  const int mb = (N + 127) / 128;        // M tiles
  const dim3 gg(mb, 2);                  // 128-wide GEMM grid
  const dim3 gg4(mb, 2, 4);              // layer-2 GEMM grid (z = head)
  const int gb = (N + 3) / 4;            // gather grid (4 nodes / block)

  if (fused) {
    // layer 0: fp16 GEMM from fp16 x
    k_gemm2h<<<gg, 256, 0, stream>>>(A16x, W0fl, W0fr, bl0, br0,
                                     xl16, xr16, N, 128);
    k_gat_small16<<<gb, 256, 0, stream>>>(xl16, xr16, att0, bias0, offs, degree,
                                          csr_src, nullptr, nullptr, A16a, 1, N);
    // layer 1: fp16 GEMM
    k_gemm2h<<<gg, 256, 0, stream>>>(A16a, W1fl, W1fr, bl1, br1,
                                     xl16, xr16, N, 128);
    k_gat_small16<<<gb, 256, 0, stream>>>(xl16, xr16, att1, bias1, offs, degree,
                                          csr_src, nullptr, nullptr, A16b, 1, N);
    // layer 2: fp16 GEMM, z = head slice
    k_gemm2h<<<gg4, 256, 0, stream>>>(A16b, W2fl, W2fr, bl2, br2,
                                      xl4, xr4, N, 512);
    k_gat_fused4<<<gb, 256, 0, stream>>>(xl4, xr4, att2, bias2, offs, degree,
                                         csr_src, (float*)d_out, N);
  } else {
    // layer 0
    k_gemm2s<<<gg, 256, 0, stream>>>(Agh, Agl, W0hl, W0ll, W0hr, W0lr,
                                     bl0, br0, xl, xr, N, 128, 0, 0);
    k_gat_small<<<gb, 256, 0, stream>>>(xl, xr, att0, bias0, offs, degree, csr_src,
                                        Agh, Agl, N);
    // layer 1
    k_gemm2s<<<gg, 256, 0, stream>>>(Agh, Agl, W1hl, W1ll, W1hr, W1lr,
                                     bl1, br1, xl, xr, N, 128, 0, 0);
    k_gat_small<<<gb, 256, 0, stream>>>(xl, xr, att1, bias1, offs, degree, csr_src,
                                        Agh, Agl, N);
    // layer 2 per head (full 3-term precision)
    for (int h = 0; h < 4; h++) {
      const int wo = h * 128 * 128;
      k_gemm2s<<<gg, 256, 0, stream>>>(Agh, Agl, W2hl + wo, W2ll + wo,
                                       W2hr + wo, W2lr + wo,
                                       bl2 + h * 128, br2 + h * 128,
                                       xl, xr, N, 128, 0, 0);
      k_gat_head<<<gb, 256, 0, stream>>>(xl, xr, att2 + h * 128, bias2, offs, degree,
                                         csr_src, (float*)d_out, N,
                                         h == 0 ? 1 : 0, h == 3 ? 1 : 0);
    }
  }
}